// Round 8
// baseline (380.361 us; speedup 1.0000x reference)
//
#include <hip/hip_runtime.h>
#include <hip/hip_bf16.h>
#include <math.h>

typedef __hip_bfloat16 bf16;
typedef __attribute__((ext_vector_type(8))) short short8v;   // 8 bf16 = 4 VGPRs (MFMA A/B frag)
typedef __attribute__((ext_vector_type(4))) float f32x4;     // MFMA C/D frag

#define NN 50000
#define EE 800000
#define EPB 4096   // edges per block (hist/scatter)
#define NBK 196    // dst buckets = ceil(NN/256); also blocks for hist/scatter
#define BCAP 6144  // max edges per bucket (mean 4096, sd ~64)

__device__ __forceinline__ float b2f(bf16 v) { return __bfloat162float(v); }
__device__ __forceinline__ float rcp_(float x) { return __builtin_amdgcn_rcpf(x); }
__device__ __forceinline__ float sigmoidf_(float x) { return rcp_(1.0f + __expf(-x)); }
__device__ __forceinline__ float tanhf_(float x) {
    float xx = fminf(fmaxf(x, -15.0f), 15.0f);
    float e = __expf(2.0f * xx);
    return (e - 1.0f) * rcp_(e + 1.0f);
}
__device__ __forceinline__ float leakyf_(float x) { return x > 0.0f ? x : 0.2f * x; }
__device__ __forceinline__ unsigned short f2bf(float f) {
    unsigned u = __float_as_uint(f);
    unsigned r = (u + 0x7FFFu + ((u >> 16) & 1u)) >> 16;
    return (unsigned short)r;
}
__device__ __forceinline__ unsigned pack2(float a, float b) {
    return (unsigned)f2bf(a) | ((unsigned)f2bf(b) << 16);
}
__device__ __forceinline__ float lo_(unsigned u) { return __uint_as_float(u << 16); }
__device__ __forceinline__ float hi_(unsigned u) { return __uint_as_float(u & 0xFFFF0000u); }

// weight-pool element offsets (fp32 pool in ws)
#define OFF_W1 0
#define OFF_B1 16384
#define OFF_W2 16512
#define OFF_B2 24704
#define OFF_W3 24768
#define OFF_B3 26816
#define OFF_GATW 26848
#define OFF_GAS 27872
#define OFF_GAD 27904
#define OFF_GAB 27936
#define OFF_WIHF 27968
#define OFF_BIHF 36160
#define OFF_BHHF 36416
#define OFF_WIHB 36672
#define OFF_BIHB 44864
#define OFF_BHHB 45120
#define OFF_GAMMA 45376
#define OFF_BETA 45504
#define OFF_FCW 45632
#define OFF_FCB 46912
#define WTOTAL 46922

// lstm-aux pool element offsets (separate fp32 buffer)
// WT: [dir][k=0..31][col=0..191] interleaved triples col=3*j+gate (gate: 0=i,1=g,2=o)
#define AX_WT 0
#define AX_BT 12288   // [dir][col]  bias (bih+bhh) in interleaved-col order
#define AX_GSC 12672  // [jj]  gamma * rsqrt(1+eps)
#define AX_GBE 12800  // [jj]  beta
#define AX_TOTAL 12928

struct WSrc { const void* p[20]; };

// ---------------- dtype detection ----------------
__global__ void k_detect(const unsigned short* __restrict__ xraw,
                         const unsigned int* __restrict__ eraw, int* __restrict__ flags) {
    __shared__ int f32f, i64f;
    int t = threadIdx.x;
    if (t == 0) { f32f = 0; i64f = 1; }
    __syncthreads();
    for (int i = t; i < 4096; i += 256) {
        unsigned short u = xraw[i];
        int ex = (u >> 7) & 0xFF;
        if (ex >= 0xC0) atomicOr(&f32f, 1);
        if (eraw[2 * i + 1] != 0u) atomicAnd(&i64f, 0);
    }
    __syncthreads();
    if (t == 0) { flags[0] = f32f; flags[1] = i64f; }
}

// ---------------- weight conversion into fp32 pool ----------------
__global__ void k_cvt_w(WSrc srcs, float* __restrict__ dst, const int* __restrict__ flags,
                        int total) {
    constexpr int WOFF[21] = {OFF_W1,   OFF_B1,   OFF_W2,   OFF_B2,   OFF_W3,   OFF_B3,
                              OFF_GATW, OFF_GAS,  OFF_GAD,  OFF_GAB,  OFF_WIHF, OFF_BIHF,
                              OFF_BHHF, OFF_WIHB, OFF_BIHB, OFF_BHHB, OFF_GAMMA, OFF_BETA,
                              OFF_FCW,  OFF_FCB,  WTOTAL};
    int i = blockIdx.x * 256 + threadIdx.x;
    if (i >= total) return;
    int tn = 0;
#pragma unroll
    for (int j = 1; j < 20; ++j)
        if (i >= WOFF[j]) tn = j;
    int local = i - WOFF[tn];
    if (flags[0]) dst[i] = ((const float*)srcs.p[tn])[local];
    else dst[i] = b2f(((const bf16*)srcs.p[tn])[local]);
}

// ---------------- LSTM weight repack: W' transposed + gate-interleaved, bias folded -----
__global__ void k_prep(const float* __restrict__ wp, float* __restrict__ aux) {
    int dir = blockIdx.x;
    int t = threadIdx.x;  // 0..191
    const float* W = wp + (dir ? OFF_WIHB : OFF_WIHF);
    const float* bi = wp + (dir ? OFF_BIHB : OFF_BIHF);
    const float* bh = wp + (dir ? OFF_BHHB : OFF_BHHF);
    int col = t;
    int j = col / 3, gate = col - 3 * j;
    int srcrow = j + (gate == 1 ? 128 : (gate == 2 ? 192 : 0));
    const float* src = W + (size_t)srcrow * 32;
    for (int k = 0; k < 32; ++k) aux[AX_WT + dir * 6144 + k * 192 + col] = src[k];
    aux[AX_BT + dir * 192 + col] = bi[srcrow] + bh[srcrow];
    if (t < 64) {
        int jj = dir * 64 + t;
        aux[AX_GSC + jj] = wp[OFF_GAMMA + jj] * rsqrtf(1.0f + 1e-5f);
        aux[AX_GBE + jj] = wp[OFF_BETA + jj];
    }
}

// ---------------- W1 split into bf16 hi+lo, transposed chunks for MFMA B-frags ----------
// wsplit layout: [kt=0..3][hi=0/lo=1][col=0..127][kk=0..31]  (ushort bf16)
__global__ void k_prep_w1(const float* __restrict__ wp, unsigned short* __restrict__ wsplit) {
    int t = blockIdx.x * 256 + threadIdx.x;
    if (t >= 16384) return;
    int k = t >> 7, col = t & 127;
    float w = wp[OFF_W1 + k * 128 + col];
    unsigned short hi = f2bf(w);
    float hif = __uint_as_float((unsigned)hi << 16);
    unsigned short lo = f2bf(w - hif);
    int kt = k >> 5, kk = k & 31;
    wsplit[((size_t)(kt * 2 + 0) * 128 + col) * 32 + kk] = hi;
    wsplit[((size_t)(kt * 2 + 1) * 128 + col) * 32 + kk] = lo;
}

// ---------------- bucketed CSR build ----------------
// P1: per-edge-block histogram over dst buckets (LDS atomics only)
__global__ __launch_bounds__(256) void k_hist(const void* __restrict__ eraw,
                                              unsigned* __restrict__ gh,
                                              const int* __restrict__ flags) {
    __shared__ int h[256];
    int t = threadIdx.x, b = blockIdx.x;
    h[t] = 0;
    __syncthreads();
    int e0 = b * EPB;
    bool i64 = flags[1] != 0;
    for (int i = t; i < EPB; i += 256) {
        int e = e0 + i;
        if (e < EE) {
            int d = i64 ? (int)((const long long*)eraw)[EE + e] : ((const int*)eraw)[EE + e];
            d = min(max(d, 0), NN - 1);
            atomicAdd(&h[d >> 8], 1);
        }
    }
    __syncthreads();
    gh[b * 256 + t] = (unsigned)h[t];
}

// P2: per-(block,bucket) bases + bucket bases (one block; coalesced reads)
__global__ __launch_bounds__(256) void k_bscan(const unsigned* __restrict__ gh,
                                               unsigned* __restrict__ gh2,
                                               int* __restrict__ bb, int* __restrict__ rptr) {
    __shared__ int s[256];
    int t = threadIdx.x;
    unsigned run = 0;
    for (int blk = 0; blk < NBK; ++blk) {
        unsigned v = gh[blk * 256 + t];
        gh2[blk * 256 + t] = run;  // within-bucket offset of this edge-block
        run += v;
    }
    s[t] = (int)run;
    __syncthreads();
    for (int o = 1; o < 256; o <<= 1) {
        int x = (t >= o) ? s[t - o] : 0;
        __syncthreads();
        s[t] += x;
        __syncthreads();
    }
    bb[t] = s[t] - (int)run;  // exclusive: bucket base (bb[196] lands on EE)
    if (t == 0) rptr[NN] = EE;
}

// P3: scatter (src,dst) pairs into bucket-partitioned array (LDS cursors, window writes)
__global__ __launch_bounds__(256) void k_scatter(const void* __restrict__ eraw,
                                                 const unsigned* __restrict__ gh2,
                                                 const int* __restrict__ bb,
                                                 int2* __restrict__ ebkt,
                                                 const int* __restrict__ flags) {
    __shared__ unsigned cur[256];
    int t = threadIdx.x, b = blockIdx.x;
    cur[t] = gh2[b * 256 + t] + (unsigned)bb[t];
    __syncthreads();
    int e0 = b * EPB;
    bool i64 = flags[1] != 0;
    for (int i = t; i < EPB; i += 256) {
        int e = e0 + i;
        if (e < EE) {
            int sn, d;
            if (i64) {
                sn = (int)((const long long*)eraw)[e];
                d = (int)((const long long*)eraw)[EE + e];
            } else {
                sn = ((const int*)eraw)[e];
                d = ((const int*)eraw)[EE + e];
            }
            sn = min(max(sn, 0), NN - 1);
            d = min(max(d, 0), NN - 1);
            unsigned pos = atomicAdd(&cur[d >> 8], 1u);
            if (pos < (unsigned)EE) ebkt[pos] = make_int2(sn, d);
        }
    }
}

// P4: per-bucket LDS counting sort -> coalesced csr_src segment + rptr/dis
__global__ __launch_bounds__(256) void k_bucket_csr(const int2* __restrict__ ebkt,
                                                    const int* __restrict__ bb,
                                                    int* __restrict__ rptr,
                                                    float* __restrict__ dis,
                                                    int* __restrict__ csr_src) {
    __shared__ int hist[256];
    __shared__ int excl[256];
    __shared__ int cur[256];
    __shared__ int sorted[BCAP];
    int t = threadIdx.x, b = blockIdx.x;
    int s0 = bb[b], s1 = bb[b + 1];
    int len = min(s1 - s0, BCAP);
    hist[t] = 0;
    __syncthreads();
    for (int i = t; i < len; i += 256) atomicAdd(&hist[ebkt[s0 + i].y & 255], 1);
    __syncthreads();
    int v = hist[t];
    excl[t] = v;
    __syncthreads();
    for (int o = 1; o < 256; o <<= 1) {
        int x = (t >= o) ? excl[t - o] : 0;
        __syncthreads();
        excl[t] += x;
        __syncthreads();
    }
    int loc = excl[t] - v;  // local exclusive offset
    int node = b * 256 + t;
    if (node < NN) {
        rptr[node] = s0 + loc;
        dis[node] = rsqrtf((float)(v + 1));
    }
    cur[t] = loc;
    __syncthreads();
    for (int i = t; i < len; i += 256) {
        int2 p = ebkt[s0 + i];
        int pos = atomicAdd(&cur[p.y & 255], 1);
        if (pos < BCAP) sorted[pos] = p.x;
    }
    __syncthreads();
    for (int i = t; i < len; i += 256) csr_src[s0 + i] = sorted[i];
}

// ---------------- GCN1 via MFMA (bf16 input path, split-precision W) --------------------
// C[64 nodes][128 cols] = x @ (Whi + Wlo), scaled by dis, bf16 out. 4 waves: wave w owns
// the 32x64 sub-tile at (w>>1, w&1). mfma_f32_16x16x32_bf16; A/B frags are [out-dim][k]
// contiguous-in-k (lane&15 = out index, (lane>>4)*8 = k chunk); C/D: col=lane&15,
// row=(lane>>4)*4+reg [m89-verified]. LDS pads (136/40 ushort strides) give 2-way bank
// access (free). Split W keeps fp32-precision weights: no new numeric noise vs VALU path.
__global__ __launch_bounds__(256) void k_gcn1_mfma(const void* __restrict__ A,
                                                   const unsigned short* __restrict__ wsplit,
                                                   unsigned* __restrict__ C, int n,
                                                   const int* __restrict__ flags,
                                                   const float* __restrict__ dis) {
    if (flags[0] != 0) return;  // bf16-input path only
    __shared__ unsigned short As[64 * 136];   // 17.4 KB
    __shared__ unsigned short Wh[128 * 40];   // 10.2 KB
    __shared__ unsigned short Wl[128 * 40];   // 10.2 KB
    int t = threadIdx.x;
    int l = t & 63, w = t >> 6;
    int base = blockIdx.x * 64;
    // stage A: 64 rows x 128 bf16 (x is raw bf16), 16B chunks
#pragma unroll
    for (int p = 0; p < 4; ++p) {
        int c = p * 256 + t;
        int nd = c >> 4, ko = (c & 15) * 8;
        int node = min(base + nd, n - 1);
        uint4 v = *(const uint4*)((const unsigned short*)A + (size_t)node * 128 + ko);
        *(uint4*)(As + nd * 136 + ko) = v;
    }
    int wr = (w >> 1) * 32, wc = (w & 1) * 64;
    int lrow = l & 15, lk = (l >> 4) * 8;
    f32x4 acc[2][4];
#pragma unroll
    for (int rb = 0; rb < 2; ++rb)
#pragma unroll
        for (int cb = 0; cb < 4; ++cb) acc[rb][cb] = (f32x4){0.f, 0.f, 0.f, 0.f};
    for (int kt = 0; kt < 4; ++kt) {
        __syncthreads();  // protects LDS (A on kt=0; W reuse after)
#pragma unroll
        for (int p = 0; p < 2; ++p) {
            int c = p * 256 + t;  // 512 chunks of 8 bf16
            int col = c >> 2, ko = (c & 3) * 8;
            *(uint4*)(Wh + col * 40 + ko) =
                *(const uint4*)(wsplit + ((size_t)(kt * 2 + 0) * 128 + col) * 32 + ko);
            *(uint4*)(Wl + col * 40 + ko) =
                *(const uint4*)(wsplit + ((size_t)(kt * 2 + 1) * 128 + col) * 32 + ko);
        }
        __syncthreads();
        short8v a0 = *(const short8v*)(As + (wr + lrow) * 136 + kt * 32 + lk);
        short8v a1 = *(const short8v*)(As + (wr + 16 + lrow) * 136 + kt * 32 + lk);
#pragma unroll
        for (int cb = 0; cb < 4; ++cb) {
            int col = wc + cb * 16 + lrow;
            short8v bh = *(const short8v*)(Wh + col * 40 + lk);
            short8v bl = *(const short8v*)(Wl + col * 40 + lk);
            acc[0][cb] = __builtin_amdgcn_mfma_f32_16x16x32_bf16(a0, bh, acc[0][cb], 0, 0, 0);
            acc[0][cb] = __builtin_amdgcn_mfma_f32_16x16x32_bf16(a0, bl, acc[0][cb], 0, 0, 0);
            acc[1][cb] = __builtin_amdgcn_mfma_f32_16x16x32_bf16(a1, bh, acc[1][cb], 0, 0, 0);
            acc[1][cb] = __builtin_amdgcn_mfma_f32_16x16x32_bf16(a1, bl, acc[1][cb], 0, 0, 0);
        }
    }
    // epilogue: scale by dis, bf16 store
#pragma unroll
    for (int rb = 0; rb < 2; ++rb) {
#pragma unroll
        for (int reg = 0; reg < 4; ++reg) {
            int row = wr + rb * 16 + (l >> 4) * 4 + reg;
            int node = base + row;
            if (node < n) {
                float sc = dis[node];
                unsigned short* cr = (unsigned short*)C + (size_t)node * 128;
#pragma unroll
                for (int cb = 0; cb < 4; ++cb) {
                    int col = wc + cb * 16 + lrow;
                    cr[col] = f2bf(acc[rb][cb][reg] * sc);
                }
            }
        }
    }
}

// ---------------- LDS-tiled GEMM: C(bf16) = A @ W, optional per-node dis scaling --------
template <int KIN, int KOUT, int MODE, bool SCALE>
__global__ __launch_bounds__(256) void k_tile_mm(const void* __restrict__ A,
                                                 const float* __restrict__ W,
                                                 unsigned* __restrict__ C, int n,
                                                 const int* __restrict__ flags, int want,
                                                 const float* __restrict__ dis) {
    if (want >= 0 && flags[0] != want) return;
    constexpr int BK = 32;
    constexpr int AST = BK + 4;
    constexpr int CPT = KOUT / 16;  // 8 / 4 / 2
    __shared__ float As[64 * AST];
    __shared__ float Ws[BK * KOUT];
    int t = threadIdx.x;
    int jc = t & 15;
    int ng = t >> 4;
    int base = blockIdx.x * 64;
    float acc[4][CPT];
#pragma unroll
    for (int i = 0; i < 4; ++i)
#pragma unroll
        for (int c = 0; c < CPT; ++c) acc[i][c] = 0.f;
    int snode = t >> 2;
    int gnode = min(base + snode, n - 1);
    int koff = (t & 3) * 8;
    for (int k0 = 0; k0 < KIN; k0 += BK) {
        {
            const float4* src = (const float4*)(W + k0 * KOUT);
            float4* dst = (float4*)Ws;
#pragma unroll
            for (int p = 0; p < BK * KOUT / 1024; ++p) dst[t + p * 256] = src[t + p * 256];
        }
        if (MODE == 0) {
            const unsigned* xr = (const unsigned*)A + (size_t)gnode * (KIN / 2) + (k0 + koff) / 2;
            unsigned u0 = xr[0], u1 = xr[1], u2 = xr[2], u3 = xr[3];
            float* d = As + snode * AST + koff;
            d[0] = lo_(u0); d[1] = hi_(u0);
            d[2] = lo_(u1); d[3] = hi_(u1);
            d[4] = lo_(u2); d[5] = hi_(u2);
            d[6] = lo_(u3); d[7] = hi_(u3);
        } else {
            const float4* ar = (const float4*)((const float*)A + (size_t)gnode * KIN + k0 + koff);
            float4 v0 = ar[0], v1 = ar[1];
            float4* d = (float4*)(As + snode * AST + koff);
            d[0] = v0;
            d[1] = v1;
        }
        __syncthreads();
#pragma unroll 8
        for (int k = 0; k < BK; ++k) {
            float w[CPT];
            const float* wr = Ws + k * KOUT + jc * CPT;
            if constexpr (CPT >= 4) {
#pragma unroll
                for (int c = 0; c < CPT; c += 4) {
                    float4 wv = *(const float4*)(wr + c);
                    w[c] = wv.x; w[c + 1] = wv.y; w[c + 2] = wv.z; w[c + 3] = wv.w;
                }
            } else {
                float2 wv = *(const float2*)wr;
                w[0] = wv.x; w[1] = wv.y;
            }
            float a0 = As[(ng * 4 + 0) * AST + k];
            float a1 = As[(ng * 4 + 1) * AST + k];
            float a2 = As[(ng * 4 + 2) * AST + k];
            float a3 = As[(ng * 4 + 3) * AST + k];
#pragma unroll
            for (int c = 0; c < CPT; ++c) {
                acc[0][c] += a0 * w[c];
                acc[1][c] += a1 * w[c];
                acc[2][c] += a2 * w[c];
                acc[3][c] += a3 * w[c];
            }
        }
        __syncthreads();
    }
#pragma unroll
    for (int i = 0; i < 4; ++i) {
        int node = base + ng * 4 + i;
        if (node < n) {
            float sc = SCALE ? dis[node] : 1.0f;
            unsigned* cr = C + (size_t)node * (KOUT / 2) + jc * (CPT / 2);
#pragma unroll
            for (int c = 0; c < CPT; c += 2)
                cr[c / 2] = pack2(acc[i][c] * sc, acc[i][c + 1] * sc);
        }
    }
}

// ---------------- GCN agg over pre-scaled t' (t*dis), bf16 gather -> fp32 out -----------
template <bool RELU>
__global__ void k_agg128(const unsigned* __restrict__ t, const int* __restrict__ rptr,
                         const int* __restrict__ csr_src, const float* __restrict__ dis,
                         const float* __restrict__ bias, float* __restrict__ out, int n) {
    int wave = (blockIdx.x * blockDim.x + threadIdx.x) >> 6;
    int lane = threadIdx.x & 63;
    if (wave >= n) return;
    int dst = wave;
    float dd = dis[dst];
    float ax, ay;
    {
        unsigned u = t[(size_t)dst * 64 + lane];
        ax = lo_(u);
        ay = hi_(u);
    }
    int s = __builtin_amdgcn_readfirstlane(max(0, min(rptr[dst], EE)));
    int e = __builtin_amdgcn_readfirstlane(max(s, min(rptr[dst + 1], EE)));
    int j = s;
    for (; j + 8 <= e; j += 8) {
        int i0 = csr_src[j], i1 = csr_src[j + 1], i2 = csr_src[j + 2], i3 = csr_src[j + 3];
        int i4 = csr_src[j + 4], i5 = csr_src[j + 5], i6 = csr_src[j + 6], i7 = csr_src[j + 7];
        unsigned u0 = t[(size_t)i0 * 64 + lane], u1 = t[(size_t)i1 * 64 + lane];
        unsigned u2 = t[(size_t)i2 * 64 + lane], u3 = t[(size_t)i3 * 64 + lane];
        unsigned u4 = t[(size_t)i4 * 64 + lane], u5 = t[(size_t)i5 * 64 + lane];
        unsigned u6 = t[(size_t)i6 * 64 + lane], u7 = t[(size_t)i7 * 64 + lane];
        ax += (lo_(u0) + lo_(u1)) + (lo_(u2) + lo_(u3)) + (lo_(u4) + lo_(u5)) + (lo_(u6) + lo_(u7));
        ay += (hi_(u0) + hi_(u1)) + (hi_(u2) + hi_(u3)) + (hi_(u4) + hi_(u5)) + (hi_(u6) + hi_(u7));
    }
    for (; j + 4 <= e; j += 4) {
        int i0 = csr_src[j], i1 = csr_src[j + 1], i2 = csr_src[j + 2], i3 = csr_src[j + 3];
        unsigned u0 = t[(size_t)i0 * 64 + lane], u1 = t[(size_t)i1 * 64 + lane];
        unsigned u2 = t[(size_t)i2 * 64 + lane], u3 = t[(size_t)i3 * 64 + lane];
        ax += (lo_(u0) + lo_(u1)) + (lo_(u2) + lo_(u3));
        ay += (hi_(u0) + hi_(u1)) + (hi_(u2) + hi_(u3));
    }
    for (; j < e; ++j) {
        unsigned u0 = t[(size_t)csr_src[j] * 64 + lane];
        ax += lo_(u0);
        ay += hi_(u0);
    }
    float2 bv = *(const float2*)(bias + 2 * lane);
    float vx = ax * dd + bv.x;
    float vy = ay * dd + bv.y;
    if (RELU) { vx = fmaxf(vx, 0.f); vy = fmaxf(vy, 0.f); }
    *(float2*)(out + (size_t)dst * 128 + 2 * lane) = make_float2(vx, vy);
}

// F=64: half-wave per edge, explicit 4-batches
template <bool RELU>
__global__ void k_agg64(const unsigned* __restrict__ t, const int* __restrict__ rptr,
                        const int* __restrict__ csr_src, const float* __restrict__ dis,
                        const float* __restrict__ bias, float* __restrict__ out, int n) {
    int wave = (blockIdx.x * blockDim.x + threadIdx.x) >> 6;
    int lane = threadIdx.x & 63;
    if (wave >= n) return;
    int dst = wave;
    int half = lane >> 5, l32 = lane & 31;
    float dd = dis[dst];
    float ax = 0.f, ay = 0.f;
    if (!half) {
        unsigned u = t[(size_t)dst * 32 + l32];
        ax = lo_(u);
        ay = hi_(u);
    }
    int s = max(0, min(rptr[dst], EE));
    int e = max(s, min(rptr[dst + 1], EE));
    int cnt = e - s;
    int pairs = cnt >> 1;
    int p = 0;
    for (; p + 4 <= pairs; p += 4) {
        int jb = s + 2 * p + half;
        int i0 = csr_src[jb], i1 = csr_src[jb + 2], i2 = csr_src[jb + 4], i3 = csr_src[jb + 6];
        unsigned u0 = t[(size_t)i0 * 32 + l32], u1 = t[(size_t)i1 * 32 + l32];
        unsigned u2 = t[(size_t)i2 * 32 + l32], u3 = t[(size_t)i3 * 32 + l32];
        ax += (lo_(u0) + lo_(u1)) + (lo_(u2) + lo_(u3));
        ay += (hi_(u0) + hi_(u1)) + (hi_(u2) + hi_(u3));
    }
    for (; p < pairs; ++p) {
        int i0 = csr_src[s + 2 * p + half];
        unsigned u0 = t[(size_t)i0 * 32 + l32];
        ax += lo_(u0);
        ay += hi_(u0);
    }
    if ((cnt & 1) && !half) {
        unsigned u0 = t[(size_t)csr_src[e - 1] * 32 + l32];
        ax += lo_(u0);
        ay += hi_(u0);
    }
    ax += __shfl_down(ax, 32);
    ay += __shfl_down(ay, 32);
    if (!half) {
        float2 bv = *(const float2*)(bias + 2 * l32);
        float vx = ax * dd + bv.x;
        float vy = ay * dd + bv.y;
        if (RELU) { vx = fmaxf(vx, 0.f); vy = fmaxf(vy, 0.f); }
        *(float2*)(out + (size_t)dst * 64 + 2 * l32) = make_float2(vx, vy);
    }
}

// F=32: quarter-wave per edge, explicit 4-batches
template <bool RELU>
__global__ void k_agg32(const unsigned* __restrict__ t, const int* __restrict__ rptr,
                        const int* __restrict__ csr_src, const float* __restrict__ dis,
                        const float* __restrict__ bias, float* __restrict__ out, int n) {
    int wave = (blockIdx.x * blockDim.x + threadIdx.x) >> 6;
    int lane = threadIdx.x & 63;
    if (wave >= n) return;
    int dst = wave;
    int q = lane >> 4, l16 = lane & 15;
    float dd = dis[dst];
    float ax = 0.f, ay = 0.f;
    if (q == 0) {
        unsigned u = t[(size_t)dst * 16 + l16];
        ax = lo_(u);
        ay = hi_(u);
    }
    int s = max(0, min(rptr[dst], EE));
    int e = max(s, min(rptr[dst + 1], EE));
    int cnt = e - s;
    int quads = cnt >> 2;
    int p = 0;
    for (; p + 4 <= quads; p += 4) {
        int jb = s + 4 * p + q;
        int i0 = csr_src[jb], i1 = csr_src[jb + 4], i2 = csr_src[jb + 8], i3 = csr_src[jb + 12];
        unsigned u0 = t[(size_t)i0 * 16 + l16], u1 = t[(size_t)i1 * 16 + l16];
        unsigned u2 = t[(size_t)i2 * 16 + l16], u3 = t[(size_t)i3 * 16 + l16];
        ax += (lo_(u0) + lo_(u1)) + (lo_(u2) + lo_(u3));
        ay += (hi_(u0) + hi_(u1)) + (hi_(u2) + hi_(u3));
    }
    for (; p < quads; ++p) {
        int i0 = csr_src[s + 4 * p + q];
        unsigned u0 = t[(size_t)i0 * 16 + l16];
        ax += lo_(u0);
        ay += hi_(u0);
    }
    int rem = cnt - 4 * quads;
    if (q < rem) {
        unsigned u0 = t[(size_t)csr_src[s + 4 * quads + q] * 16 + l16];
        ax += lo_(u0);
        ay += hi_(u0);
    }
    ax += __shfl_down(ax, 32);
    ay += __shfl_down(ay, 32);
    ax += __shfl_down(ax, 16);
    ay += __shfl_down(ay, 16);
    if (q == 0) {
        float2 bv = *(const float2*)(bias + 2 * l16);
        float vx = ax * dd + bv.x;
        float vy = ay * dd + bv.y;
        if (RELU) { vx = fmaxf(vx, 0.f); vy = fmaxf(vy, 0.f); }
        *(float2*)(out + (size_t)dst * 32 + 2 * l16) = make_float2(vx, vy);
    }
}

// ---------------- GAT ----------------
__global__ void k_gat_vec(const unsigned* __restrict__ g, const float* __restrict__ a_src,
                          const float* __restrict__ a_dst, float* __restrict__ asrc,
                          float* __restrict__ adst, int n) {
    int i = blockIdx.x * 256 + threadIdx.x;
    if (i >= n) return;
    float s = 0.0f, d = 0.0f;
    const unsigned* gr = g + (size_t)i * 16;
#pragma unroll
    for (int k = 0; k < 16; ++k) {
        unsigned u = gr[k];
        float v0 = lo_(u), v1 = hi_(u);
        s += v0 * a_src[2 * k] + v1 * a_src[2 * k + 1];
        d += v0 * a_dst[2 * k] + v1 * a_dst[2 * k + 1];
    }
    asrc[i] = s;
    adst[i] = d;
}

__global__ void k_gat_agg(const unsigned* __restrict__ g, const int* __restrict__ rptr,
                          const int* __restrict__ csr_src, const float* __restrict__ asrc,
                          const float* __restrict__ adst, const float* __restrict__ gat_b,
                          float* __restrict__ out, int n) {
    int wave = (blockIdx.x * blockDim.x + threadIdx.x) >> 6;
    int lane = threadIdx.x & 63;
    if (wave >= n) return;
    int dst = wave;
    int q = lane >> 4, l16 = lane & 15;
    float ad = adst[dst];
    int s = max(0, min(rptr[dst], EE));
    int e = max(s, min(rptr[dst + 1], EE));
    float ax = 0.f, ay = 0.f, denom = 0.f;
    if (q == 0) {
        float w0 = __expf(fminf(leakyf_(asrc[dst] + ad), 80.f));
        unsigned u = g[(size_t)dst * 16 + l16];
        ax = lo_(u) * w0;
        ay = hi_(u) * w0;
        denom = w0;
    }
    int cnt = e - s;
    int quads = cnt >> 2;
    int p = 0;
    for (; p + 4 <= quads; p += 4) {
        int jb = s + 4 * p + q;
        int i0 = csr_src[jb], i1 = csr_src[jb + 4], i2 = csr_src[jb + 8], i3 = csr_src[jb + 12];
        float a0 = asrc[i0], a1 = asrc[i1], a2 = asrc[i2], a3 = asrc[i3];
        unsigned u0 = g[(size_t)i0 * 16 + l16], u1 = g[(size_t)i1 * 16 + l16];
        unsigned u2 = g[(size_t)i2 * 16 + l16], u3 = g[(size_t)i3 * 16 + l16];
        float w0 = __expf(fminf(leakyf_(a0 + ad), 80.f));
        float w1 = __expf(fminf(leakyf_(a1 + ad), 80.f));
        float w2 = __expf(fminf(leakyf_(a2 + ad), 80.f));
        float w3 = __expf(fminf(leakyf_(a3 + ad), 80.f));
        denom += (w0 + w1) + (w2 + w3);
        ax += lo_(u0) * w0 + lo_(u1) * w1 + lo_(u2) * w2 + lo_(u3) * w3;
        ay += hi_(u0) * w0 + hi_(u1) * w1 + hi_(u2) * w2 + hi_(u3) * w3;
    }
    for (; p < quads; ++p) {
        int i0 = csr_src[s + 4 * p + q];
        float wgt = __expf(fminf(leakyf_(asrc[i0] + ad), 80.f));
        unsigned u0 = g[(size_t)i0 * 16 + l16];
        denom += wgt;
        ax += lo_(u0) * wgt;
        ay += hi_(u0) * wgt;
    }
    int rem = cnt - 4 * quads;
    if (q < rem) {
        int i0 = csr_src[s + 4 * quads + q];
        float wgt = __expf(fminf(leakyf_(asrc[i0] + ad), 80.f));
        unsigned u0 = g[(size_t)i0 * 16 + l16];
        denom += wgt;
        ax += lo_(u0) * wgt;
        ay += hi_(u0) * wgt;
    }
    ax += __shfl_down(ax, 32);
    ay += __shfl_down(ay, 32);
    denom += __shfl_down(denom, 32);
    ax += __shfl_down(ax, 16);
    ay += __shfl_down(ay, 16);
    denom += __shfl_down(denom, 16);
    if (q == 0) {
        float r = rcp_(denom);
        float vx = fmaxf(ax * r + gat_b[2 * l16], 0.f);
        float vy = fmaxf(ay * r + gat_b[2 * l16 + 1], 0.f);
        *(float2*)(out + (size_t)dst * 32 + 2 * l16) = make_float2(vx, vy);
    }
}

// ---------------- LSTM gates as tiled GEMM (k_tile_mm structure, proven fast) -----------
__global__ __launch_bounds__(256) void k_gates(const float* __restrict__ h,
                                               const float* __restrict__ aux,
                                               float* __restrict__ rbuf, int n) {
    constexpr int AST = 36;
    __shared__ float As[64 * AST];    // 9.2 KB
    __shared__ float Ws[32 * 192];    // 24.6 KB
    int t = threadIdx.x;
    int dir = blockIdx.y;
    int jc = t & 15;
    int ng = t >> 4;
    int base = blockIdx.x * 64;
    // stage Ws (6 float4/thread, coalesced)
    {
        const float4* src = (const float4*)(aux + AX_WT + dir * 6144);
        float4* dst = (float4*)Ws;
#pragma unroll
        for (int p = 0; p < 6; ++p) dst[t + p * 256] = src[t + p * 256];
    }
    // stage As (fp32 h rows)
    {
        int snode = t >> 2;
        int gnode = min(base + snode, n - 1);
        int koff = (t & 3) * 8;
        const float4* ar = (const float4*)(h + (size_t)gnode * 32 + koff);
        float4* d = (float4*)(As + snode * AST + koff);
        d[0] = ar[0];
        d[1] = ar[1];
    }
    // acc init = folded bias (bih+bhh), interleaved-col order
    float acc[4][12];
    {
        const float4* bt = (const float4*)(aux + AX_BT + dir * 192 + jc * 12);
        float4 b0 = bt[0], b1 = bt[1], b2 = bt[2];
        float b12[12] = {b0.x, b0.y, b0.z, b0.w, b1.x, b1.y, b1.z, b1.w,
                         b2.x, b2.y, b2.z, b2.w};
#pragma unroll
        for (int i = 0; i < 4; ++i)
#pragma unroll
            for (int c = 0; c < 12; ++c) acc[i][c] = b12[c];
    }
    __syncthreads();
#pragma unroll 8
    for (int k = 0; k < 32; ++k) {
        float w[12];
        const float* wr = Ws + k * 192 + jc * 12;
#pragma unroll
        for (int c = 0; c < 12; c += 4) {
            float4 wv = *(const float4*)(wr + c);
            w[c] = wv.x; w[c + 1] = wv.y; w[c + 2] = wv.z; w[c + 3] = wv.w;
        }
        float a0 = As[(ng * 4 + 0) * AST + k];
        float a1 = As[(ng * 4 + 1) * AST + k];
        float a2 = As[(ng * 4 + 2) * AST + k];
        float a3 = As[(ng * 4 + 3) * AST + k];
#pragma unroll
        for (int c = 0; c < 12; ++c) {
            acc[0][c] += a0 * w[c];
            acc[1][c] += a1 * w[c];
            acc[2][c] += a2 * w[c];
            acc[3][c] += a3 * w[c];
        }
    }
    // epilogue: v = sig(o)*tanh(sig(i)*tanh(g)); r = v*gsc + gbe
    float4 gscv = *(const float4*)(aux + AX_GSC + dir * 64 + jc * 4);
    float4 gbev = *(const float4*)(aux + AX_GBE + dir * 64 + jc * 4);
#pragma unroll
    for (int i = 0; i < 4; ++i) {
        int node = base + ng * 4 + i;
        if (node < n) {
            float v0 = sigmoidf_(acc[i][2]) * tanhf_(sigmoidf_(acc[i][0]) * tanhf_(acc[i][1]));
            float v1 = sigmoidf_(acc[i][5]) * tanhf_(sigmoidf_(acc[i][3]) * tanhf_(acc[i][4]));
            float v2 = sigmoidf_(acc[i][8]) * tanhf_(sigmoidf_(acc[i][6]) * tanhf_(acc[i][7]));
            float v3 = sigmoidf_(acc[i][11]) * tanhf_(sigmoidf_(acc[i][9]) * tanhf_(acc[i][10]));
            float4 rv;
            rv.x = v0 * gscv.x + gbev.x;
            rv.y = v1 * gscv.y + gbev.y;
            rv.z = v2 * gscv.z + gbev.z;
            rv.w = v3 * gscv.w + gbev.w;
            *(float4*)(rbuf + (size_t)node * 128 + dir * 64 + jc * 4) = rv;
        }
    }
}

// ---------------- FC 128->10 + output cast ------------------
__global__ __launch_bounds__(256) void k_fc(const float* __restrict__ rbuf,
                                            const float* __restrict__ wp,
                                            void* __restrict__ out,
                                            const int* __restrict__ flags, int n) {
    __shared__ float rs[64 * 129];  // 33 KB, stride 129 -> 2 lanes/bank (free)
    __shared__ float ps[4 * 640];   // 10 KB
    int t = threadIdx.x;
    int base = blockIdx.x * 64;
    for (int i = t; i < 2048; i += 256) {
        int nd = i >> 5, k4 = i & 31;
        int node = min(base + nd, n - 1);
        float4 v = ((const float4*)rbuf)[(size_t)node * 32 + k4];
        float* d = rs + nd * 129 + k4 * 4;
        d[0] = v.x; d[1] = v.y; d[2] = v.z; d[3] = v.w;
    }
    __syncthreads();
    {
        int nd = t & 63, quarter = t >> 6;  // quarter wave-uniform -> fcw scalar loads
        const float* fcw = wp + OFF_FCW;
        int jbase = quarter * 32;
        float p10[10];
#pragma unroll
        for (int c = 0; c < 10; ++c) p10[c] = 0.f;
#pragma unroll 4
        for (int k = 0; k < 32; ++k) {
            float r = rs[nd * 129 + jbase + k];
#pragma unroll
            for (int c = 0; c < 10; ++c) p10[c] += r * fcw[c * 128 + jbase + k];
        }
#pragma unroll
        for (int c = 0; c < 10; ++c) ps[quarter * 640 + nd * 10 + c] = p10[c];
    }
    __syncthreads();
    bool f32o = flags[0] != 0;
    for (int idx = t; idx < 640; idx += 256) {
        int gnode = base + idx / 10;
        if (gnode < n) {
            int c = idx % 10;
            float v = wp[OFF_FCB + c] + ps[idx] + ps[640 + idx] + ps[1280 + idx] + ps[1920 + idx];
            if (f32o) ((float*)out)[(size_t)base * 10 + idx] = v;
            else ((unsigned short*)out)[(size_t)base * 10 + idx] = f2bf(v);
        }
    }
}

// ---------------- launch ----------------
extern "C" void kernel_launch(void* const* d_in, const int* in_sizes, int n_in,
                              void* d_out, int out_size, void* d_ws, size_t ws_size,
                              hipStream_t stream) {
    const int N = NN;

    char* w = (char*)d_ws;
    auto alloc = [&](size_t bytes) {
        void* p = (void*)w;
        w += (bytes + 255) & ~(size_t)255;
        return p;
    };
    int* flags = (int*)alloc(256);
    float* wpool = (float*)alloc((size_t)WTOTAL * 4);
    float* aux = (float*)alloc((size_t)AX_TOTAL * 4);
    unsigned short* wsplit = (unsigned short*)alloc(65536);  // W1 bf16 hi/lo, transposed chunks
    float* dis = (float*)alloc((size_t)N * 4);
    int* rptr = (int*)alloc((size_t)(N + 1) * 4);
    int* csr_src = (int*)alloc((size_t)EE * 4);
    unsigned* gh = (unsigned*)alloc((size_t)NBK * 256 * 4);
    unsigned* gh2 = (unsigned*)alloc((size_t)NBK * 256 * 4);
    int* bb = (int*)alloc(1024);
    int2* ebkt = (int2*)alloc((size_t)EE * 8);
    float* asrc = (float*)alloc((size_t)N * 4);
    float* adst = (float*)alloc((size_t)N * 4);
    unsigned* bufT = (unsigned*)alloc((size_t)N * 64 * 4);  // bf16 N x 128
    float* bufH = (float*)alloc((size_t)N * 128 * 4);       // fp32 N x 128
    float* rbuf = (float*)alloc((size_t)N * 128 * 4);       // fp32 N x 128 (BN'd LSTM out)

    WSrc ws_srcs;
    for (int i = 0; i < 20; ++i) ws_srcs.p[i] = d_in[2 + i];

    const int NB = (N + 255) / 256;
    const int AGG = (N + 3) / 4;
    const int TMB = (N + 63) / 64;
    const int WB = (WTOTAL + 255) / 256;

    k_detect<<<1, 256, 0, stream>>>((const unsigned short*)d_in[0],
                                    (const unsigned int*)d_in[1], flags);
    k_cvt_w<<<WB, 256, 0, stream>>>(ws_srcs, wpool, flags, WTOTAL);
    k_prep<<<2, 192, 0, stream>>>(wpool, aux);
    k_prep_w1<<<64, 256, 0, stream>>>(wpool, wsplit);
    // bucketed CSR build
    k_hist<<<NBK, 256, 0, stream>>>(d_in[1], gh, flags);
    k_bscan<<<1, 256, 0, stream>>>(gh, gh2, bb, rptr);
    k_scatter<<<NBK, 256, 0, stream>>>(d_in[1], gh2, bb, ebkt, flags);
    k_bucket_csr<<<NBK, 256, 0, stream>>>(ebkt, bb, rptr, dis, csr_src);

    // GCN 1 (x -> t1' = (x@W1)*dis, bf16): MFMA path for bf16 input, VALU fallback for fp32
    k_gcn1_mfma<<<TMB, 256, 0, stream>>>(d_in[0], wsplit, bufT, N, flags, dis);
    k_tile_mm<128, 128, 1, true><<<TMB, 256, 0, stream>>>(d_in[0], wpool + OFF_W1, bufT, N, flags, 1, dis);
    k_agg128<true><<<AGG, 256, 0, stream>>>(bufT, rptr, csr_src, dis, wpool + OFF_B1, bufH, N);
    // GCN 2
    k_tile_mm<128, 64, 1, true><<<TMB, 256, 0, stream>>>(bufH, wpool + OFF_W2, bufT, N, flags, -1, dis);
    k_agg64<true><<<AGG, 256, 0, stream>>>(bufT, rptr, csr_src, dis, wpool + OFF_B2, bufH, N);
    // GCN 3
    k_tile_mm<64, 32, 1, true><<<TMB, 256, 0, stream>>>(bufH, wpool + OFF_W3, bufT, N, flags, -1, dis);
    k_agg32<false><<<AGG, 256, 0, stream>>>(bufT, rptr, csr_src, dis, wpool + OFF_B3, bufH, N);
    // GAT (unscaled)
    k_tile_mm<32, 32, 1, false><<<TMB, 256, 0, stream>>>(bufH, wpool + OFF_GATW, bufT, N, flags, -1, dis);
    k_gat_vec<<<NB, 256, 0, stream>>>(bufT, wpool + OFF_GAS, wpool + OFF_GAD, asrc, adst, N);
    k_gat_agg<<<AGG, 256, 0, stream>>>(bufT, rptr, csr_src, asrc, adst, wpool + OFF_GAB, bufH, N);
    // LSTM gates as tiled GEMM (+fused activation/BN), then FC
    k_gates<<<dim3(TMB, 2), 256, 0, stream>>>(bufH, aux, rbuf, N);
    k_fc<<<TMB, 256, 0, stream>>>(rbuf, wpool, d_out, flags, N);
}

// Round 9
// 362.858 us; speedup vs baseline: 1.0482x; 1.0482x over previous
//
#include <hip/hip_runtime.h>
#include <hip/hip_bf16.h>
#include <math.h>

typedef __hip_bfloat16 bf16;
typedef __attribute__((ext_vector_type(8))) short short8v;   // 8 bf16 = 4 VGPRs (MFMA A/B frag)
typedef __attribute__((ext_vector_type(4))) float f32x4;     // MFMA C/D frag

#define NN 50000
#define EE 800000
#define EPB 4096   // edges per block (hist/scatter)
#define NBK 196    // dst buckets = ceil(NN/256); also blocks for hist/scatter
#define BCAP 6144  // max edges per bucket (mean 4096, sd ~64)

__device__ __forceinline__ float b2f(bf16 v) { return __bfloat162float(v); }
__device__ __forceinline__ float rcp_(float x) { return __builtin_amdgcn_rcpf(x); }
__device__ __forceinline__ float sigmoidf_(float x) { return rcp_(1.0f + __expf(-x)); }
__device__ __forceinline__ float tanhf_(float x) {
    float xx = fminf(fmaxf(x, -15.0f), 15.0f);
    float e = __expf(2.0f * xx);
    return (e - 1.0f) * rcp_(e + 1.0f);
}
__device__ __forceinline__ float leakyf_(float x) { return x > 0.0f ? x : 0.2f * x; }
__device__ __forceinline__ unsigned short f2bf(float f) {
    unsigned u = __float_as_uint(f);
    unsigned r = (u + 0x7FFFu + ((u >> 16) & 1u)) >> 16;
    return (unsigned short)r;
}
__device__ __forceinline__ unsigned pack2(float a, float b) {
    return (unsigned)f2bf(a) | ((unsigned)f2bf(b) << 16);
}
__device__ __forceinline__ float lo_(unsigned u) { return __uint_as_float(u << 16); }
__device__ __forceinline__ float hi_(unsigned u) { return __uint_as_float(u & 0xFFFF0000u); }

// weight-pool element offsets (fp32 pool in ws)
#define OFF_W1 0
#define OFF_B1 16384
#define OFF_W2 16512
#define OFF_B2 24704
#define OFF_W3 24768
#define OFF_B3 26816
#define OFF_GATW 26848
#define OFF_GAS 27872
#define OFF_GAD 27904
#define OFF_GAB 27936
#define OFF_WIHF 27968
#define OFF_BIHF 36160
#define OFF_BHHF 36416
#define OFF_WIHB 36672
#define OFF_BIHB 44864
#define OFF_BHHB 45120
#define OFF_GAMMA 45376
#define OFF_BETA 45504
#define OFF_FCW 45632
#define OFF_FCB 46912
#define WTOTAL 46922

// lstm-aux pool element offsets (separate fp32 buffer)
// WT: [dir][k=0..31][col=0..191] interleaved triples col=3*j+gate (gate: 0=i,1=g,2=o)
#define AX_WT 0
#define AX_BT 12288   // [dir][col]  bias (bih+bhh) in interleaved-col order
#define AX_GSC 12672  // [jj]  gamma * rsqrt(1+eps)
#define AX_GBE 12800  // [jj]  beta
#define AX_TOTAL 12928

struct WSrc { const void* p[20]; };

// ---------------- dtype detection ----------------
__global__ void k_detect(const unsigned short* __restrict__ xraw,
                         const unsigned int* __restrict__ eraw, int* __restrict__ flags) {
    __shared__ int f32f, i64f;
    int t = threadIdx.x;
    if (t == 0) { f32f = 0; i64f = 1; }
    __syncthreads();
    for (int i = t; i < 4096; i += 256) {
        unsigned short u = xraw[i];
        int ex = (u >> 7) & 0xFF;
        if (ex >= 0xC0) atomicOr(&f32f, 1);
        if (eraw[2 * i + 1] != 0u) atomicAnd(&i64f, 0);
    }
    __syncthreads();
    if (t == 0) { flags[0] = f32f; flags[1] = i64f; }
}

// ---------------- weight conversion into fp32 pool ----------------
__global__ void k_cvt_w(WSrc srcs, float* __restrict__ dst, const int* __restrict__ flags,
                        int total) {
    constexpr int WOFF[21] = {OFF_W1,   OFF_B1,   OFF_W2,   OFF_B2,   OFF_W3,   OFF_B3,
                              OFF_GATW, OFF_GAS,  OFF_GAD,  OFF_GAB,  OFF_WIHF, OFF_BIHF,
                              OFF_BHHF, OFF_WIHB, OFF_BIHB, OFF_BHHB, OFF_GAMMA, OFF_BETA,
                              OFF_FCW,  OFF_FCB,  WTOTAL};
    int i = blockIdx.x * 256 + threadIdx.x;
    if (i >= total) return;
    int tn = 0;
#pragma unroll
    for (int j = 1; j < 20; ++j)
        if (i >= WOFF[j]) tn = j;
    int local = i - WOFF[tn];
    if (flags[0]) dst[i] = ((const float*)srcs.p[tn])[local];
    else dst[i] = b2f(((const bf16*)srcs.p[tn])[local]);
}

// ---------------- LSTM weight repack: W' transposed + gate-interleaved, bias folded -----
__global__ void k_prep(const float* __restrict__ wp, float* __restrict__ aux) {
    int dir = blockIdx.x;
    int t = threadIdx.x;  // 0..191
    const float* W = wp + (dir ? OFF_WIHB : OFF_WIHF);
    const float* bi = wp + (dir ? OFF_BIHB : OFF_BIHF);
    const float* bh = wp + (dir ? OFF_BHHB : OFF_BHHF);
    int col = t;
    int j = col / 3, gate = col - 3 * j;
    int srcrow = j + (gate == 1 ? 128 : (gate == 2 ? 192 : 0));
    const float* src = W + (size_t)srcrow * 32;
    for (int k = 0; k < 32; ++k) aux[AX_WT + dir * 6144 + k * 192 + col] = src[k];
    aux[AX_BT + dir * 192 + col] = bi[srcrow] + bh[srcrow];
    if (t < 64) {
        int jj = dir * 64 + t;
        aux[AX_GSC + jj] = wp[OFF_GAMMA + jj] * rsqrtf(1.0f + 1e-5f);
        aux[AX_GBE + jj] = wp[OFF_BETA + jj];
    }
}

// ---------------- W1 split into bf16 hi+lo, transposed chunks for MFMA B-frags ----------
// wsplit layout: [kt=0..3][hi=0/lo=1][col=0..127][kk=0..31]  (ushort bf16)
__global__ void k_prep_w1(const float* __restrict__ wp, unsigned short* __restrict__ wsplit) {
    int t = blockIdx.x * 256 + threadIdx.x;
    if (t >= 16384) return;
    int k = t >> 7, col = t & 127;
    float w = wp[OFF_W1 + k * 128 + col];
    unsigned short hi = f2bf(w);
    float hif = __uint_as_float((unsigned)hi << 16);
    unsigned short lo = f2bf(w - hif);
    int kt = k >> 5, kk = k & 31;
    wsplit[((size_t)(kt * 2 + 0) * 128 + col) * 32 + kk] = hi;
    wsplit[((size_t)(kt * 2 + 1) * 128 + col) * 32 + kk] = lo;
}

// ---------------- bucketed CSR build ----------------
// P1: per-edge-block histogram over dst buckets (LDS atomics only)
__global__ __launch_bounds__(256) void k_hist(const void* __restrict__ eraw,
                                              unsigned* __restrict__ gh,
                                              const int* __restrict__ flags) {
    __shared__ int h[256];
    int t = threadIdx.x, b = blockIdx.x;
    h[t] = 0;
    __syncthreads();
    int e0 = b * EPB;
    bool i64 = flags[1] != 0;
    for (int i = t; i < EPB; i += 256) {
        int e = e0 + i;
        if (e < EE) {
            int d = i64 ? (int)((const long long*)eraw)[EE + e] : ((const int*)eraw)[EE + e];
            d = min(max(d, 0), NN - 1);
            atomicAdd(&h[d >> 8], 1);
        }
    }
    __syncthreads();
    gh[b * 256 + t] = (unsigned)h[t];
}

// P2: per-(block,bucket) bases + bucket bases (one block; coalesced reads)
__global__ __launch_bounds__(256) void k_bscan(const unsigned* __restrict__ gh,
                                               unsigned* __restrict__ gh2,
                                               int* __restrict__ bb, int* __restrict__ rptr) {
    __shared__ int s[256];
    int t = threadIdx.x;
    unsigned run = 0;
    for (int blk = 0; blk < NBK; ++blk) {
        unsigned v = gh[blk * 256 + t];
        gh2[blk * 256 + t] = run;  // within-bucket offset of this edge-block
        run += v;
    }
    s[t] = (int)run;
    __syncthreads();
    for (int o = 1; o < 256; o <<= 1) {
        int x = (t >= o) ? s[t - o] : 0;
        __syncthreads();
        s[t] += x;
        __syncthreads();
    }
    bb[t] = s[t] - (int)run;  // exclusive: bucket base (bb[196] lands on EE)
    if (t == 0) rptr[NN] = EE;
}

// P3: scatter (src,dst) pairs into bucket-partitioned array (LDS cursors, window writes)
__global__ __launch_bounds__(256) void k_scatter(const void* __restrict__ eraw,
                                                 const unsigned* __restrict__ gh2,
                                                 const int* __restrict__ bb,
                                                 int2* __restrict__ ebkt,
                                                 const int* __restrict__ flags) {
    __shared__ unsigned cur[256];
    int t = threadIdx.x, b = blockIdx.x;
    cur[t] = gh2[b * 256 + t] + (unsigned)bb[t];
    __syncthreads();
    int e0 = b * EPB;
    bool i64 = flags[1] != 0;
    for (int i = t; i < EPB; i += 256) {
        int e = e0 + i;
        if (e < EE) {
            int sn, d;
            if (i64) {
                sn = (int)((const long long*)eraw)[e];
                d = (int)((const long long*)eraw)[EE + e];
            } else {
                sn = ((const int*)eraw)[e];
                d = ((const int*)eraw)[EE + e];
            }
            sn = min(max(sn, 0), NN - 1);
            d = min(max(d, 0), NN - 1);
            unsigned pos = atomicAdd(&cur[d >> 8], 1u);
            if (pos < (unsigned)EE) ebkt[pos] = make_int2(sn, d);
        }
    }
}

// P4: per-bucket LDS counting sort -> coalesced csr_src segment + rptr/dis
__global__ __launch_bounds__(256) void k_bucket_csr(const int2* __restrict__ ebkt,
                                                    const int* __restrict__ bb,
                                                    int* __restrict__ rptr,
                                                    float* __restrict__ dis,
                                                    int* __restrict__ csr_src) {
    __shared__ int hist[256];
    __shared__ int excl[256];
    __shared__ int cur[256];
    __shared__ int sorted[BCAP];
    int t = threadIdx.x, b = blockIdx.x;
    int s0 = bb[b], s1 = bb[b + 1];
    int len = min(s1 - s0, BCAP);
    hist[t] = 0;
    __syncthreads();
    for (int i = t; i < len; i += 256) atomicAdd(&hist[ebkt[s0 + i].y & 255], 1);
    __syncthreads();
    int v = hist[t];
    excl[t] = v;
    __syncthreads();
    for (int o = 1; o < 256; o <<= 1) {
        int x = (t >= o) ? excl[t - o] : 0;
        __syncthreads();
        excl[t] += x;
        __syncthreads();
    }
    int loc = excl[t] - v;  // local exclusive offset
    int node = b * 256 + t;
    if (node < NN) {
        rptr[node] = s0 + loc;
        dis[node] = rsqrtf((float)(v + 1));
    }
    cur[t] = loc;
    __syncthreads();
    for (int i = t; i < len; i += 256) {
        int2 p = ebkt[s0 + i];
        int pos = atomicAdd(&cur[p.y & 255], 1);
        if (pos < BCAP) sorted[pos] = p.x;
    }
    __syncthreads();
    for (int i = t; i < len; i += 256) csr_src[s0 + i] = sorted[i];
}

// ---------------- GCN1 via MFMA (both input dtypes, split-precision) --------------------
// MODE 0: x already bf16 -> 2-term (x@Whi + x@Wlo).
// MODE 1: x fp32 -> staged as bf16 hi+lo -> 3-term (xhi@Whi + xhi@Wlo + xlo@Whi);
//         dropped xlo@Wlo term is ~2^-16 relative, invisible under bf16 output rounding.
// 4 waves: wave w owns the 32x64 sub-tile at (w>>1, w&1). mfma_f32_16x16x32_bf16.
// Both A/B frags are [out-dim][k] contiguous-in-k (B^T pattern, learn_hip m92/m97);
// C/D: col=lane&15, row=(lane>>4)*4+reg [m89-verified]. LDS strides 136/40 ushorts
// give <=4-way (mostly 2-way = free) bank access.
template <int MODE>
__global__ __launch_bounds__(256) void k_gcn1_mfma(const void* __restrict__ A,
                                                   const unsigned short* __restrict__ wsplit,
                                                   unsigned* __restrict__ C, int n,
                                                   const int* __restrict__ flags,
                                                   const float* __restrict__ dis) {
    if (flags[0] != MODE) return;
    __shared__ unsigned short Ah[64 * 136];                   // 17.4 KB
    __shared__ unsigned short Al[MODE ? 64 * 136 : 4];        // 17.4 KB (MODE 1 only)
    __shared__ unsigned short Wh[128 * 40];                   // 10.2 KB
    __shared__ unsigned short Wl[128 * 40];                   // 10.2 KB
    int t = threadIdx.x;
    int l = t & 63, w = t >> 6;
    int base = blockIdx.x * 64;
    if constexpr (MODE == 0) {
        // bf16 input: 16B chunks of 8 bf16
#pragma unroll
        for (int p = 0; p < 4; ++p) {
            int c = p * 256 + t;  // 1024 chunks
            int nd = c >> 4, ko = (c & 15) * 8;
            int node = min(base + nd, n - 1);
            uint4 v = *(const uint4*)((const unsigned short*)A + (size_t)node * 128 + ko);
            *(uint4*)(Ah + nd * 136 + ko) = v;
        }
    } else {
        // fp32 input: on-the-fly hi/lo bf16 split
#pragma unroll
        for (int p = 0; p < 8; ++p) {
            int c = p * 256 + t;  // 2048 float4 chunks
            int nd = c >> 5, ko = (c & 31) * 4;
            int node = min(base + nd, n - 1);
            float4 v = *(const float4*)((const float*)A + (size_t)node * 128 + ko);
            ushort4 hi, lo;
            hi.x = f2bf(v.x); lo.x = f2bf(v.x - __uint_as_float((unsigned)hi.x << 16));
            hi.y = f2bf(v.y); lo.y = f2bf(v.y - __uint_as_float((unsigned)hi.y << 16));
            hi.z = f2bf(v.z); lo.z = f2bf(v.z - __uint_as_float((unsigned)hi.z << 16));
            hi.w = f2bf(v.w); lo.w = f2bf(v.w - __uint_as_float((unsigned)hi.w << 16));
            *(ushort4*)(Ah + nd * 136 + ko) = hi;
            *(ushort4*)(Al + nd * 136 + ko) = lo;
        }
    }
    int wr = (w >> 1) * 32, wc = (w & 1) * 64;
    int lrow = l & 15, lk = (l >> 4) * 8;
    f32x4 acc[2][4];
#pragma unroll
    for (int rb = 0; rb < 2; ++rb)
#pragma unroll
        for (int cb = 0; cb < 4; ++cb) acc[rb][cb] = (f32x4){0.f, 0.f, 0.f, 0.f};
    for (int kt = 0; kt < 4; ++kt) {
        __syncthreads();  // protects Ah/Al (kt=0) and Wh/Wl reuse (kt>0)
#pragma unroll
        for (int p = 0; p < 2; ++p) {
            int c = p * 256 + t;  // 512 chunks of 8 bf16
            int col = c >> 2, ko = (c & 3) * 8;
            *(uint4*)(Wh + col * 40 + ko) =
                *(const uint4*)(wsplit + ((size_t)(kt * 2 + 0) * 128 + col) * 32 + ko);
            *(uint4*)(Wl + col * 40 + ko) =
                *(const uint4*)(wsplit + ((size_t)(kt * 2 + 1) * 128 + col) * 32 + ko);
        }
        __syncthreads();
        short8v ah0 = *(const short8v*)(Ah + (wr + lrow) * 136 + kt * 32 + lk);
        short8v ah1 = *(const short8v*)(Ah + (wr + 16 + lrow) * 136 + kt * 32 + lk);
        short8v al0, al1;
        if constexpr (MODE == 1) {
            al0 = *(const short8v*)(Al + (wr + lrow) * 136 + kt * 32 + lk);
            al1 = *(const short8v*)(Al + (wr + 16 + lrow) * 136 + kt * 32 + lk);
        }
#pragma unroll
        for (int cb = 0; cb < 4; ++cb) {
            int col = wc + cb * 16 + lrow;
            short8v bh = *(const short8v*)(Wh + col * 40 + lk);
            short8v bl = *(const short8v*)(Wl + col * 40 + lk);
            acc[0][cb] = __builtin_amdgcn_mfma_f32_16x16x32_bf16(ah0, bh, acc[0][cb], 0, 0, 0);
            acc[0][cb] = __builtin_amdgcn_mfma_f32_16x16x32_bf16(ah0, bl, acc[0][cb], 0, 0, 0);
            acc[1][cb] = __builtin_amdgcn_mfma_f32_16x16x32_bf16(ah1, bh, acc[1][cb], 0, 0, 0);
            acc[1][cb] = __builtin_amdgcn_mfma_f32_16x16x32_bf16(ah1, bl, acc[1][cb], 0, 0, 0);
            if constexpr (MODE == 1) {
                acc[0][cb] = __builtin_amdgcn_mfma_f32_16x16x32_bf16(al0, bh, acc[0][cb], 0, 0, 0);
                acc[1][cb] = __builtin_amdgcn_mfma_f32_16x16x32_bf16(al1, bh, acc[1][cb], 0, 0, 0);
            }
        }
    }
    // epilogue: scale by dis, bf16 store
#pragma unroll
    for (int rb = 0; rb < 2; ++rb) {
#pragma unroll
        for (int reg = 0; reg < 4; ++reg) {
            int row = wr + rb * 16 + (l >> 4) * 4 + reg;
            int node = base + row;
            if (node < n) {
                float sc = dis[node];
                unsigned short* cr = (unsigned short*)C + (size_t)node * 128;
#pragma unroll
                for (int cb = 0; cb < 4; ++cb) {
                    int col = wc + cb * 16 + lrow;
                    cr[col] = f2bf(acc[rb][cb][reg] * sc);
                }
            }
        }
    }
}

// ---------------- LDS-tiled GEMM: C(bf16) = A @ W, optional per-node dis scaling --------
template <int KIN, int KOUT, int MODE, bool SCALE>
__global__ __launch_bounds__(256) void k_tile_mm(const void* __restrict__ A,
                                                 const float* __restrict__ W,
                                                 unsigned* __restrict__ C, int n,
                                                 const int* __restrict__ flags, int want,
                                                 const float* __restrict__ dis) {
    if (want >= 0 && flags[0] != want) return;
    constexpr int BK = 32;
    constexpr int AST = BK + 4;
    constexpr int CPT = KOUT / 16;  // 8 / 4 / 2
    __shared__ float As[64 * AST];
    __shared__ float Ws[BK * KOUT];
    int t = threadIdx.x;
    int jc = t & 15;
    int ng = t >> 4;
    int base = blockIdx.x * 64;
    float acc[4][CPT];
#pragma unroll
    for (int i = 0; i < 4; ++i)
#pragma unroll
        for (int c = 0; c < CPT; ++c) acc[i][c] = 0.f;
    int snode = t >> 2;
    int gnode = min(base + snode, n - 1);
    int koff = (t & 3) * 8;
    for (int k0 = 0; k0 < KIN; k0 += BK) {
        {
            const float4* src = (const float4*)(W + k0 * KOUT);
            float4* dst = (float4*)Ws;
#pragma unroll
            for (int p = 0; p < BK * KOUT / 1024; ++p) dst[t + p * 256] = src[t + p * 256];
        }
        if (MODE == 0) {
            const unsigned* xr = (const unsigned*)A + (size_t)gnode * (KIN / 2) + (k0 + koff) / 2;
            unsigned u0 = xr[0], u1 = xr[1], u2 = xr[2], u3 = xr[3];
            float* d = As + snode * AST + koff;
            d[0] = lo_(u0); d[1] = hi_(u0);
            d[2] = lo_(u1); d[3] = hi_(u1);
            d[4] = lo_(u2); d[5] = hi_(u2);
            d[6] = lo_(u3); d[7] = hi_(u3);
        } else {
            const float4* ar = (const float4*)((const float*)A + (size_t)gnode * KIN + k0 + koff);
            float4 v0 = ar[0], v1 = ar[1];
            float4* d = (float4*)(As + snode * AST + koff);
            d[0] = v0;
            d[1] = v1;
        }
        __syncthreads();
#pragma unroll 8
        for (int k = 0; k < BK; ++k) {
            float w[CPT];
            const float* wr = Ws + k * KOUT + jc * CPT;
            if constexpr (CPT >= 4) {
#pragma unroll
                for (int c = 0; c < CPT; c += 4) {
                    float4 wv = *(const float4*)(wr + c);
                    w[c] = wv.x; w[c + 1] = wv.y; w[c + 2] = wv.z; w[c + 3] = wv.w;
                }
            } else {
                float2 wv = *(const float2*)wr;
                w[0] = wv.x; w[1] = wv.y;
            }
            float a0 = As[(ng * 4 + 0) * AST + k];
            float a1 = As[(ng * 4 + 1) * AST + k];
            float a2 = As[(ng * 4 + 2) * AST + k];
            float a3 = As[(ng * 4 + 3) * AST + k];
#pragma unroll
            for (int c = 0; c < CPT; ++c) {
                acc[0][c] += a0 * w[c];
                acc[1][c] += a1 * w[c];
                acc[2][c] += a2 * w[c];
                acc[3][c] += a3 * w[c];
            }
        }
        __syncthreads();
    }
#pragma unroll
    for (int i = 0; i < 4; ++i) {
        int node = base + ng * 4 + i;
        if (node < n) {
            float sc = SCALE ? dis[node] : 1.0f;
            unsigned* cr = C + (size_t)node * (KOUT / 2) + jc * (CPT / 2);
#pragma unroll
            for (int c = 0; c < CPT; c += 2)
                cr[c / 2] = pack2(acc[i][c] * sc, acc[i][c + 1] * sc);
        }
    }
}

// ---------------- GCN agg over pre-scaled t' (t*dis), bf16 gather -> fp32 out -----------
template <bool RELU>
__global__ void k_agg128(const unsigned* __restrict__ t, const int* __restrict__ rptr,
                         const int* __restrict__ csr_src, const float* __restrict__ dis,
                         const float* __restrict__ bias, float* __restrict__ out, int n) {
    int wave = (blockIdx.x * blockDim.x + threadIdx.x) >> 6;
    int lane = threadIdx.x & 63;
    if (wave >= n) return;
    int dst = wave;
    float dd = dis[dst];
    float ax, ay;
    {
        unsigned u = t[(size_t)dst * 64 + lane];
        ax = lo_(u);
        ay = hi_(u);
    }
    int s = __builtin_amdgcn_readfirstlane(max(0, min(rptr[dst], EE)));
    int e = __builtin_amdgcn_readfirstlane(max(s, min(rptr[dst + 1], EE)));
    int j = s;
    for (; j + 8 <= e; j += 8) {
        int i0 = csr_src[j], i1 = csr_src[j + 1], i2 = csr_src[j + 2], i3 = csr_src[j + 3];
        int i4 = csr_src[j + 4], i5 = csr_src[j + 5], i6 = csr_src[j + 6], i7 = csr_src[j + 7];
        unsigned u0 = t[(size_t)i0 * 64 + lane], u1 = t[(size_t)i1 * 64 + lane];
        unsigned u2 = t[(size_t)i2 * 64 + lane], u3 = t[(size_t)i3 * 64 + lane];
        unsigned u4 = t[(size_t)i4 * 64 + lane], u5 = t[(size_t)i5 * 64 + lane];
        unsigned u6 = t[(size_t)i6 * 64 + lane], u7 = t[(size_t)i7 * 64 + lane];
        ax += (lo_(u0) + lo_(u1)) + (lo_(u2) + lo_(u3)) + (lo_(u4) + lo_(u5)) + (lo_(u6) + lo_(u7));
        ay += (hi_(u0) + hi_(u1)) + (hi_(u2) + hi_(u3)) + (hi_(u4) + hi_(u5)) + (hi_(u6) + hi_(u7));
    }
    for (; j + 4 <= e; j += 4) {
        int i0 = csr_src[j], i1 = csr_src[j + 1], i2 = csr_src[j + 2], i3 = csr_src[j + 3];
        unsigned u0 = t[(size_t)i0 * 64 + lane], u1 = t[(size_t)i1 * 64 + lane];
        unsigned u2 = t[(size_t)i2 * 64 + lane], u3 = t[(size_t)i3 * 64 + lane];
        ax += (lo_(u0) + lo_(u1)) + (lo_(u2) + lo_(u3));
        ay += (hi_(u0) + hi_(u1)) + (hi_(u2) + hi_(u3));
    }
    for (; j < e; ++j) {
        unsigned u0 = t[(size_t)csr_src[j] * 64 + lane];
        ax += lo_(u0);
        ay += hi_(u0);
    }
    float2 bv = *(const float2*)(bias + 2 * lane);
    float vx = ax * dd + bv.x;
    float vy = ay * dd + bv.y;
    if (RELU) { vx = fmaxf(vx, 0.f); vy = fmaxf(vy, 0.f); }
    *(float2*)(out + (size_t)dst * 128 + 2 * lane) = make_float2(vx, vy);
}

// F=64: half-wave per edge, explicit 4-batches
template <bool RELU>
__global__ void k_agg64(const unsigned* __restrict__ t, const int* __restrict__ rptr,
                        const int* __restrict__ csr_src, const float* __restrict__ dis,
                        const float* __restrict__ bias, float* __restrict__ out, int n) {
    int wave = (blockIdx.x * blockDim.x + threadIdx.x) >> 6;
    int lane = threadIdx.x & 63;
    if (wave >= n) return;
    int dst = wave;
    int half = lane >> 5, l32 = lane & 31;
    float dd = dis[dst];
    float ax = 0.f, ay = 0.f;
    if (!half) {
        unsigned u = t[(size_t)dst * 32 + l32];
        ax = lo_(u);
        ay = hi_(u);
    }
    int s = max(0, min(rptr[dst], EE));
    int e = max(s, min(rptr[dst + 1], EE));
    int cnt = e - s;
    int pairs = cnt >> 1;
    int p = 0;
    for (; p + 4 <= pairs; p += 4) {
        int jb = s + 2 * p + half;
        int i0 = csr_src[jb], i1 = csr_src[jb + 2], i2 = csr_src[jb + 4], i3 = csr_src[jb + 6];
        unsigned u0 = t[(size_t)i0 * 32 + l32], u1 = t[(size_t)i1 * 32 + l32];
        unsigned u2 = t[(size_t)i2 * 32 + l32], u3 = t[(size_t)i3 * 32 + l32];
        ax += (lo_(u0) + lo_(u1)) + (lo_(u2) + lo_(u3));
        ay += (hi_(u0) + hi_(u1)) + (hi_(u2) + hi_(u3));
    }
    for (; p < pairs; ++p) {
        int i0 = csr_src[s + 2 * p + half];
        unsigned u0 = t[(size_t)i0 * 32 + l32];
        ax += lo_(u0);
        ay += hi_(u0);
    }
    if ((cnt & 1) && !half) {
        unsigned u0 = t[(size_t)csr_src[e - 1] * 32 + l32];
        ax += lo_(u0);
        ay += hi_(u0);
    }
    ax += __shfl_down(ax, 32);
    ay += __shfl_down(ay, 32);
    if (!half) {
        float2 bv = *(const float2*)(bias + 2 * l32);
        float vx = ax * dd + bv.x;
        float vy = ay * dd + bv.y;
        if (RELU) { vx = fmaxf(vx, 0.f); vy = fmaxf(vy, 0.f); }
        *(float2*)(out + (size_t)dst * 64 + 2 * l32) = make_float2(vx, vy);
    }
}

// F=32: quarter-wave per edge, explicit 4-batches
template <bool RELU>
__global__ void k_agg32(const unsigned* __restrict__ t, const int* __restrict__ rptr,
                        const int* __restrict__ csr_src, const float* __restrict__ dis,
                        const float* __restrict__ bias, float* __restrict__ out, int n) {
    int wave = (blockIdx.x * blockDim.x + threadIdx.x) >> 6;
    int lane = threadIdx.x & 63;
    if (wave >= n) return;
    int dst = wave;
    int q = lane >> 4, l16 = lane & 15;
    float dd = dis[dst];
    float ax = 0.f, ay = 0.f;
    if (q == 0) {
        unsigned u = t[(size_t)dst * 16 + l16];
        ax = lo_(u);
        ay = hi_(u);
    }
    int s = max(0, min(rptr[dst], EE));
    int e = max(s, min(rptr[dst + 1], EE));
    int cnt = e - s;
    int quads = cnt >> 2;
    int p = 0;
    for (; p + 4 <= quads; p += 4) {
        int jb = s + 4 * p + q;
        int i0 = csr_src[jb], i1 = csr_src[jb + 4], i2 = csr_src[jb + 8], i3 = csr_src[jb + 12];
        unsigned u0 = t[(size_t)i0 * 16 + l16], u1 = t[(size_t)i1 * 16 + l16];
        unsigned u2 = t[(size_t)i2 * 16 + l16], u3 = t[(size_t)i3 * 16 + l16];
        ax += (lo_(u0) + lo_(u1)) + (lo_(u2) + lo_(u3));
        ay += (hi_(u0) + hi_(u1)) + (hi_(u2) + hi_(u3));
    }
    for (; p < quads; ++p) {
        int i0 = csr_src[s + 4 * p + q];
        unsigned u0 = t[(size_t)i0 * 16 + l16];
        ax += lo_(u0);
        ay += hi_(u0);
    }
    int rem = cnt - 4 * quads;
    if (q < rem) {
        unsigned u0 = t[(size_t)csr_src[s + 4 * quads + q] * 16 + l16];
        ax += lo_(u0);
        ay += hi_(u0);
    }
    ax += __shfl_down(ax, 32);
    ay += __shfl_down(ay, 32);
    ax += __shfl_down(ax, 16);
    ay += __shfl_down(ay, 16);
    if (q == 0) {
        float2 bv = *(const float2*)(bias + 2 * l16);
        float vx = ax * dd + bv.x;
        float vy = ay * dd + bv.y;
        if (RELU) { vx = fmaxf(vx, 0.f); vy = fmaxf(vy, 0.f); }
        *(float2*)(out + (size_t)dst * 32 + 2 * l16) = make_float2(vx, vy);
    }
}

// ---------------- GAT ----------------
__global__ void k_gat_vec(const unsigned* __restrict__ g, const float* __restrict__ a_src,
                          const float* __restrict__ a_dst, float* __restrict__ asrc,
                          float* __restrict__ adst, int n) {
    int i = blockIdx.x * 256 + threadIdx.x;
    if (i >= n) return;
    float s = 0.0f, d = 0.0f;
    const unsigned* gr = g + (size_t)i * 16;
#pragma unroll
    for (int k = 0; k < 16; ++k) {
        unsigned u = gr[k];
        float v0 = lo_(u), v1 = hi_(u);
        s += v0 * a_src[2 * k] + v1 * a_src[2 * k + 1];
        d += v0 * a_dst[2 * k] + v1 * a_dst[2 * k + 1];
    }
    asrc[i] = s;
    adst[i] = d;
}

__global__ void k_gat_agg(const unsigned* __restrict__ g, const int* __restrict__ rptr,
                          const int* __restrict__ csr_src, const float* __restrict__ asrc,
                          const float* __restrict__ adst, const float* __restrict__ gat_b,
                          float* __restrict__ out, int n) {
    int wave = (blockIdx.x * blockDim.x + threadIdx.x) >> 6;
    int lane = threadIdx.x & 63;
    if (wave >= n) return;
    int dst = wave;
    int q = lane >> 4, l16 = lane & 15;
    float ad = adst[dst];
    int s = max(0, min(rptr[dst], EE));
    int e = max(s, min(rptr[dst + 1], EE));
    float ax = 0.f, ay = 0.f, denom = 0.f;
    if (q == 0) {
        float w0 = __expf(fminf(leakyf_(asrc[dst] + ad), 80.f));
        unsigned u = g[(size_t)dst * 16 + l16];
        ax = lo_(u) * w0;
        ay = hi_(u) * w0;
        denom = w0;
    }
    int cnt = e - s;
    int quads = cnt >> 2;
    int p = 0;
    for (; p + 4 <= quads; p += 4) {
        int jb = s + 4 * p + q;
        int i0 = csr_src[jb], i1 = csr_src[jb + 4], i2 = csr_src[jb + 8], i3 = csr_src[jb + 12];
        float a0 = asrc[i0], a1 = asrc[i1], a2 = asrc[i2], a3 = asrc[i3];
        unsigned u0 = g[(size_t)i0 * 16 + l16], u1 = g[(size_t)i1 * 16 + l16];
        unsigned u2 = g[(size_t)i2 * 16 + l16], u3 = g[(size_t)i3 * 16 + l16];
        float w0 = __expf(fminf(leakyf_(a0 + ad), 80.f));
        float w1 = __expf(fminf(leakyf_(a1 + ad), 80.f));
        float w2 = __expf(fminf(leakyf_(a2 + ad), 80.f));
        float w3 = __expf(fminf(leakyf_(a3 + ad), 80.f));
        denom += (w0 + w1) + (w2 + w3);
        ax += lo_(u0) * w0 + lo_(u1) * w1 + lo_(u2) * w2 + lo_(u3) * w3;
        ay += hi_(u0) * w0 + hi_(u1) * w1 + hi_(u2) * w2 + hi_(u3) * w3;
    }
    for (; p < quads; ++p) {
        int i0 = csr_src[s + 4 * p + q];
        float wgt = __expf(fminf(leakyf_(asrc[i0] + ad), 80.f));
        unsigned u0 = g[(size_t)i0 * 16 + l16];
        denom += wgt;
        ax += lo_(u0) * wgt;
        ay += hi_(u0) * wgt;
    }
    int rem = cnt - 4 * quads;
    if (q < rem) {
        int i0 = csr_src[s + 4 * quads + q];
        float wgt = __expf(fminf(leakyf_(asrc[i0] + ad), 80.f));
        unsigned u0 = g[(size_t)i0 * 16 + l16];
        denom += wgt;
        ax += lo_(u0) * wgt;
        ay += hi_(u0) * wgt;
    }
    ax += __shfl_down(ax, 32);
    ay += __shfl_down(ay, 32);
    denom += __shfl_down(denom, 32);
    ax += __shfl_down(ax, 16);
    ay += __shfl_down(ay, 16);
    denom += __shfl_down(denom, 16);
    if (q == 0) {
        float r = rcp_(denom);
        float vx = fmaxf(ax * r + gat_b[2 * l16], 0.f);
        float vy = fmaxf(ay * r + gat_b[2 * l16 + 1], 0.f);
        *(float2*)(out + (size_t)dst * 32 + 2 * l16) = make_float2(vx, vy);
    }
}

// ---------------- LSTM gates as tiled GEMM (k_tile_mm structure, proven fast) -----------
__global__ __launch_bounds__(256) void k_gates(const float* __restrict__ h,
                                               const float* __restrict__ aux,
                                               float* __restrict__ rbuf, int n) {
    constexpr int AST = 36;
    __shared__ float As[64 * AST];    // 9.2 KB
    __shared__ float Ws[32 * 192];    // 24.6 KB
    int t = threadIdx.x;
    int dir = blockIdx.y;
    int jc = t & 15;
    int ng = t >> 4;
    int base = blockIdx.x * 64;
    // stage Ws (6 float4/thread, coalesced)
    {
        const float4* src = (const float4*)(aux + AX_WT + dir * 6144);
        float4* dst = (float4*)Ws;
#pragma unroll
        for (int p = 0; p < 6; ++p) dst[t + p * 256] = src[t + p * 256];
    }
    // stage As (fp32 h rows)
    {
        int snode = t >> 2;
        int gnode = min(base + snode, n - 1);
        int koff = (t & 3) * 8;
        const float4* ar = (const float4*)(h + (size_t)gnode * 32 + koff);
        float4* d = (float4*)(As + snode * AST + koff);
        d[0] = ar[0];
        d[1] = ar[1];
    }
    // acc init = folded bias (bih+bhh), interleaved-col order
    float acc[4][12];
    {
        const float4* bt = (const float4*)(aux + AX_BT + dir * 192 + jc * 12);
        float4 b0 = bt[0], b1 = bt[1], b2 = bt[2];
        float b12[12] = {b0.x, b0.y, b0.z, b0.w, b1.x, b1.y, b1.z, b1.w,
                         b2.x, b2.y, b2.z, b2.w};
#pragma unroll
        for (int i = 0; i < 4; ++i)
#pragma unroll
            for (int c = 0; c < 12; ++c) acc[i][c] = b12[c];
    }
    __syncthreads();
#pragma unroll 8
    for (int k = 0; k < 32; ++k) {
        float w[12];
        const float* wr = Ws + k * 192 + jc * 12;
#pragma unroll
        for (int c = 0; c < 12; c += 4) {
            float4 wv = *(const float4*)(wr + c);
            w[c] = wv.x; w[c + 1] = wv.y; w[c + 2] = wv.z; w[c + 3] = wv.w;
        }
        float a0 = As[(ng * 4 + 0) * AST + k];
        float a1 = As[(ng * 4 + 1) * AST + k];
        float a2 = As[(ng * 4 + 2) * AST + k];
        float a3 = As[(ng * 4 + 3) * AST + k];
#pragma unroll
        for (int c = 0; c < 12; ++c) {
            acc[0][c] += a0 * w[c];
            acc[1][c] += a1 * w[c];
            acc[2][c] += a2 * w[c];
            acc[3][c] += a3 * w[c];
        }
    }
    // epilogue: v = sig(o)*tanh(sig(i)*tanh(g)); r = v*gsc + gbe
    float4 gscv = *(const float4*)(aux + AX_GSC + dir * 64 + jc * 4);
    float4 gbev = *(const float4*)(aux + AX_GBE + dir * 64 + jc * 4);
#pragma unroll
    for (int i = 0; i < 4; ++i) {
        int node = base + ng * 4 + i;
        if (node < n) {
            float v0 = sigmoidf_(acc[i][2]) * tanhf_(sigmoidf_(acc[i][0]) * tanhf_(acc[i][1]));
            float v1 = sigmoidf_(acc[i][5]) * tanhf_(sigmoidf_(acc[i][3]) * tanhf_(acc[i][4]));
            float v2 = sigmoidf_(acc[i][8]) * tanhf_(sigmoidf_(acc[i][6]) * tanhf_(acc[i][7]));
            float v3 = sigmoidf_(acc[i][11]) * tanhf_(sigmoidf_(acc[i][9]) * tanhf_(acc[i][10]));
            float4 rv;
            rv.x = v0 * gscv.x + gbev.x;
            rv.y = v1 * gscv.y + gbev.y;
            rv.z = v2 * gscv.z + gbev.z;
            rv.w = v3 * gscv.w + gbev.w;
            *(float4*)(rbuf + (size_t)node * 128 + dir * 64 + jc * 4) = rv;
        }
    }
}

// ---------------- FC 128->10 + output cast ------------------
__global__ __launch_bounds__(256) void k_fc(const float* __restrict__ rbuf,
                                            const float* __restrict__ wp,
                                            void* __restrict__ out,
                                            const int* __restrict__ flags, int n) {
    __shared__ float rs[64 * 129];  // 33 KB, stride 129 -> 2 lanes/bank (free)
    __shared__ float ps[4 * 640];   // 10 KB
    int t = threadIdx.x;
    int base = blockIdx.x * 64;
    for (int i = t; i < 2048; i += 256) {
        int nd = i >> 5, k4 = i & 31;
        int node = min(base + nd, n - 1);
        float4 v = ((const float4*)rbuf)[(size_t)node * 32 + k4];
        float* d = rs + nd * 129 + k4 * 4;
        d[0] = v.x; d[1] = v.y; d[2] = v.z; d[3] = v.w;
    }
    __syncthreads();
    {
        int nd = t & 63, quarter = t >> 6;  // quarter wave-uniform -> fcw scalar loads
        const float* fcw = wp + OFF_FCW;
        int jbase = quarter * 32;
        float p10[10];
#pragma unroll
        for (int c = 0; c < 10; ++c) p10[c] = 0.f;
#pragma unroll 4
        for (int k = 0; k < 32; ++k) {
            float r = rs[nd * 129 + jbase + k];
#pragma unroll
            for (int c = 0; c < 10; ++c) p10[c] += r * fcw[c * 128 + jbase + k];
        }
#pragma unroll
        for (int c = 0; c < 10; ++c) ps[quarter * 640 + nd * 10 + c] = p10[c];
    }
    __syncthreads();
    bool f32o = flags[0] != 0;
    for (int idx = t; idx < 640; idx += 256) {
        int gnode = base + idx / 10;
        if (gnode < n) {
            int c = idx % 10;
            float v = wp[OFF_FCB + c] + ps[idx] + ps[640 + idx] + ps[1280 + idx] + ps[1920 + idx];
            if (f32o) ((float*)out)[(size_t)base * 10 + idx] = v;
            else ((unsigned short*)out)[(size_t)base * 10 + idx] = f2bf(v);
        }
    }
}

// ---------------- launch ----------------
extern "C" void kernel_launch(void* const* d_in, const int* in_sizes, int n_in,
                              void* d_out, int out_size, void* d_ws, size_t ws_size,
                              hipStream_t stream) {
    const int N = NN;

    char* w = (char*)d_ws;
    auto alloc = [&](size_t bytes) {
        void* p = (void*)w;
        w += (bytes + 255) & ~(size_t)255;
        return p;
    };
    int* flags = (int*)alloc(256);
    float* wpool = (float*)alloc((size_t)WTOTAL * 4);
    float* aux = (float*)alloc((size_t)AX_TOTAL * 4);
    unsigned short* wsplit = (unsigned short*)alloc(65536);  // W1 bf16 hi/lo, transposed chunks
    float* dis = (float*)alloc((size_t)N * 4);
    int* rptr = (int*)alloc((size_t)(N + 1) * 4);
    int* csr_src = (int*)alloc((size_t)EE * 4);
    unsigned* gh = (unsigned*)alloc((size_t)NBK * 256 * 4);
    unsigned* gh2 = (unsigned*)alloc((size_t)NBK * 256 * 4);
    int* bb = (int*)alloc(1024);
    int2* ebkt = (int2*)alloc((size_t)EE * 8);
    float* asrc = (float*)alloc((size_t)N * 4);
    float* adst = (float*)alloc((size_t)N * 4);
    unsigned* bufT = (unsigned*)alloc((size_t)N * 64 * 4);  // bf16 N x 128
    float* bufH = (float*)alloc((size_t)N * 128 * 4);       // fp32 N x 128
    float* rbuf = (float*)alloc((size_t)N * 128 * 4);       // fp32 N x 128 (BN'd LSTM out)

    WSrc ws_srcs;
    for (int i = 0; i < 20; ++i) ws_srcs.p[i] = d_in[2 + i];

    const int NB = (N + 255) / 256;
    const int AGG = (N + 3) / 4;
    const int TMB = (N + 63) / 64;
    const int WB = (WTOTAL + 255) / 256;

    k_detect<<<1, 256, 0, stream>>>((const unsigned short*)d_in[0],
                                    (const unsigned int*)d_in[1], flags);
    k_cvt_w<<<WB, 256, 0, stream>>>(ws_srcs, wpool, flags, WTOTAL);
    k_prep<<<2, 192, 0, stream>>>(wpool, aux);
    k_prep_w1<<<64, 256, 0, stream>>>(wpool, wsplit);
    // bucketed CSR build
    k_hist<<<NBK, 256, 0, stream>>>(d_in[1], gh, flags);
    k_bscan<<<1, 256, 0, stream>>>(gh, gh2, bb, rptr);
    k_scatter<<<NBK, 256, 0, stream>>>(d_in[1], gh2, bb, ebkt, flags);
    k_bucket_csr<<<NBK, 256, 0, stream>>>(ebkt, bb, rptr, dis, csr_src);

    // GCN 1 (x -> t1' = (x@W1)*dis, bf16): MFMA for BOTH input dtypes (flag-gated)
    k_gcn1_mfma<0><<<TMB, 256, 0, stream>>>(d_in[0], wsplit, bufT, N, flags, dis);
    k_gcn1_mfma<1><<<TMB, 256, 0, stream>>>(d_in[0], wsplit, bufT, N, flags, dis);
    k_agg128<true><<<AGG, 256, 0, stream>>>(bufT, rptr, csr_src, dis, wpool + OFF_B1, bufH, N);
    // GCN 2
    k_tile_mm<128, 64, 1, true><<<TMB, 256, 0, stream>>>(bufH, wpool + OFF_W2, bufT, N, flags, -1, dis);
    k_agg64<true><<<AGG, 256, 0, stream>>>(bufT, rptr, csr_src, dis, wpool + OFF_B2, bufH, N);
    // GCN 3
    k_tile_mm<64, 32, 1, true><<<TMB, 256, 0, stream>>>(bufH, wpool + OFF_W3, bufT, N, flags, -1, dis);
    k_agg32<false><<<AGG, 256, 0, stream>>>(bufT, rptr, csr_src, dis, wpool + OFF_B3, bufH, N);
    // GAT (unscaled)
    k_tile_mm<32, 32, 1, false><<<TMB, 256, 0, stream>>>(bufH, wpool + OFF_GATW, bufT, N, flags, -1, dis);
    k_gat_vec<<<NB, 256, 0, stream>>>(bufT, wpool + OFF_GAS, wpool + OFF_GAD, asrc, adst, N);
    k_gat_agg<<<AGG, 256, 0, stream>>>(bufT, rptr, csr_src, asrc, adst, wpool + OFF_GAB, bufH, N);
    // LSTM gates as tiled GEMM (+fused activation/BN), then FC
    k_gates<<<dim3(TMB, 2), 256, 0, stream>>>(bufH, aux, rbuf, N);
    k_fc<<<TMB, 256, 0, stream>>>(rbuf, wpool, d_out, flags, N);
}

// Round 10
// 353.636 us; speedup vs baseline: 1.0756x; 1.0261x over previous
//
#include <hip/hip_runtime.h>
#include <hip/hip_bf16.h>
#include <math.h>

typedef __hip_bfloat16 bf16;
typedef __attribute__((ext_vector_type(8))) short short8v;   // 8 bf16 = 4 VGPRs (MFMA A/B frag)
typedef __attribute__((ext_vector_type(4))) float f32x4;     // MFMA C/D frag

#define NN 50000
#define EE 800000
#define EPB 4096   // edges per block (hist/scatter)
#define NBK 196    // dst buckets = ceil(NN/256); also blocks for hist/scatter
#define BCAP 6144  // max edges per bucket (mean 4096, sd ~64)

__device__ __forceinline__ float b2f(bf16 v) { return __bfloat162float(v); }
__device__ __forceinline__ float rcp_(float x) { return __builtin_amdgcn_rcpf(x); }
__device__ __forceinline__ float sigmoidf_(float x) { return rcp_(1.0f + __expf(-x)); }
__device__ __forceinline__ float tanhf_(float x) {
    float xx = fminf(fmaxf(x, -15.0f), 15.0f);
    float e = __expf(2.0f * xx);
    return (e - 1.0f) * rcp_(e + 1.0f);
}
__device__ __forceinline__ float leakyf_(float x) { return x > 0.0f ? x : 0.2f * x; }
__device__ __forceinline__ unsigned short f2bf(float f) {
    unsigned u = __float_as_uint(f);
    unsigned r = (u + 0x7FFFu + ((u >> 16) & 1u)) >> 16;
    return (unsigned short)r;
}
__device__ __forceinline__ unsigned pack2(float a, float b) {
    return (unsigned)f2bf(a) | ((unsigned)f2bf(b) << 16);
}
__device__ __forceinline__ float lo_(unsigned u) { return __uint_as_float(u << 16); }
__device__ __forceinline__ float hi_(unsigned u) { return __uint_as_float(u & 0xFFFF0000u); }
__device__ __forceinline__ void split4(float4 v, ushort4& hi, ushort4& lo) {
    hi.x = f2bf(v.x); lo.x = f2bf(v.x - __uint_as_float((unsigned)hi.x << 16));
    hi.y = f2bf(v.y); lo.y = f2bf(v.y - __uint_as_float((unsigned)hi.y << 16));
    hi.z = f2bf(v.z); lo.z = f2bf(v.z - __uint_as_float((unsigned)hi.z << 16));
    hi.w = f2bf(v.w); lo.w = f2bf(v.w - __uint_as_float((unsigned)hi.w << 16));
}

// weight-pool element offsets (fp32 pool in ws)
#define OFF_W1 0
#define OFF_B1 16384
#define OFF_W2 16512
#define OFF_B2 24704
#define OFF_W3 24768
#define OFF_B3 26816
#define OFF_GATW 26848
#define OFF_GAS 27872
#define OFF_GAD 27904
#define OFF_GAB 27936
#define OFF_WIHF 27968
#define OFF_BIHF 36160
#define OFF_BHHF 36416
#define OFF_WIHB 36672
#define OFF_BIHB 44864
#define OFF_BHHB 45120
#define OFF_GAMMA 45376
#define OFF_BETA 45504
#define OFF_FCW 45632
#define OFF_FCB 46912
#define WTOTAL 46922

struct WSrc { const void* p[20]; };

// ---------------- dtype detection ----------------
__global__ void k_detect(const unsigned short* __restrict__ xraw,
                         const unsigned int* __restrict__ eraw, int* __restrict__ flags) {
    __shared__ int f32f, i64f;
    int t = threadIdx.x;
    if (t == 0) { f32f = 0; i64f = 1; }
    __syncthreads();
    for (int i = t; i < 4096; i += 256) {
        unsigned short u = xraw[i];
        int ex = (u >> 7) & 0xFF;
        if (ex >= 0xC0) atomicOr(&f32f, 1);
        if (eraw[2 * i + 1] != 0u) atomicAnd(&i64f, 0);
    }
    __syncthreads();
    if (t == 0) { flags[0] = f32f; flags[1] = i64f; }
}

// ---------------- weight conversion into fp32 pool ----------------
__global__ void k_cvt_w(WSrc srcs, float* __restrict__ dst, const int* __restrict__ flags,
                        int total) {
    constexpr int WOFF[21] = {OFF_W1,   OFF_B1,   OFF_W2,   OFF_B2,   OFF_W3,   OFF_B3,
                              OFF_GATW, OFF_GAS,  OFF_GAD,  OFF_GAB,  OFF_WIHF, OFF_BIHF,
                              OFF_BHHF, OFF_WIHB, OFF_BIHB, OFF_BHHB, OFF_GAMMA, OFF_BETA,
                              OFF_FCW,  OFF_FCB,  WTOTAL};
    int i = blockIdx.x * 256 + threadIdx.x;
    if (i >= total) return;
    int tn = 0;
#pragma unroll
    for (int j = 1; j < 20; ++j)
        if (i >= WOFF[j]) tn = j;
    int local = i - WOFF[tn];
    if (flags[0]) dst[i] = ((const float*)srcs.p[tn])[local];
    else dst[i] = b2f(((const bf16*)srcs.p[tn])[local]);
}

// ---------------- W1 split into bf16 hi+lo, transposed chunks for MFMA B-frags ----------
// wsplit layout: [kt=0..3][hi=0/lo=1][col=0..127][kk=0..31]  (ushort bf16)
__global__ void k_prep_w1(const float* __restrict__ wp, unsigned short* __restrict__ wsplit) {
    int t = blockIdx.x * 256 + threadIdx.x;
    if (t >= 16384) return;
    int k = t >> 7, col = t & 127;
    float w = wp[OFF_W1 + k * 128 + col];
    unsigned short hi = f2bf(w);
    float hif = __uint_as_float((unsigned)hi << 16);
    unsigned short lo = f2bf(w - hif);
    int kt = k >> 5, kk = k & 31;
    wsplit[((size_t)(kt * 2 + 0) * 128 + col) * 32 + kk] = hi;
    wsplit[((size_t)(kt * 2 + 1) * 128 + col) * 32 + kk] = lo;
}

// ---------------- generic W split (row-major [KIN][KOUT] fp32 -> [kt][2][KOUT][32]) -----
template <int KIN, int KOUT>
__global__ void k_prep_ws(const float* __restrict__ src, unsigned short* __restrict__ dst) {
    int i = blockIdx.x * 256 + threadIdx.x;
    if (i >= KIN * KOUT) return;
    int k = i / KOUT, col = i % KOUT;
    float w = src[(size_t)k * KOUT + col];
    unsigned short hi = f2bf(w);
    unsigned short lo = f2bf(w - __uint_as_float((unsigned)hi << 16));
    int kt = k >> 5, kk = k & 31;
    dst[((size_t)(kt * 2 + 0) * KOUT + col) * 32 + kk] = hi;
    dst[((size_t)(kt * 2 + 1) * KOUT + col) * 32 + kk] = lo;
}

// ---------------- LSTM gate weight repack for MFMA: blocked gate rows, hi/lo -----------
// wsg layout: [dir][hi=0/lo=1][row=gate*64+j (gate 0=i,1=g,2=o)][k=0..31]
__global__ void k_prep_wg(const float* __restrict__ wp, unsigned short* __restrict__ wsg) {
    int t = blockIdx.x * 256 + threadIdx.x;
    if (t >= 12288) return;
    int dir = t / 6144, r2 = t % 6144;
    int row = r2 >> 5, k = r2 & 31;
    int gate = row >> 6, j = row & 63;
    int srcrow = j + (gate == 1 ? 128 : (gate == 2 ? 192 : 0));
    const float* W = wp + (dir ? OFF_WIHB : OFF_WIHF);
    float w = W[(size_t)srcrow * 32 + k];
    unsigned short hi = f2bf(w);
    unsigned short lo = f2bf(w - __uint_as_float((unsigned)hi << 16));
    wsg[((size_t)(dir * 2 + 0) * 192 + row) * 32 + k] = hi;
    wsg[((size_t)(dir * 2 + 1) * 192 + row) * 32 + k] = lo;
}

// ---------------- bucketed CSR build ----------------
__global__ __launch_bounds__(256) void k_hist(const void* __restrict__ eraw,
                                              unsigned* __restrict__ gh,
                                              const int* __restrict__ flags) {
    __shared__ int h[256];
    int t = threadIdx.x, b = blockIdx.x;
    h[t] = 0;
    __syncthreads();
    int e0 = b * EPB;
    bool i64 = flags[1] != 0;
    for (int i = t; i < EPB; i += 256) {
        int e = e0 + i;
        if (e < EE) {
            int d = i64 ? (int)((const long long*)eraw)[EE + e] : ((const int*)eraw)[EE + e];
            d = min(max(d, 0), NN - 1);
            atomicAdd(&h[d >> 8], 1);
        }
    }
    __syncthreads();
    gh[b * 256 + t] = (unsigned)h[t];
}

__global__ __launch_bounds__(256) void k_bscan(const unsigned* __restrict__ gh,
                                               unsigned* __restrict__ gh2,
                                               int* __restrict__ bb, int* __restrict__ rptr) {
    __shared__ int s[256];
    int t = threadIdx.x;
    unsigned run = 0;
    for (int blk = 0; blk < NBK; ++blk) {
        unsigned v = gh[blk * 256 + t];
        gh2[blk * 256 + t] = run;  // within-bucket offset of this edge-block
        run += v;
    }
    s[t] = (int)run;
    __syncthreads();
    for (int o = 1; o < 256; o <<= 1) {
        int x = (t >= o) ? s[t - o] : 0;
        __syncthreads();
        s[t] += x;
        __syncthreads();
    }
    bb[t] = s[t] - (int)run;  // exclusive: bucket base (bb[196] lands on EE)
    if (t == 0) rptr[NN] = EE;
}

__global__ __launch_bounds__(256) void k_scatter(const void* __restrict__ eraw,
                                                 const unsigned* __restrict__ gh2,
                                                 const int* __restrict__ bb,
                                                 int2* __restrict__ ebkt,
                                                 const int* __restrict__ flags) {
    __shared__ unsigned cur[256];
    int t = threadIdx.x, b = blockIdx.x;
    cur[t] = gh2[b * 256 + t] + (unsigned)bb[t];
    __syncthreads();
    int e0 = b * EPB;
    bool i64 = flags[1] != 0;
    for (int i = t; i < EPB; i += 256) {
        int e = e0 + i;
        if (e < EE) {
            int sn, d;
            if (i64) {
                sn = (int)((const long long*)eraw)[e];
                d = (int)((const long long*)eraw)[EE + e];
            } else {
                sn = ((const int*)eraw)[e];
                d = ((const int*)eraw)[EE + e];
            }
            sn = min(max(sn, 0), NN - 1);
            d = min(max(d, 0), NN - 1);
            unsigned pos = atomicAdd(&cur[d >> 8], 1u);
            if (pos < (unsigned)EE) ebkt[pos] = make_int2(sn, d);
        }
    }
}

__global__ __launch_bounds__(256) void k_bucket_csr(const int2* __restrict__ ebkt,
                                                    const int* __restrict__ bb,
                                                    int* __restrict__ rptr,
                                                    float* __restrict__ dis,
                                                    int* __restrict__ csr_src) {
    __shared__ int hist[256];
    __shared__ int excl[256];
    __shared__ int cur[256];
    __shared__ int sorted[BCAP];
    int t = threadIdx.x, b = blockIdx.x;
    int s0 = bb[b], s1 = bb[b + 1];
    int len = min(s1 - s0, BCAP);
    hist[t] = 0;
    __syncthreads();
    for (int i = t; i < len; i += 256) atomicAdd(&hist[ebkt[s0 + i].y & 255], 1);
    __syncthreads();
    int v = hist[t];
    excl[t] = v;
    __syncthreads();
    for (int o = 1; o < 256; o <<= 1) {
        int x = (t >= o) ? excl[t - o] : 0;
        __syncthreads();
        excl[t] += x;
        __syncthreads();
    }
    int loc = excl[t] - v;  // local exclusive offset
    int node = b * 256 + t;
    if (node < NN) {
        rptr[node] = s0 + loc;
        dis[node] = rsqrtf((float)(v + 1));
    }
    cur[t] = loc;
    __syncthreads();
    for (int i = t; i < len; i += 256) {
        int2 p = ebkt[s0 + i];
        int pos = atomicAdd(&cur[p.y & 255], 1);
        if (pos < BCAP) sorted[pos] = p.x;
    }
    __syncthreads();
    for (int i = t; i < len; i += 256) csr_src[s0 + i] = sorted[i];
}

// ---------------- GCN1 via MFMA (both input dtypes, split-precision) --------------------
template <int MODE>
__global__ __launch_bounds__(256) void k_gcn1_mfma(const void* __restrict__ A,
                                                   const unsigned short* __restrict__ wsplit,
                                                   unsigned* __restrict__ C, int n,
                                                   const int* __restrict__ flags,
                                                   const float* __restrict__ dis) {
    if (flags[0] != MODE) return;
    __shared__ unsigned short Ah[64 * 136];                   // 17.4 KB
    __shared__ unsigned short Al[MODE ? 64 * 136 : 4];        // 17.4 KB (MODE 1 only)
    __shared__ unsigned short Wh[128 * 40];                   // 10.2 KB
    __shared__ unsigned short Wl[128 * 40];                   // 10.2 KB
    int t = threadIdx.x;
    int l = t & 63, w = t >> 6;
    int base = blockIdx.x * 64;
    if constexpr (MODE == 0) {
#pragma unroll
        for (int p = 0; p < 4; ++p) {
            int c = p * 256 + t;
            int nd = c >> 4, ko = (c & 15) * 8;
            int node = min(base + nd, n - 1);
            uint4 v = *(const uint4*)((const unsigned short*)A + (size_t)node * 128 + ko);
            *(uint4*)(Ah + nd * 136 + ko) = v;
        }
    } else {
#pragma unroll
        for (int p = 0; p < 8; ++p) {
            int c = p * 256 + t;
            int nd = c >> 5, ko = (c & 31) * 4;
            int node = min(base + nd, n - 1);
            float4 v = *(const float4*)((const float*)A + (size_t)node * 128 + ko);
            ushort4 hi, lo;
            split4(v, hi, lo);
            *(ushort4*)(Ah + nd * 136 + ko) = hi;
            *(ushort4*)(Al + nd * 136 + ko) = lo;
        }
    }
    int wr = (w >> 1) * 32, wc = (w & 1) * 64;
    int lrow = l & 15, lk = (l >> 4) * 8;
    f32x4 acc[2][4];
#pragma unroll
    for (int rb = 0; rb < 2; ++rb)
#pragma unroll
        for (int cb = 0; cb < 4; ++cb) acc[rb][cb] = (f32x4){0.f, 0.f, 0.f, 0.f};
    for (int kt = 0; kt < 4; ++kt) {
        __syncthreads();
#pragma unroll
        for (int p = 0; p < 2; ++p) {
            int c = p * 256 + t;
            int col = c >> 2, ko = (c & 3) * 8;
            *(uint4*)(Wh + col * 40 + ko) =
                *(const uint4*)(wsplit + ((size_t)(kt * 2 + 0) * 128 + col) * 32 + ko);
            *(uint4*)(Wl + col * 40 + ko) =
                *(const uint4*)(wsplit + ((size_t)(kt * 2 + 1) * 128 + col) * 32 + ko);
        }
        __syncthreads();
        short8v ah0 = *(const short8v*)(Ah + (wr + lrow) * 136 + kt * 32 + lk);
        short8v ah1 = *(const short8v*)(Ah + (wr + 16 + lrow) * 136 + kt * 32 + lk);
        short8v al0, al1;
        if constexpr (MODE == 1) {
            al0 = *(const short8v*)(Al + (wr + lrow) * 136 + kt * 32 + lk);
            al1 = *(const short8v*)(Al + (wr + 16 + lrow) * 136 + kt * 32 + lk);
        }
#pragma unroll
        for (int cb = 0; cb < 4; ++cb) {
            int col = wc + cb * 16 + lrow;
            short8v bh = *(const short8v*)(Wh + col * 40 + lk);
            short8v bl = *(const short8v*)(Wl + col * 40 + lk);
            acc[0][cb] = __builtin_amdgcn_mfma_f32_16x16x32_bf16(ah0, bh, acc[0][cb], 0, 0, 0);
            acc[0][cb] = __builtin_amdgcn_mfma_f32_16x16x32_bf16(ah0, bl, acc[0][cb], 0, 0, 0);
            acc[1][cb] = __builtin_amdgcn_mfma_f32_16x16x32_bf16(ah1, bh, acc[1][cb], 0, 0, 0);
            acc[1][cb] = __builtin_amdgcn_mfma_f32_16x16x32_bf16(ah1, bl, acc[1][cb], 0, 0, 0);
            if constexpr (MODE == 1) {
                acc[0][cb] = __builtin_amdgcn_mfma_f32_16x16x32_bf16(al0, bh, acc[0][cb], 0, 0, 0);
                acc[1][cb] = __builtin_amdgcn_mfma_f32_16x16x32_bf16(al1, bh, acc[1][cb], 0, 0, 0);
            }
        }
    }
#pragma unroll
    for (int rb = 0; rb < 2; ++rb) {
#pragma unroll
        for (int reg = 0; reg < 4; ++reg) {
            int row = wr + rb * 16 + (l >> 4) * 4 + reg;
            int node = base + row;
            if (node < n) {
                float sc = dis[node];
                unsigned short* cr = (unsigned short*)C + (size_t)node * 128;
#pragma unroll
                for (int cb = 0; cb < 4; ++cb) {
                    int col = wc + cb * 16 + lrow;
                    cr[col] = f2bf(acc[rb][cb][reg] * sc);
                }
            }
        }
    }
}

// ---------------- generic MFMA GEMM: C(bf16[KOUT]) = A(fp32[KIN]) @ W, split-precision --
// Same verified layout as k_gcn1_mfma<1>: 4 waves, wave w owns (row-tile w>>1, col-half
// w&1); A hi/lo staged in LDS; 3-term MFMA (AhWh + AhWl + AlWh).
template <int KIN, int KOUT, bool SCALE>
__global__ __launch_bounds__(256) void k_mm_mfma(const float* __restrict__ A,
                                                 const unsigned short* __restrict__ wsplit,
                                                 unsigned short* __restrict__ C, int n,
                                                 const float* __restrict__ dis) {
    constexpr int AST = KIN + 8;
    constexpr int KT = KIN / 32;
    constexpr int CB = KOUT / 32;  // col-blocks per wave (KOUT=64 -> 2, 32 -> 1)
    __shared__ unsigned short Ah[64 * AST];
    __shared__ unsigned short Al[64 * AST];
    __shared__ unsigned short Wh[KOUT * 40];
    __shared__ unsigned short Wl[KOUT * 40];
    int t = threadIdx.x;
    int l = t & 63, w = t >> 6;
    int base = blockIdx.x * 64;
#pragma unroll
    for (int p = 0; p < KIN / 16; ++p) {
        int c = p * 256 + t;  // 64*KIN/4 float4 chunks
        int nd = c / (KIN / 4), ko = (c % (KIN / 4)) * 4;
        int node = min(base + nd, n - 1);
        float4 v = *(const float4*)(A + (size_t)node * KIN + ko);
        ushort4 hi, lo;
        split4(v, hi, lo);
        *(ushort4*)(Ah + nd * AST + ko) = hi;
        *(ushort4*)(Al + nd * AST + ko) = lo;
    }
    int wr = (w >> 1) * 32, wc = (w & 1) * (KOUT / 2);
    int lrow = l & 15, lk = (l >> 4) * 8;
    f32x4 acc[2][CB];
#pragma unroll
    for (int rb = 0; rb < 2; ++rb)
#pragma unroll
        for (int cb = 0; cb < CB; ++cb) acc[rb][cb] = (f32x4){0.f, 0.f, 0.f, 0.f};
    for (int kt = 0; kt < KT; ++kt) {
        __syncthreads();
        for (int c = t; c < KOUT * 4; c += 256) {  // uint4 chunks of 8 bf16
            int col = c >> 2, ko = (c & 3) * 8;
            *(uint4*)(Wh + col * 40 + ko) =
                *(const uint4*)(wsplit + ((size_t)(kt * 2 + 0) * KOUT + col) * 32 + ko);
            *(uint4*)(Wl + col * 40 + ko) =
                *(const uint4*)(wsplit + ((size_t)(kt * 2 + 1) * KOUT + col) * 32 + ko);
        }
        __syncthreads();
        short8v ah0 = *(const short8v*)(Ah + (wr + lrow) * AST + kt * 32 + lk);
        short8v ah1 = *(const short8v*)(Ah + (wr + 16 + lrow) * AST + kt * 32 + lk);
        short8v al0 = *(const short8v*)(Al + (wr + lrow) * AST + kt * 32 + lk);
        short8v al1 = *(const short8v*)(Al + (wr + 16 + lrow) * AST + kt * 32 + lk);
#pragma unroll
        for (int cb = 0; cb < CB; ++cb) {
            int col = wc + cb * 16 + lrow;
            short8v bh = *(const short8v*)(Wh + col * 40 + lk);
            short8v bl = *(const short8v*)(Wl + col * 40 + lk);
            acc[0][cb] = __builtin_amdgcn_mfma_f32_16x16x32_bf16(ah0, bh, acc[0][cb], 0, 0, 0);
            acc[0][cb] = __builtin_amdgcn_mfma_f32_16x16x32_bf16(ah0, bl, acc[0][cb], 0, 0, 0);
            acc[0][cb] = __builtin_amdgcn_mfma_f32_16x16x32_bf16(al0, bh, acc[0][cb], 0, 0, 0);
            acc[1][cb] = __builtin_amdgcn_mfma_f32_16x16x32_bf16(ah1, bh, acc[1][cb], 0, 0, 0);
            acc[1][cb] = __builtin_amdgcn_mfma_f32_16x16x32_bf16(ah1, bl, acc[1][cb], 0, 0, 0);
            acc[1][cb] = __builtin_amdgcn_mfma_f32_16x16x32_bf16(al1, bh, acc[1][cb], 0, 0, 0);
        }
    }
#pragma unroll
    for (int rb = 0; rb < 2; ++rb) {
#pragma unroll
        for (int reg = 0; reg < 4; ++reg) {
            int row = wr + rb * 16 + (l >> 4) * 4 + reg;
            int node = base + row;
            if (node < n) {
                float sc = SCALE ? dis[node] : 1.0f;
                unsigned short* cr = C + (size_t)node * KOUT;
#pragma unroll
                for (int cb = 0; cb < CB; ++cb) {
                    int col = wc + cb * 16 + lrow;
                    cr[col] = f2bf(acc[rb][cb][reg] * sc);
                }
            }
        }
    }
}

// ---------------- GCN agg over pre-scaled t' (t*dis), bf16 gather -> fp32 out -----------
template <bool RELU>
__global__ void k_agg128(const unsigned* __restrict__ t, const int* __restrict__ rptr,
                         const int* __restrict__ csr_src, const float* __restrict__ dis,
                         const float* __restrict__ bias, float* __restrict__ out, int n) {
    int wave = (blockIdx.x * blockDim.x + threadIdx.x) >> 6;
    int lane = threadIdx.x & 63;
    if (wave >= n) return;
    int dst = wave;
    float dd = dis[dst];
    float ax, ay;
    {
        unsigned u = t[(size_t)dst * 64 + lane];
        ax = lo_(u);
        ay = hi_(u);
    }
    int s = __builtin_amdgcn_readfirstlane(max(0, min(rptr[dst], EE)));
    int e = __builtin_amdgcn_readfirstlane(max(s, min(rptr[dst + 1], EE)));
    int j = s;
    for (; j + 8 <= e; j += 8) {
        int i0 = csr_src[j], i1 = csr_src[j + 1], i2 = csr_src[j + 2], i3 = csr_src[j + 3];
        int i4 = csr_src[j + 4], i5 = csr_src[j + 5], i6 = csr_src[j + 6], i7 = csr_src[j + 7];
        unsigned u0 = t[(size_t)i0 * 64 + lane], u1 = t[(size_t)i1 * 64 + lane];
        unsigned u2 = t[(size_t)i2 * 64 + lane], u3 = t[(size_t)i3 * 64 + lane];
        unsigned u4 = t[(size_t)i4 * 64 + lane], u5 = t[(size_t)i5 * 64 + lane];
        unsigned u6 = t[(size_t)i6 * 64 + lane], u7 = t[(size_t)i7 * 64 + lane];
        ax += (lo_(u0) + lo_(u1)) + (lo_(u2) + lo_(u3)) + (lo_(u4) + lo_(u5)) + (lo_(u6) + lo_(u7));
        ay += (hi_(u0) + hi_(u1)) + (hi_(u2) + hi_(u3)) + (hi_(u4) + hi_(u5)) + (hi_(u6) + hi_(u7));
    }
    for (; j + 4 <= e; j += 4) {
        int i0 = csr_src[j], i1 = csr_src[j + 1], i2 = csr_src[j + 2], i3 = csr_src[j + 3];
        unsigned u0 = t[(size_t)i0 * 64 + lane], u1 = t[(size_t)i1 * 64 + lane];
        unsigned u2 = t[(size_t)i2 * 64 + lane], u3 = t[(size_t)i3 * 64 + lane];
        ax += (lo_(u0) + lo_(u1)) + (lo_(u2) + lo_(u3));
        ay += (hi_(u0) + hi_(u1)) + (hi_(u2) + hi_(u3));
    }
    for (; j < e; ++j) {
        unsigned u0 = t[(size_t)csr_src[j] * 64 + lane];
        ax += lo_(u0);
        ay += hi_(u0);
    }
    float2 bv = *(const float2*)(bias + 2 * lane);
    float vx = ax * dd + bv.x;
    float vy = ay * dd + bv.y;
    if (RELU) { vx = fmaxf(vx, 0.f); vy = fmaxf(vy, 0.f); }
    *(float2*)(out + (size_t)dst * 128 + 2 * lane) = make_float2(vx, vy);
}

// F=64: half-wave per edge, explicit 4-batches
template <bool RELU>
__global__ void k_agg64(const unsigned* __restrict__ t, const int* __restrict__ rptr,
                        const int* __restrict__ csr_src, const float* __restrict__ dis,
                        const float* __restrict__ bias, float* __restrict__ out, int n) {
    int wave = (blockIdx.x * blockDim.x + threadIdx.x) >> 6;
    int lane = threadIdx.x & 63;
    if (wave >= n) return;
    int dst = wave;
    int half = lane >> 5, l32 = lane & 31;
    float dd = dis[dst];
    float ax = 0.f, ay = 0.f;
    if (!half) {
        unsigned u = t[(size_t)dst * 32 + l32];
        ax = lo_(u);
        ay = hi_(u);
    }
    int s = max(0, min(rptr[dst], EE));
    int e = max(s, min(rptr[dst + 1], EE));
    int cnt = e - s;
    int pairs = cnt >> 1;
    int p = 0;
    for (; p + 4 <= pairs; p += 4) {
        int jb = s + 2 * p + half;
        int i0 = csr_src[jb], i1 = csr_src[jb + 2], i2 = csr_src[jb + 4], i3 = csr_src[jb + 6];
        unsigned u0 = t[(size_t)i0 * 32 + l32], u1 = t[(size_t)i1 * 32 + l32];
        unsigned u2 = t[(size_t)i2 * 32 + l32], u3 = t[(size_t)i3 * 32 + l32];
        ax += (lo_(u0) + lo_(u1)) + (lo_(u2) + lo_(u3));
        ay += (hi_(u0) + hi_(u1)) + (hi_(u2) + hi_(u3));
    }
    for (; p < pairs; ++p) {
        int i0 = csr_src[s + 2 * p + half];
        unsigned u0 = t[(size_t)i0 * 32 + l32];
        ax += lo_(u0);
        ay += hi_(u0);
    }
    if ((cnt & 1) && !half) {
        unsigned u0 = t[(size_t)csr_src[e - 1] * 32 + l32];
        ax += lo_(u0);
        ay += hi_(u0);
    }
    ax += __shfl_down(ax, 32);
    ay += __shfl_down(ay, 32);
    if (!half) {
        float2 bv = *(const float2*)(bias + 2 * l32);
        float vx = ax * dd + bv.x;
        float vy = ay * dd + bv.y;
        if (RELU) { vx = fmaxf(vx, 0.f); vy = fmaxf(vy, 0.f); }
        *(float2*)(out + (size_t)dst * 64 + 2 * l32) = make_float2(vx, vy);
    }
}

// F=32: quarter-wave per edge, explicit 4-batches
template <bool RELU>
__global__ void k_agg32(const unsigned* __restrict__ t, const int* __restrict__ rptr,
                        const int* __restrict__ csr_src, const float* __restrict__ dis,
                        const float* __restrict__ bias, float* __restrict__ out, int n) {
    int wave = (blockIdx.x * blockDim.x + threadIdx.x) >> 6;
    int lane = threadIdx.x & 63;
    if (wave >= n) return;
    int dst = wave;
    int q = lane >> 4, l16 = lane & 15;
    float dd = dis[dst];
    float ax = 0.f, ay = 0.f;
    if (q == 0) {
        unsigned u = t[(size_t)dst * 16 + l16];
        ax = lo_(u);
        ay = hi_(u);
    }
    int s = max(0, min(rptr[dst], EE));
    int e = max(s, min(rptr[dst + 1], EE));
    int cnt = e - s;
    int quads = cnt >> 2;
    int p = 0;
    for (; p + 4 <= quads; p += 4) {
        int jb = s + 4 * p + q;
        int i0 = csr_src[jb], i1 = csr_src[jb + 4], i2 = csr_src[jb + 8], i3 = csr_src[jb + 12];
        unsigned u0 = t[(size_t)i0 * 16 + l16], u1 = t[(size_t)i1 * 16 + l16];
        unsigned u2 = t[(size_t)i2 * 16 + l16], u3 = t[(size_t)i3 * 16 + l16];
        ax += (lo_(u0) + lo_(u1)) + (lo_(u2) + lo_(u3));
        ay += (hi_(u0) + hi_(u1)) + (hi_(u2) + hi_(u3));
    }
    for (; p < quads; ++p) {
        int i0 = csr_src[s + 4 * p + q];
        unsigned u0 = t[(size_t)i0 * 16 + l16];
        ax += lo_(u0);
        ay += hi_(u0);
    }
    int rem = cnt - 4 * quads;
    if (q < rem) {
        unsigned u0 = t[(size_t)csr_src[s + 4 * quads + q] * 16 + l16];
        ax += lo_(u0);
        ay += hi_(u0);
    }
    ax += __shfl_down(ax, 32);
    ay += __shfl_down(ay, 32);
    ax += __shfl_down(ax, 16);
    ay += __shfl_down(ay, 16);
    if (q == 0) {
        float2 bv = *(const float2*)(bias + 2 * l16);
        float vx = ax * dd + bv.x;
        float vy = ay * dd + bv.y;
        if (RELU) { vx = fmaxf(vx, 0.f); vy = fmaxf(vy, 0.f); }
        *(float2*)(out + (size_t)dst * 32 + 2 * l16) = make_float2(vx, vy);
    }
}

// ---------------- GAT ----------------
__global__ void k_gat_vec(const unsigned* __restrict__ g, const float* __restrict__ a_src,
                          const float* __restrict__ a_dst, float* __restrict__ asrc,
                          float* __restrict__ adst, int n) {
    int i = blockIdx.x * 256 + threadIdx.x;
    if (i >= n) return;
    float s = 0.0f, d = 0.0f;
    const unsigned* gr = g + (size_t)i * 16;
#pragma unroll
    for (int k = 0; k < 16; ++k) {
        unsigned u = gr[k];
        float v0 = lo_(u), v1 = hi_(u);
        s += v0 * a_src[2 * k] + v1 * a_src[2 * k + 1];
        d += v0 * a_dst[2 * k] + v1 * a_dst[2 * k + 1];
    }
    asrc[i] = s;
    adst[i] = d;
}

__global__ void k_gat_agg(const unsigned* __restrict__ g, const int* __restrict__ rptr,
                          const int* __restrict__ csr_src, const float* __restrict__ asrc,
                          const float* __restrict__ adst, const float* __restrict__ gat_b,
                          float* __restrict__ out, int n) {
    int wave = (blockIdx.x * blockDim.x + threadIdx.x) >> 6;
    int lane = threadIdx.x & 63;
    if (wave >= n) return;
    int dst = wave;
    int q = lane >> 4, l16 = lane & 15;
    float ad = adst[dst];
    int s = max(0, min(rptr[dst], EE));
    int e = max(s, min(rptr[dst + 1], EE));
    float ax = 0.f, ay = 0.f, denom = 0.f;
    if (q == 0) {
        float w0 = __expf(fminf(leakyf_(asrc[dst] + ad), 80.f));
        unsigned u = g[(size_t)dst * 16 + l16];
        ax = lo_(u) * w0;
        ay = hi_(u) * w0;
        denom = w0;
    }
    int cnt = e - s;
    int quads = cnt >> 2;
    int p = 0;
    for (; p + 4 <= quads; p += 4) {
        int jb = s + 4 * p + q;
        int i0 = csr_src[jb], i1 = csr_src[jb + 4], i2 = csr_src[jb + 8], i3 = csr_src[jb + 12];
        float a0 = asrc[i0], a1 = asrc[i1], a2 = asrc[i2], a3 = asrc[i3];
        unsigned u0 = g[(size_t)i0 * 16 + l16], u1 = g[(size_t)i1 * 16 + l16];
        unsigned u2 = g[(size_t)i2 * 16 + l16], u3 = g[(size_t)i3 * 16 + l16];
        float w0 = __expf(fminf(leakyf_(a0 + ad), 80.f));
        float w1 = __expf(fminf(leakyf_(a1 + ad), 80.f));
        float w2 = __expf(fminf(leakyf_(a2 + ad), 80.f));
        float w3 = __expf(fminf(leakyf_(a3 + ad), 80.f));
        denom += (w0 + w1) + (w2 + w3);
        ax += lo_(u0) * w0 + lo_(u1) * w1 + lo_(u2) * w2 + lo_(u3) * w3;
        ay += hi_(u0) * w0 + hi_(u1) * w1 + hi_(u2) * w2 + hi_(u3) * w3;
    }
    for (; p < quads; ++p) {
        int i0 = csr_src[s + 4 * p + q];
        float wgt = __expf(fminf(leakyf_(asrc[i0] + ad), 80.f));
        unsigned u0 = g[(size_t)i0 * 16 + l16];
        denom += wgt;
        ax += lo_(u0) * wgt;
        ay += hi_(u0) * wgt;
    }
    int rem = cnt - 4 * quads;
    if (q < rem) {
        int i0 = csr_src[s + 4 * quads + q];
        float wgt = __expf(fminf(leakyf_(asrc[i0] + ad), 80.f));
        unsigned u0 = g[(size_t)i0 * 16 + l16];
        denom += wgt;
        ax += lo_(u0) * wgt;
        ay += hi_(u0) * wgt;
    }
    ax += __shfl_down(ax, 32);
    ay += __shfl_down(ay, 32);
    denom += __shfl_down(denom, 32);
    ax += __shfl_down(ax, 16);
    ay += __shfl_down(ay, 16);
    denom += __shfl_down(denom, 16);
    if (q == 0) {
        float r = rcp_(denom);
        float vx = fmaxf(ax * r + gat_b[2 * l16], 0.f);
        float vy = fmaxf(ay * r + gat_b[2 * l16 + 1], 0.f);
        *(float2*)(out + (size_t)dst * 32 + 2 * l16) = make_float2(vx, vy);
    }
}

// ---------------- LSTM gates via MFMA, transposed: C^T = W''@h^T ------------------------
// A-operand = gate rows (blocked: i rows 0..63, g 64..127, o 128..191); B-operand = nodes.
// C/D: col(lane&15) = node within wave's 16-node tile; row = gate-row. Lane's acc tiles
// m, m+4, m+8 hold (i,g,o) for the SAME j -> activation epilogue fully in-lane.
// Output: rbufT[jj][node] (transposed, coalesced stores).
__global__ __launch_bounds__(256) void k_gates_mfma(const float* __restrict__ h,
                                                    const unsigned short* __restrict__ wsg,
                                                    const float* __restrict__ wp,
                                                    float* __restrict__ rbufT, int n) {
    __shared__ unsigned short Ah[64 * 40];   // h hi: 5.1 KB
    __shared__ unsigned short Al[64 * 40];   // h lo: 5.1 KB
    __shared__ unsigned short Wh[192 * 40];  // 15.4 KB
    __shared__ unsigned short Wl[192 * 40];  // 15.4 KB
    __shared__ float bI[64], bG[64], bO[64], gs[64], gb[64];
    int t = threadIdx.x;
    int dir = blockIdx.y;
    int l = t & 63, w = t >> 6;
    int base = blockIdx.x * 64;
    // stage h hi/lo (64 rows x 32 fp32 = 512 float4 chunks)
#pragma unroll
    for (int p = 0; p < 2; ++p) {
        int c = p * 256 + t;
        int nd = c >> 3, ko = (c & 7) * 4;
        int node = min(base + nd, n - 1);
        float4 v = *(const float4*)(h + (size_t)node * 32 + ko);
        ushort4 hi, lo;
        split4(v, hi, lo);
        *(ushort4*)(Ah + nd * 40 + ko) = hi;
        *(ushort4*)(Al + nd * 40 + ko) = lo;
    }
    // stage W'' hi/lo (192 rows x 32 k = 768 uint4 chunks each)
    {
        const unsigned short* sh = wsg + (size_t)(dir * 2 + 0) * 192 * 32;
        const unsigned short* sl = wsg + (size_t)(dir * 2 + 1) * 192 * 32;
#pragma unroll
        for (int p = 0; p < 3; ++p) {
            int c = p * 256 + t;
            int row = c >> 2, ko = (c & 3) * 8;
            *(uint4*)(Wh + row * 40 + ko) = *(const uint4*)(sh + (size_t)row * 32 + ko);
            *(uint4*)(Wl + row * 40 + ko) = *(const uint4*)(sl + (size_t)row * 32 + ko);
        }
    }
    if (t < 64) {
        const float* bi_ = wp + (dir ? OFF_BIHB : OFF_BIHF);
        const float* bh_ = wp + (dir ? OFF_BHHB : OFF_BHHF);
        bI[t] = bi_[t] + bh_[t];
        bG[t] = bi_[128 + t] + bh_[128 + t];
        bO[t] = bi_[192 + t] + bh_[192 + t];
        gs[t] = wp[OFF_GAMMA + dir * 64 + t] * rsqrtf(1.0f + 1e-5f);
        gb[t] = wp[OFF_BETA + dir * 64 + t];
    }
    __syncthreads();
    int lrow = l & 15, lk = (l >> 4) * 8;
    short8v hh = *(const short8v*)(Ah + (w * 16 + lrow) * 40 + lk);
    short8v hl = *(const short8v*)(Al + (w * 16 + lrow) * 40 + lk);
    f32x4 acc[12];
#pragma unroll
    for (int m = 0; m < 12; ++m) acc[m] = (f32x4){0.f, 0.f, 0.f, 0.f};
#pragma unroll
    for (int m = 0; m < 12; ++m) {
        short8v wh = *(const short8v*)(Wh + (m * 16 + lrow) * 40 + lk);
        short8v wl = *(const short8v*)(Wl + (m * 16 + lrow) * 40 + lk);
        acc[m] = __builtin_amdgcn_mfma_f32_16x16x32_bf16(wh, hh, acc[m], 0, 0, 0);
        acc[m] = __builtin_amdgcn_mfma_f32_16x16x32_bf16(wl, hh, acc[m], 0, 0, 0);
        acc[m] = __builtin_amdgcn_mfma_f32_16x16x32_bf16(wh, hl, acc[m], 0, 0, 0);
    }
    int node = base + w * 16 + lrow;
    if (node < n) {
#pragma unroll
        for (int m = 0; m < 4; ++m) {
#pragma unroll
            for (int reg = 0; reg < 4; ++reg) {
                int j = 16 * m + (l >> 4) * 4 + reg;
                float iv = acc[m][reg] + bI[j];
                float gv = acc[m + 4][reg] + bG[j];
                float ov = acc[m + 8][reg] + bO[j];
                float v = sigmoidf_(ov) * tanhf_(sigmoidf_(iv) * tanhf_(gv));
                rbufT[(size_t)(dir * 64 + j) * NN + node] = v * gs[j] + gb[j];
            }
        }
    }
}

// ---------------- FC 128->10 + output cast (reads transposed rbufT) ---------------------
__global__ __launch_bounds__(256) void k_fc(const float* __restrict__ rbufT,
                                            const float* __restrict__ wp,
                                            void* __restrict__ out,
                                            const int* __restrict__ flags, int n) {
    __shared__ float rs[64 * 129];  // 33 KB, stride 129 -> conflict-free
    __shared__ float ps[4 * 640];   // 10 KB
    int t = threadIdx.x;
    int base = blockIdx.x * 64;
    // stage: rs[node][jj] from rbufT[jj][node]; lanes cover 64 consecutive nodes per jj
    for (int i = t; i < 8192; i += 256) {
        int jj = i >> 6, nd = i & 63;
        int node = min(base + nd, n - 1);
        rs[nd * 129 + jj] = rbufT[(size_t)jj * NN + node];
    }
    __syncthreads();
    {
        int nd = t & 63, quarter = t >> 6;  // quarter wave-uniform -> fcw scalar loads
        const float* fcw = wp + OFF_FCW;
        int jbase = quarter * 32;
        float p10[10];
#pragma unroll
        for (int c = 0; c < 10; ++c) p10[c] = 0.f;
#pragma unroll 4
        for (int k = 0; k < 32; ++k) {
            float r = rs[nd * 129 + jbase + k];
#pragma unroll
            for (int c = 0; c < 10; ++c) p10[c] += r * fcw[c * 128 + jbase + k];
        }
#pragma unroll
        for (int c = 0; c < 10; ++c) ps[quarter * 640 + nd * 10 + c] = p10[c];
    }
    __syncthreads();
    bool f32o = flags[0] != 0;
    for (int idx = t; idx < 640; idx += 256) {
        int gnode = base + idx / 10;
        if (gnode < n) {
            int c = idx % 10;
            float v = wp[OFF_FCB + c] + ps[idx] + ps[640 + idx] + ps[1280 + idx] + ps[1920 + idx];
            if (f32o) ((float*)out)[(size_t)base * 10 + idx] = v;
            else ((unsigned short*)out)[(size_t)base * 10 + idx] = f2bf(v);
        }
    }
}

// ---------------- launch ----------------
extern "C" void kernel_launch(void* const* d_in, const int* in_sizes, int n_in,
                              void* d_out, int out_size, void* d_ws, size_t ws_size,
                              hipStream_t stream) {
    const int N = NN;

    char* w = (char*)d_ws;
    auto alloc = [&](size_t bytes) {
        void* p = (void*)w;
        w += (bytes + 255) & ~(size_t)255;
        return p;
    };
    int* flags = (int*)alloc(256);
    float* wpool = (float*)alloc((size_t)WTOTAL * 4);
    unsigned short* wsplit = (unsigned short*)alloc(65536);   // W1 hi/lo
    unsigned short* ws2 = (unsigned short*)alloc(32768);      // W2 hi/lo
    unsigned short* ws3 = (unsigned short*)alloc(8192);       // W3 hi/lo
    unsigned short* wsgat = (unsigned short*)alloc(4096);     // GATW hi/lo
    unsigned short* wsg = (unsigned short*)alloc(49152);      // LSTM gate W'' hi/lo
    float* dis = (float*)alloc((size_t)N * 4);
    int* rptr = (int*)alloc((size_t)(N + 1) * 4);
    int* csr_src = (int*)alloc((size_t)EE * 4);
    unsigned* gh = (unsigned*)alloc((size_t)NBK * 256 * 4);
    unsigned* gh2 = (unsigned*)alloc((size_t)NBK * 256 * 4);
    int* bb = (int*)alloc(1024);
    int2* ebkt = (int2*)alloc((size_t)EE * 8);
    float* asrc = (float*)alloc((size_t)N * 4);
    float* adst = (float*)alloc((size_t)N * 4);
    unsigned* bufT = (unsigned*)alloc((size_t)N * 64 * 4);  // bf16 N x 128
    float* bufH = (float*)alloc((size_t)N * 128 * 4);       // fp32 N x 128
    float* rbufT = (float*)alloc((size_t)N * 128 * 4);      // fp32 [128][N] (BN'd LSTM out, transposed)

    WSrc ws_srcs;
    for (int i = 0; i < 20; ++i) ws_srcs.p[i] = d_in[2 + i];

    const int NB = (N + 255) / 256;
    const int AGG = (N + 3) / 4;
    const int TMB = (N + 63) / 64;
    const int WB = (WTOTAL + 255) / 256;

    k_detect<<<1, 256, 0, stream>>>((const unsigned short*)d_in[0],
                                    (const unsigned int*)d_in[1], flags);
    k_cvt_w<<<WB, 256, 0, stream>>>(ws_srcs, wpool, flags, WTOTAL);
    k_prep_w1<<<64, 256, 0, stream>>>(wpool, wsplit);
    k_prep_ws<128, 64><<<32, 256, 0, stream>>>(wpool + OFF_W2, ws2);
    k_prep_ws<64, 32><<<8, 256, 0, stream>>>(wpool + OFF_W3, ws3);
    k_prep_ws<32, 32><<<4, 256, 0, stream>>>(wpool + OFF_GATW, wsgat);
    k_prep_wg<<<48, 256, 0, stream>>>(wpool, wsg);
    // bucketed CSR build
    k_hist<<<NBK, 256, 0, stream>>>(d_in[1], gh, flags);
    k_bscan<<<1, 256, 0, stream>>>(gh, gh2, bb, rptr);
    k_scatter<<<NBK, 256, 0, stream>>>(d_in[1], gh2, bb, ebkt, flags);
    k_bucket_csr<<<NBK, 256, 0, stream>>>(ebkt, bb, rptr, dis, csr_src);

    // GCN 1 (x -> t1' = (x@W1)*dis, bf16): MFMA for BOTH input dtypes (flag-gated)
    k_gcn1_mfma<0><<<TMB, 256, 0, stream>>>(d_in[0], wsplit, bufT, N, flags, dis);
    k_gcn1_mfma<1><<<TMB, 256, 0, stream>>>(d_in[0], wsplit, bufT, N, flags, dis);
    k_agg128<true><<<AGG, 256, 0, stream>>>(bufT, rptr, csr_src, dis, wpool + OFF_B1, bufH, N);
    // GCN 2 (MFMA)
    k_mm_mfma<128, 64, true><<<TMB, 256, 0, stream>>>(bufH, ws2, (unsigned short*)bufT, N, dis);
    k_agg64<true><<<AGG, 256, 0, stream>>>(bufT, rptr, csr_src, dis, wpool + OFF_B2, bufH, N);
    // GCN 3 (MFMA)
    k_mm_mfma<64, 32, true><<<TMB, 256, 0, stream>>>(bufH, ws3, (unsigned short*)bufT, N, dis);
    k_agg32<false><<<AGG, 256, 0, stream>>>(bufT, rptr, csr_src, dis, wpool + OFF_B3, bufH, N);
    // GAT (MFMA, unscaled)
    k_mm_mfma<32, 32, false><<<TMB, 256, 0, stream>>>(bufH, wsgat, (unsigned short*)bufT, N, dis);
    k_gat_vec<<<NB, 256, 0, stream>>>(bufT, wpool + OFF_GAS, wpool + OFF_GAD, asrc, adst, N);
    k_gat_agg<<<AGG, 256, 0, stream>>>(bufT, rptr, csr_src, asrc, adst, wpool + OFF_GAB, bufH, N);
    // LSTM gates via MFMA (transposed output), then FC
    k_gates_mfma<<<dim3(TMB, 2), 256, 0, stream>>>(bufH, wsg, wpool, rbufT, N);
    k_fc<<<TMB, 256, 0, stream>>>(rbufT, wpool, d_out, flags, N);
}

// Round 11
// 333.321 us; speedup vs baseline: 1.1411x; 1.0609x over previous
//
#include <hip/hip_runtime.h>
#include <hip/hip_bf16.h>
#include <math.h>

typedef __hip_bfloat16 bf16;
typedef __attribute__((ext_vector_type(8))) short short8v;   // 8 bf16 = 4 VGPRs (MFMA A/B frag)
typedef __attribute__((ext_vector_type(4))) float f32x4;     // MFMA C/D frag

#define NN 50000
#define EE 800000
#define EPB 4096   // edges per block (hist/scatter)
#define NBK 196    // dst buckets = ceil(NN/256); also blocks for hist/scatter
#define BCAP 6144  // max edges per bucket (mean 4096, sd ~64)

__device__ __forceinline__ float b2f(bf16 v) { return __bfloat162float(v); }
__device__ __forceinline__ float rcp_(float x) { return __builtin_amdgcn_rcpf(x); }
__device__ __forceinline__ float sigmoidf_(float x) { return rcp_(1.0f + __expf(-x)); }
__device__ __forceinline__ float tanhf_(float x) {
    float xx = fminf(fmaxf(x, -15.0f), 15.0f);
    float e = __expf(2.0f * xx);
    return (e - 1.0f) * rcp_(e + 1.0f);
}
__device__ __forceinline__ float leakyf_(float x) { return x > 0.0f ? x : 0.2f * x; }
__device__ __forceinline__ unsigned short f2bf(float f) {
    unsigned u = __float_as_uint(f);
    unsigned r = (u + 0x7FFFu + ((u >> 16) & 1u)) >> 16;
    return (unsigned short)r;
}
__device__ __forceinline__ unsigned pack2(float a, float b) {
    return (unsigned)f2bf(a) | ((unsigned)f2bf(b) << 16);
}
__device__ __forceinline__ float lo_(unsigned u) { return __uint_as_float(u << 16); }
__device__ __forceinline__ float hi_(unsigned u) { return __uint_as_float(u & 0xFFFF0000u); }
__device__ __forceinline__ void split4(float4 v, ushort4& hi, ushort4& lo) {
    hi.x = f2bf(v.x); lo.x = f2bf(v.x - __uint_as_float((unsigned)hi.x << 16));
    hi.y = f2bf(v.y); lo.y = f2bf(v.y - __uint_as_float((unsigned)hi.y << 16));
    hi.z = f2bf(v.z); lo.z = f2bf(v.z - __uint_as_float((unsigned)hi.z << 16));
    hi.w = f2bf(v.w); lo.w = f2bf(v.w - __uint_as_float((unsigned)hi.w << 16));
}

// weight-pool element offsets (fp32 pool in ws)
#define OFF_W1 0
#define OFF_B1 16384
#define OFF_W2 16512
#define OFF_B2 24704
#define OFF_W3 24768
#define OFF_B3 26816
#define OFF_GATW 26848
#define OFF_GAS 27872
#define OFF_GAD 27904
#define OFF_GAB 27936
#define OFF_WIHF 27968
#define OFF_BIHF 36160
#define OFF_BHHF 36416
#define OFF_WIHB 36672
#define OFF_BIHB 44864
#define OFF_BHHB 45120
#define OFF_GAMMA 45376
#define OFF_BETA 45504
#define OFF_FCW 45632
#define OFF_FCB 46912
#define WTOTAL 46922

struct WSrc { const void* p[20]; };

// ---------------- dtype detection ----------------
__global__ void k_detect(const unsigned short* __restrict__ xraw,
                         const unsigned int* __restrict__ eraw, int* __restrict__ flags) {
    __shared__ int f32f, i64f;
    int t = threadIdx.x;
    if (t == 0) { f32f = 0; i64f = 1; }
    __syncthreads();
    for (int i = t; i < 4096; i += 256) {
        unsigned short u = xraw[i];
        int ex = (u >> 7) & 0xFF;
        if (ex >= 0xC0) atomicOr(&f32f, 1);
        if (eraw[2 * i + 1] != 0u) atomicAnd(&i64f, 0);
    }
    __syncthreads();
    if (t == 0) { flags[0] = f32f; flags[1] = i64f; }
}

// ---------------- weight conversion into fp32 pool ----------------
__global__ void k_cvt_w(WSrc srcs, float* __restrict__ dst, const int* __restrict__ flags,
                        int total) {
    constexpr int WOFF[21] = {OFF_W1,   OFF_B1,   OFF_W2,   OFF_B2,   OFF_W3,   OFF_B3,
                              OFF_GATW, OFF_GAS,  OFF_GAD,  OFF_GAB,  OFF_WIHF, OFF_BIHF,
                              OFF_BHHF, OFF_WIHB, OFF_BIHB, OFF_BHHB, OFF_GAMMA, OFF_BETA,
                              OFF_FCW,  OFF_FCB,  WTOTAL};
    int i = blockIdx.x * 256 + threadIdx.x;
    if (i >= total) return;
    int tn = 0;
#pragma unroll
    for (int j = 1; j < 20; ++j)
        if (i >= WOFF[j]) tn = j;
    int local = i - WOFF[tn];
    if (flags[0]) dst[i] = ((const float*)srcs.p[tn])[local];
    else dst[i] = b2f(((const bf16*)srcs.p[tn])[local]);
}

// ---------------- ALL weight hi/lo splits in one kernel ---------------------------------
// ranges: [0,16384) W1 128x128 | [16384,24576) W2 128x64 | [24576,26624) W3 64x32 |
//         [26624,27648) GAT 32x32 | [27648,39936) LSTM gates (blocked rows)
__global__ void k_prep_all(const float* __restrict__ wp, unsigned short* __restrict__ w1,
                           unsigned short* __restrict__ w2, unsigned short* __restrict__ w3,
                           unsigned short* __restrict__ wgat, unsigned short* __restrict__ wg) {
    int i = blockIdx.x * 256 + threadIdx.x;
    if (i < 16384) {
        int k = i >> 7, col = i & 127;
        float v = wp[OFF_W1 + k * 128 + col];
        unsigned short hi = f2bf(v);
        unsigned short lo = f2bf(v - __uint_as_float((unsigned)hi << 16));
        int kt = k >> 5, kk = k & 31;
        w1[((size_t)(kt * 2 + 0) * 128 + col) * 32 + kk] = hi;
        w1[((size_t)(kt * 2 + 1) * 128 + col) * 32 + kk] = lo;
    } else if (i < 24576) {
        int j = i - 16384;
        int k = j >> 6, col = j & 63;
        float v = wp[OFF_W2 + k * 64 + col];
        unsigned short hi = f2bf(v);
        unsigned short lo = f2bf(v - __uint_as_float((unsigned)hi << 16));
        int kt = k >> 5, kk = k & 31;
        w2[((size_t)(kt * 2 + 0) * 64 + col) * 32 + kk] = hi;
        w2[((size_t)(kt * 2 + 1) * 64 + col) * 32 + kk] = lo;
    } else if (i < 26624) {
        int j = i - 24576;
        int k = j >> 5, col = j & 31;
        float v = wp[OFF_W3 + k * 32 + col];
        unsigned short hi = f2bf(v);
        unsigned short lo = f2bf(v - __uint_as_float((unsigned)hi << 16));
        int kt = k >> 5, kk = k & 31;
        w3[((size_t)(kt * 2 + 0) * 32 + col) * 32 + kk] = hi;
        w3[((size_t)(kt * 2 + 1) * 32 + col) * 32 + kk] = lo;
    } else if (i < 27648) {
        int j = i - 26624;
        int k = j >> 5, col = j & 31;
        float v = wp[OFF_GATW + k * 32 + col];
        unsigned short hi = f2bf(v);
        unsigned short lo = f2bf(v - __uint_as_float((unsigned)hi << 16));
        int kk = k & 31;
        wgat[((size_t)col) * 32 + kk] = hi;
        wgat[((size_t)(32 + col)) * 32 + kk] = lo;
    } else if (i < 39936) {
        int j = i - 27648;
        int dir = j / 6144, r2 = j % 6144;
        int row = r2 >> 5, k = r2 & 31;
        int gate = row >> 6, jj = row & 63;
        int srcrow = jj + (gate == 1 ? 128 : (gate == 2 ? 192 : 0));
        const float* W = wp + (dir ? OFF_WIHB : OFF_WIHF);
        float v = W[(size_t)srcrow * 32 + k];
        unsigned short hi = f2bf(v);
        unsigned short lo = f2bf(v - __uint_as_float((unsigned)hi << 16));
        wg[((size_t)(dir * 2 + 0) * 192 + row) * 32 + k] = hi;
        wg[((size_t)(dir * 2 + 1) * 192 + row) * 32 + k] = lo;
    }
}

// ---------------- bucketed CSR build ----------------
__global__ __launch_bounds__(256) void k_hist(const void* __restrict__ eraw,
                                              unsigned* __restrict__ gh,
                                              const int* __restrict__ flags) {
    __shared__ int h[256];
    int t = threadIdx.x, b = blockIdx.x;
    h[t] = 0;
    __syncthreads();
    int e0 = b * EPB;
    bool i64 = flags[1] != 0;
    for (int i = t; i < EPB; i += 256) {
        int e = e0 + i;
        if (e < EE) {
            int d = i64 ? (int)((const long long*)eraw)[EE + e] : ((const int*)eraw)[EE + e];
            d = min(max(d, 0), NN - 1);
            atomicAdd(&h[d >> 8], 1);
        }
    }
    __syncthreads();
    gh[b * 256 + t] = (unsigned)h[t];
}

__global__ __launch_bounds__(256) void k_bscan(const unsigned* __restrict__ gh,
                                               unsigned* __restrict__ gh2,
                                               int* __restrict__ bb, int* __restrict__ rptr) {
    __shared__ int s[256];
    int t = threadIdx.x;
    unsigned run = 0;
    for (int blk = 0; blk < NBK; ++blk) {
        unsigned v = gh[blk * 256 + t];
        gh2[blk * 256 + t] = run;  // within-bucket offset of this edge-block
        run += v;
    }
    s[t] = (int)run;
    __syncthreads();
    for (int o = 1; o < 256; o <<= 1) {
        int x = (t >= o) ? s[t - o] : 0;
        __syncthreads();
        s[t] += x;
        __syncthreads();
    }
    bb[t] = s[t] - (int)run;  // exclusive: bucket base (bb[196] lands on EE)
    if (t == 0) rptr[NN] = EE;
}

__global__ __launch_bounds__(256) void k_scatter(const void* __restrict__ eraw,
                                                 const unsigned* __restrict__ gh2,
                                                 const int* __restrict__ bb,
                                                 int2* __restrict__ ebkt,
                                                 const int* __restrict__ flags) {
    __shared__ unsigned cur[256];
    int t = threadIdx.x, b = blockIdx.x;
    cur[t] = gh2[b * 256 + t] + (unsigned)bb[t];
    __syncthreads();
    int e0 = b * EPB;
    bool i64 = flags[1] != 0;
    for (int i = t; i < EPB; i += 256) {
        int e = e0 + i;
        if (e < EE) {
            int sn, d;
            if (i64) {
                sn = (int)((const long long*)eraw)[e];
                d = (int)((const long long*)eraw)[EE + e];
            } else {
                sn = ((const int*)eraw)[e];
                d = ((const int*)eraw)[EE + e];
            }
            sn = min(max(sn, 0), NN - 1);
            d = min(max(d, 0), NN - 1);
            unsigned pos = atomicAdd(&cur[d >> 8], 1u);
            if (pos < (unsigned)EE) ebkt[pos] = make_int2(sn, d);
        }
    }
}

__global__ __launch_bounds__(256) void k_bucket_csr(const int2* __restrict__ ebkt,
                                                    const int* __restrict__ bb,
                                                    int* __restrict__ rptr,
                                                    float* __restrict__ dis,
                                                    int* __restrict__ csr_src) {
    __shared__ int hist[256];
    __shared__ int excl[256];
    __shared__ int cur[256];
    __shared__ int sorted[BCAP];
    int t = threadIdx.x, b = blockIdx.x;
    int s0 = bb[b], s1 = bb[b + 1];
    int len = min(s1 - s0, BCAP);
    hist[t] = 0;
    __syncthreads();
    for (int i = t; i < len; i += 256) atomicAdd(&hist[ebkt[s0 + i].y & 255], 1);
    __syncthreads();
    int v = hist[t];
    excl[t] = v;
    __syncthreads();
    for (int o = 1; o < 256; o <<= 1) {
        int x = (t >= o) ? excl[t - o] : 0;
        __syncthreads();
        excl[t] += x;
        __syncthreads();
    }
    int loc = excl[t] - v;  // local exclusive offset
    int node = b * 256 + t;
    if (node < NN) {
        rptr[node] = s0 + loc;
        dis[node] = rsqrtf((float)(v + 1));
    }
    cur[t] = loc;
    __syncthreads();
    for (int i = t; i < len; i += 256) {
        int2 p = ebkt[s0 + i];
        int pos = atomicAdd(&cur[p.y & 255], 1);
        if (pos < BCAP) sorted[pos] = p.x;
    }
    __syncthreads();
    for (int i = t; i < len; i += 256) csr_src[s0 + i] = sorted[i];
}

// ---------------- GCN1 via MFMA (both input dtypes, split-precision) --------------------
template <int MODE>
__global__ __launch_bounds__(256) void k_gcn1_mfma(const void* __restrict__ A,
                                                   const unsigned short* __restrict__ wsplit,
                                                   unsigned* __restrict__ C, int n,
                                                   const int* __restrict__ flags,
                                                   const float* __restrict__ dis) {
    if (flags[0] != MODE) return;
    __shared__ unsigned short Ah[64 * 136];                   // 17.4 KB
    __shared__ unsigned short Al[MODE ? 64 * 136 : 4];        // 17.4 KB (MODE 1 only)
    __shared__ unsigned short Wh[128 * 40];                   // 10.2 KB
    __shared__ unsigned short Wl[128 * 40];                   // 10.2 KB
    int t = threadIdx.x;
    int l = t & 63, w = t >> 6;
    int base = blockIdx.x * 64;
    if constexpr (MODE == 0) {
#pragma unroll
        for (int p = 0; p < 4; ++p) {
            int c = p * 256 + t;
            int nd = c >> 4, ko = (c & 15) * 8;
            int node = min(base + nd, n - 1);
            uint4 v = *(const uint4*)((const unsigned short*)A + (size_t)node * 128 + ko);
            *(uint4*)(Ah + nd * 136 + ko) = v;
        }
    } else {
#pragma unroll
        for (int p = 0; p < 8; ++p) {
            int c = p * 256 + t;
            int nd = c >> 5, ko = (c & 31) * 4;
            int node = min(base + nd, n - 1);
            float4 v = *(const float4*)((const float*)A + (size_t)node * 128 + ko);
            ushort4 hi, lo;
            split4(v, hi, lo);
            *(ushort4*)(Ah + nd * 136 + ko) = hi;
            *(ushort4*)(Al + nd * 136 + ko) = lo;
        }
    }
    int wr = (w >> 1) * 32, wc = (w & 1) * 64;
    int lrow = l & 15, lk = (l >> 4) * 8;
    f32x4 acc[2][4];
#pragma unroll
    for (int rb = 0; rb < 2; ++rb)
#pragma unroll
        for (int cb = 0; cb < 4; ++cb) acc[rb][cb] = (f32x4){0.f, 0.f, 0.f, 0.f};
    for (int kt = 0; kt < 4; ++kt) {
        __syncthreads();
#pragma unroll
        for (int p = 0; p < 2; ++p) {
            int c = p * 256 + t;
            int col = c >> 2, ko = (c & 3) * 8;
            *(uint4*)(Wh + col * 40 + ko) =
                *(const uint4*)(wsplit + ((size_t)(kt * 2 + 0) * 128 + col) * 32 + ko);
            *(uint4*)(Wl + col * 40 + ko) =
                *(const uint4*)(wsplit + ((size_t)(kt * 2 + 1) * 128 + col) * 32 + ko);
        }
        __syncthreads();
        short8v ah0 = *(const short8v*)(Ah + (wr + lrow) * 136 + kt * 32 + lk);
        short8v ah1 = *(const short8v*)(Ah + (wr + 16 + lrow) * 136 + kt * 32 + lk);
        short8v al0, al1;
        if constexpr (MODE == 1) {
            al0 = *(const short8v*)(Al + (wr + lrow) * 136 + kt * 32 + lk);
            al1 = *(const short8v*)(Al + (wr + 16 + lrow) * 136 + kt * 32 + lk);
        }
#pragma unroll
        for (int cb = 0; cb < 4; ++cb) {
            int col = wc + cb * 16 + lrow;
            short8v bh = *(const short8v*)(Wh + col * 40 + lk);
            short8v bl = *(const short8v*)(Wl + col * 40 + lk);
            acc[0][cb] = __builtin_amdgcn_mfma_f32_16x16x32_bf16(ah0, bh, acc[0][cb], 0, 0, 0);
            acc[0][cb] = __builtin_amdgcn_mfma_f32_16x16x32_bf16(ah0, bl, acc[0][cb], 0, 0, 0);
            acc[1][cb] = __builtin_amdgcn_mfma_f32_16x16x32_bf16(ah1, bh, acc[1][cb], 0, 0, 0);
            acc[1][cb] = __builtin_amdgcn_mfma_f32_16x16x32_bf16(ah1, bl, acc[1][cb], 0, 0, 0);
            if constexpr (MODE == 1) {
                acc[0][cb] = __builtin_amdgcn_mfma_f32_16x16x32_bf16(al0, bh, acc[0][cb], 0, 0, 0);
                acc[1][cb] = __builtin_amdgcn_mfma_f32_16x16x32_bf16(al1, bh, acc[1][cb], 0, 0, 0);
            }
        }
    }
#pragma unroll
    for (int rb = 0; rb < 2; ++rb) {
#pragma unroll
        for (int reg = 0; reg < 4; ++reg) {
            int row = wr + rb * 16 + (l >> 4) * 4 + reg;
            int node = base + row;
            if (node < n) {
                float sc = dis[node];
                unsigned short* cr = (unsigned short*)C + (size_t)node * 128;
#pragma unroll
                for (int cb = 0; cb < 4; ++cb) {
                    int col = wc + cb * 16 + lrow;
                    cr[col] = f2bf(acc[rb][cb][reg] * sc);
                }
            }
        }
    }
}

// ---------------- generic MFMA GEMM: C(bf16[KOUT]) = A(fp32[KIN]) @ W, split-precision --
template <int KIN, int KOUT, bool SCALE>
__global__ __launch_bounds__(256) void k_mm_mfma(const float* __restrict__ A,
                                                 const unsigned short* __restrict__ wsplit,
                                                 unsigned short* __restrict__ C, int n,
                                                 const float* __restrict__ dis) {
    constexpr int AST = KIN + 8;
    constexpr int KT = KIN / 32;
    constexpr int CB = KOUT / 32;  // col-blocks per wave (KOUT=64 -> 2, 32 -> 1)
    __shared__ unsigned short Ah[64 * AST];
    __shared__ unsigned short Al[64 * AST];
    __shared__ unsigned short Wh[KOUT * 40];
    __shared__ unsigned short Wl[KOUT * 40];
    int t = threadIdx.x;
    int l = t & 63, w = t >> 6;
    int base = blockIdx.x * 64;
#pragma unroll
    for (int p = 0; p < KIN / 16; ++p) {
        int c = p * 256 + t;  // 64*KIN/4 float4 chunks
        int nd = c / (KIN / 4), ko = (c % (KIN / 4)) * 4;
        int node = min(base + nd, n - 1);
        float4 v = *(const float4*)(A + (size_t)node * KIN + ko);
        ushort4 hi, lo;
        split4(v, hi, lo);
        *(ushort4*)(Ah + nd * AST + ko) = hi;
        *(ushort4*)(Al + nd * AST + ko) = lo;
    }
    int wr = (w >> 1) * 32, wc = (w & 1) * (KOUT / 2);
    int lrow = l & 15, lk = (l >> 4) * 8;
    f32x4 acc[2][CB];
#pragma unroll
    for (int rb = 0; rb < 2; ++rb)
#pragma unroll
        for (int cb = 0; cb < CB; ++cb) acc[rb][cb] = (f32x4){0.f, 0.f, 0.f, 0.f};
    for (int kt = 0; kt < KT; ++kt) {
        __syncthreads();
        for (int c = t; c < KOUT * 4; c += 256) {  // uint4 chunks of 8 bf16
            int col = c >> 2, ko = (c & 3) * 8;
            *(uint4*)(Wh + col * 40 + ko) =
                *(const uint4*)(wsplit + ((size_t)(kt * 2 + 0) * KOUT + col) * 32 + ko);
            *(uint4*)(Wl + col * 40 + ko) =
                *(const uint4*)(wsplit + ((size_t)(kt * 2 + 1) * KOUT + col) * 32 + ko);
        }
        __syncthreads();
        short8v ah0 = *(const short8v*)(Ah + (wr + lrow) * AST + kt * 32 + lk);
        short8v ah1 = *(const short8v*)(Ah + (wr + 16 + lrow) * AST + kt * 32 + lk);
        short8v al0 = *(const short8v*)(Al + (wr + lrow) * AST + kt * 32 + lk);
        short8v al1 = *(const short8v*)(Al + (wr + 16 + lrow) * AST + kt * 32 + lk);
#pragma unroll
        for (int cb = 0; cb < CB; ++cb) {
            int col = wc + cb * 16 + lrow;
            short8v bh = *(const short8v*)(Wh + col * 40 + lk);
            short8v bl = *(const short8v*)(Wl + col * 40 + lk);
            acc[0][cb] = __builtin_amdgcn_mfma_f32_16x16x32_bf16(ah0, bh, acc[0][cb], 0, 0, 0);
            acc[0][cb] = __builtin_amdgcn_mfma_f32_16x16x32_bf16(ah0, bl, acc[0][cb], 0, 0, 0);
            acc[0][cb] = __builtin_amdgcn_mfma_f32_16x16x32_bf16(al0, bh, acc[0][cb], 0, 0, 0);
            acc[1][cb] = __builtin_amdgcn_mfma_f32_16x16x32_bf16(ah1, bh, acc[1][cb], 0, 0, 0);
            acc[1][cb] = __builtin_amdgcn_mfma_f32_16x16x32_bf16(ah1, bl, acc[1][cb], 0, 0, 0);
            acc[1][cb] = __builtin_amdgcn_mfma_f32_16x16x32_bf16(al1, bh, acc[1][cb], 0, 0, 0);
        }
    }
#pragma unroll
    for (int rb = 0; rb < 2; ++rb) {
#pragma unroll
        for (int reg = 0; reg < 4; ++reg) {
            int row = wr + rb * 16 + (l >> 4) * 4 + reg;
            int node = base + row;
            if (node < n) {
                float sc = SCALE ? dis[node] : 1.0f;
                unsigned short* cr = C + (size_t)node * KOUT;
#pragma unroll
                for (int cb = 0; cb < CB; ++cb) {
                    int col = wc + cb * 16 + lrow;
                    cr[col] = f2bf(acc[rb][cb][reg] * sc);
                }
            }
        }
    }
}

// ---------------- GAT projection (32x32 MFMA) fused with a_src/a_dst dots ---------------
// Same layout as k_mm_mfma<32,32,false>; epilogue additionally parks bf16-rounded g in
// gsh[64][33] and a 64-thread phase computes asrc/adst (matches old k_gat_vec bit-wise:
// dots taken over the bf16-rounded values).
__global__ __launch_bounds__(256) void k_mm_gat(const float* __restrict__ A,
                                                const unsigned short* __restrict__ wsplit,
                                                unsigned short* __restrict__ C, int n,
                                                const float* __restrict__ wp,
                                                float* __restrict__ asrc,
                                                float* __restrict__ adst) {
    __shared__ unsigned short Ah[64 * 40];
    __shared__ unsigned short Al[64 * 40];
    __shared__ unsigned short Wh[32 * 40];
    __shared__ unsigned short Wl[32 * 40];
    __shared__ float gsh[64 * 33];
    int t = threadIdx.x;
    int l = t & 63, w = t >> 6;
    int base = blockIdx.x * 64;
#pragma unroll
    for (int p = 0; p < 2; ++p) {
        int c = p * 256 + t;  // 512 float4 chunks
        int nd = c >> 3, ko = (c & 7) * 4;
        int node = min(base + nd, n - 1);
        float4 v = *(const float4*)(A + (size_t)node * 32 + ko);
        ushort4 hi, lo;
        split4(v, hi, lo);
        *(ushort4*)(Ah + nd * 40 + ko) = hi;
        *(ushort4*)(Al + nd * 40 + ko) = lo;
    }
    if (t < 128) {  // 128 uint4 chunks per buffer
        int col = t >> 2, ko = (t & 3) * 8;
        *(uint4*)(Wh + col * 40 + ko) = *(const uint4*)(wsplit + ((size_t)col) * 32 + ko);
        *(uint4*)(Wl + col * 40 + ko) = *(const uint4*)(wsplit + ((size_t)(32 + col)) * 32 + ko);
    }
    __syncthreads();
    int wr = (w >> 1) * 32, wc = (w & 1) * 16;
    int lrow = l & 15, lk = (l >> 4) * 8;
    short8v ah0 = *(const short8v*)(Ah + (wr + lrow) * 40 + lk);
    short8v ah1 = *(const short8v*)(Ah + (wr + 16 + lrow) * 40 + lk);
    short8v al0 = *(const short8v*)(Al + (wr + lrow) * 40 + lk);
    short8v al1 = *(const short8v*)(Al + (wr + 16 + lrow) * 40 + lk);
    short8v bh = *(const short8v*)(Wh + (wc + lrow) * 40 + lk);
    short8v bl = *(const short8v*)(Wl + (wc + lrow) * 40 + lk);
    f32x4 acc0 = (f32x4){0.f, 0.f, 0.f, 0.f}, acc1 = (f32x4){0.f, 0.f, 0.f, 0.f};
    acc0 = __builtin_amdgcn_mfma_f32_16x16x32_bf16(ah0, bh, acc0, 0, 0, 0);
    acc0 = __builtin_amdgcn_mfma_f32_16x16x32_bf16(ah0, bl, acc0, 0, 0, 0);
    acc0 = __builtin_amdgcn_mfma_f32_16x16x32_bf16(al0, bh, acc0, 0, 0, 0);
    acc1 = __builtin_amdgcn_mfma_f32_16x16x32_bf16(ah1, bh, acc1, 0, 0, 0);
    acc1 = __builtin_amdgcn_mfma_f32_16x16x32_bf16(ah1, bl, acc1, 0, 0, 0);
    acc1 = __builtin_amdgcn_mfma_f32_16x16x32_bf16(al1, bh, acc1, 0, 0, 0);
#pragma unroll
    for (int rb = 0; rb < 2; ++rb) {
#pragma unroll
        for (int reg = 0; reg < 4; ++reg) {
            int row = wr + rb * 16 + (l >> 4) * 4 + reg;
            int node = base + row;
            float v = rb ? acc1[reg] : acc0[reg];
            unsigned short b16 = f2bf(v);
            gsh[row * 33 + wc + lrow] = __uint_as_float((unsigned)b16 << 16);
            if (node < n) C[(size_t)node * 32 + wc + lrow] = b16;
        }
    }
    __syncthreads();
    if (t < 64) {
        int node = base + t;
        float s = 0.f, d = 0.f;
#pragma unroll
        for (int c = 0; c < 32; ++c) {
            float gv = gsh[t * 33 + c];
            s += gv * wp[OFF_GAS + c];
            d += gv * wp[OFF_GAD + c];
        }
        if (node < n) { asrc[node] = s; adst[node] = d; }
    }
}

// ---------------- GCN agg over pre-scaled t' (t*dis), bf16 gather -> fp32 out -----------
template <bool RELU>
__global__ void k_agg128(const unsigned* __restrict__ t, const int* __restrict__ rptr,
                         const int* __restrict__ csr_src, const float* __restrict__ dis,
                         const float* __restrict__ bias, float* __restrict__ out, int n) {
    int wave = (blockIdx.x * blockDim.x + threadIdx.x) >> 6;
    int lane = threadIdx.x & 63;
    if (wave >= n) return;
    int dst = wave;
    float dd = dis[dst];
    float ax, ay;
    {
        unsigned u = t[(size_t)dst * 64 + lane];
        ax = lo_(u);
        ay = hi_(u);
    }
    int s = __builtin_amdgcn_readfirstlane(max(0, min(rptr[dst], EE)));
    int e = __builtin_amdgcn_readfirstlane(max(s, min(rptr[dst + 1], EE)));
    int j = s;
    for (; j + 8 <= e; j += 8) {
        int i0 = csr_src[j], i1 = csr_src[j + 1], i2 = csr_src[j + 2], i3 = csr_src[j + 3];
        int i4 = csr_src[j + 4], i5 = csr_src[j + 5], i6 = csr_src[j + 6], i7 = csr_src[j + 7];
        unsigned u0 = t[(size_t)i0 * 64 + lane], u1 = t[(size_t)i1 * 64 + lane];
        unsigned u2 = t[(size_t)i2 * 64 + lane], u3 = t[(size_t)i3 * 64 + lane];
        unsigned u4 = t[(size_t)i4 * 64 + lane], u5 = t[(size_t)i5 * 64 + lane];
        unsigned u6 = t[(size_t)i6 * 64 + lane], u7 = t[(size_t)i7 * 64 + lane];
        ax += (lo_(u0) + lo_(u1)) + (lo_(u2) + lo_(u3)) + (lo_(u4) + lo_(u5)) + (lo_(u6) + lo_(u7));
        ay += (hi_(u0) + hi_(u1)) + (hi_(u2) + hi_(u3)) + (hi_(u4) + hi_(u5)) + (hi_(u6) + hi_(u7));
    }
    for (; j + 4 <= e; j += 4) {
        int i0 = csr_src[j], i1 = csr_src[j + 1], i2 = csr_src[j + 2], i3 = csr_src[j + 3];
        unsigned u0 = t[(size_t)i0 * 64 + lane], u1 = t[(size_t)i1 * 64 + lane];
        unsigned u2 = t[(size_t)i2 * 64 + lane], u3 = t[(size_t)i3 * 64 + lane];
        ax += (lo_(u0) + lo_(u1)) + (lo_(u2) + lo_(u3));
        ay += (hi_(u0) + hi_(u1)) + (hi_(u2) + hi_(u3));
    }
    for (; j < e; ++j) {
        unsigned u0 = t[(size_t)csr_src[j] * 64 + lane];
        ax += lo_(u0);
        ay += hi_(u0);
    }
    float2 bv = *(const float2*)(bias + 2 * lane);
    float vx = ax * dd + bv.x;
    float vy = ay * dd + bv.y;
    if (RELU) { vx = fmaxf(vx, 0.f); vy = fmaxf(vy, 0.f); }
    *(float2*)(out + (size_t)dst * 128 + 2 * lane) = make_float2(vx, vy);
}

// F=64: half-wave per edge, explicit 4-batches
template <bool RELU>
__global__ void k_agg64(const unsigned* __restrict__ t, const int* __restrict__ rptr,
                        const int* __restrict__ csr_src, const float* __restrict__ dis,
                        const float* __restrict__ bias, float* __restrict__ out, int n) {
    int wave = (blockIdx.x * blockDim.x + threadIdx.x) >> 6;
    int lane = threadIdx.x & 63;
    if (wave >= n) return;
    int dst = wave;
    int half = lane >> 5, l32 = lane & 31;
    float dd = dis[dst];
    float ax = 0.f, ay = 0.f;
    if (!half) {
        unsigned u = t[(size_t)dst * 32 + l32];
        ax = lo_(u);
        ay = hi_(u);
    }
    int s = max(0, min(rptr[dst], EE));
    int e = max(s, min(rptr[dst + 1], EE));
    int cnt = e - s;
    int pairs = cnt >> 1;
    int p = 0;
    for (; p + 4 <= pairs; p += 4) {
        int jb = s + 2 * p + half;
        int i0 = csr_src[jb], i1 = csr_src[jb + 2], i2 = csr_src[jb + 4], i3 = csr_src[jb + 6];
        unsigned u0 = t[(size_t)i0 * 32 + l32], u1 = t[(size_t)i1 * 32 + l32];
        unsigned u2 = t[(size_t)i2 * 32 + l32], u3 = t[(size_t)i3 * 32 + l32];
        ax += (lo_(u0) + lo_(u1)) + (lo_(u2) + lo_(u3));
        ay += (hi_(u0) + hi_(u1)) + (hi_(u2) + hi_(u3));
    }
    for (; p < pairs; ++p) {
        int i0 = csr_src[s + 2 * p + half];
        unsigned u0 = t[(size_t)i0 * 32 + l32];
        ax += lo_(u0);
        ay += hi_(u0);
    }
    if ((cnt & 1) && !half) {
        unsigned u0 = t[(size_t)csr_src[e - 1] * 32 + l32];
        ax += lo_(u0);
        ay += hi_(u0);
    }
    ax += __shfl_down(ax, 32);
    ay += __shfl_down(ay, 32);
    if (!half) {
        float2 bv = *(const float2*)(bias + 2 * l32);
        float vx = ax * dd + bv.x;
        float vy = ay * dd + bv.y;
        if (RELU) { vx = fmaxf(vx, 0.f); vy = fmaxf(vy, 0.f); }
        *(float2*)(out + (size_t)dst * 64 + 2 * l32) = make_float2(vx, vy);
    }
}

// F=32: quarter-wave per edge, explicit 4-batches
template <bool RELU>
__global__ void k_agg32(const unsigned* __restrict__ t, const int* __restrict__ rptr,
                        const int* __restrict__ csr_src, const float* __restrict__ dis,
                        const float* __restrict__ bias, float* __restrict__ out, int n) {
    int wave = (blockIdx.x * blockDim.x + threadIdx.x) >> 6;
    int lane = threadIdx.x & 63;
    if (wave >= n) return;
    int dst = wave;
    int q = lane >> 4, l16 = lane & 15;
    float dd = dis[dst];
    float ax = 0.f, ay = 0.f;
    if (q == 0) {
        unsigned u = t[(size_t)dst * 16 + l16];
        ax = lo_(u);
        ay = hi_(u);
    }
    int s = max(0, min(rptr[dst], EE));
    int e = max(s, min(rptr[dst + 1], EE));
    int cnt = e - s;
    int quads = cnt >> 2;
    int p = 0;
    for (; p + 4 <= quads; p += 4) {
        int jb = s + 4 * p + q;
        int i0 = csr_src[jb], i1 = csr_src[jb + 4], i2 = csr_src[jb + 8], i3 = csr_src[jb + 12];
        unsigned u0 = t[(size_t)i0 * 16 + l16], u1 = t[(size_t)i1 * 16 + l16];
        unsigned u2 = t[(size_t)i2 * 16 + l16], u3 = t[(size_t)i3 * 16 + l16];
        ax += (lo_(u0) + lo_(u1)) + (lo_(u2) + lo_(u3));
        ay += (hi_(u0) + hi_(u1)) + (hi_(u2) + hi_(u3));
    }
    for (; p < quads; ++p) {
        int i0 = csr_src[s + 4 * p + q];
        unsigned u0 = t[(size_t)i0 * 16 + l16];
        ax += lo_(u0);
        ay += hi_(u0);
    }
    int rem = cnt - 4 * quads;
    if (q < rem) {
        unsigned u0 = t[(size_t)csr_src[s + 4 * quads + q] * 16 + l16];
        ax += lo_(u0);
        ay += hi_(u0);
    }
    ax += __shfl_down(ax, 32);
    ay += __shfl_down(ay, 32);
    ax += __shfl_down(ax, 16);
    ay += __shfl_down(ay, 16);
    if (q == 0) {
        float2 bv = *(const float2*)(bias + 2 * l16);
        float vx = ax * dd + bv.x;
        float vy = ay * dd + bv.y;
        if (RELU) { vx = fmaxf(vx, 0.f); vy = fmaxf(vy, 0.f); }
        *(float2*)(out + (size_t)dst * 32 + 2 * l16) = make_float2(vx, vy);
    }
}

// ---------------- GAT aggregation ----------------
__global__ void k_gat_agg(const unsigned* __restrict__ g, const int* __restrict__ rptr,
                          const int* __restrict__ csr_src, const float* __restrict__ asrc,
                          const float* __restrict__ adst, const float* __restrict__ gat_b,
                          float* __restrict__ out, int n) {
    int wave = (blockIdx.x * blockDim.x + threadIdx.x) >> 6;
    int lane = threadIdx.x & 63;
    if (wave >= n) return;
    int dst = wave;
    int q = lane >> 4, l16 = lane & 15;
    float ad = adst[dst];
    int s = max(0, min(rptr[dst], EE));
    int e = max(s, min(rptr[dst + 1], EE));
    float ax = 0.f, ay = 0.f, denom = 0.f;
    if (q == 0) {
        float w0 = __expf(fminf(leakyf_(asrc[dst] + ad), 80.f));
        unsigned u = g[(size_t)dst * 16 + l16];
        ax = lo_(u) * w0;
        ay = hi_(u) * w0;
        denom = w0;
    }
    int cnt = e - s;
    int quads = cnt >> 2;
    int p = 0;
    for (; p + 4 <= quads; p += 4) {
        int jb = s + 4 * p + q;
        int i0 = csr_src[jb], i1 = csr_src[jb + 4], i2 = csr_src[jb + 8], i3 = csr_src[jb + 12];
        float a0 = asrc[i0], a1 = asrc[i1], a2 = asrc[i2], a3 = asrc[i3];
        unsigned u0 = g[(size_t)i0 * 16 + l16], u1 = g[(size_t)i1 * 16 + l16];
        unsigned u2 = g[(size_t)i2 * 16 + l16], u3 = g[(size_t)i3 * 16 + l16];
        float w0 = __expf(fminf(leakyf_(a0 + ad), 80.f));
        float w1 = __expf(fminf(leakyf_(a1 + ad), 80.f));
        float w2 = __expf(fminf(leakyf_(a2 + ad), 80.f));
        float w3 = __expf(fminf(leakyf_(a3 + ad), 80.f));
        denom += (w0 + w1) + (w2 + w3);
        ax += lo_(u0) * w0 + lo_(u1) * w1 + lo_(u2) * w2 + lo_(u3) * w3;
        ay += hi_(u0) * w0 + hi_(u1) * w1 + hi_(u2) * w2 + hi_(u3) * w3;
    }
    for (; p < quads; ++p) {
        int i0 = csr_src[s + 4 * p + q];
        float wgt = __expf(fminf(leakyf_(asrc[i0] + ad), 80.f));
        unsigned u0 = g[(size_t)i0 * 16 + l16];
        denom += wgt;
        ax += lo_(u0) * wgt;
        ay += hi_(u0) * wgt;
    }
    int rem = cnt - 4 * quads;
    if (q < rem) {
        int i0 = csr_src[s + 4 * quads + q];
        float wgt = __expf(fminf(leakyf_(asrc[i0] + ad), 80.f));
        unsigned u0 = g[(size_t)i0 * 16 + l16];
        denom += wgt;
        ax += lo_(u0) * wgt;
        ay += hi_(u0) * wgt;
    }
    ax += __shfl_down(ax, 32);
    ay += __shfl_down(ay, 32);
    denom += __shfl_down(denom, 32);
    ax += __shfl_down(ax, 16);
    ay += __shfl_down(ay, 16);
    denom += __shfl_down(denom, 16);
    if (q == 0) {
        float r = rcp_(denom);
        float vx = fmaxf(ax * r + gat_b[2 * l16], 0.f);
        float vy = fmaxf(ay * r + gat_b[2 * l16 + 1], 0.f);
        *(float2*)(out + (size_t)dst * 32 + 2 * l16) = make_float2(vx, vy);
    }
}

// ---------------- fused LSTM gates (MFMA, both dirs) + BN + FC + output -----------------
// Block = 64 nodes, 256 threads. Gate GEMM transposed (A=gate rows blocked i/g/o,
// B=nodes); acc tiles m, m+4, m+8 hold the (i,g,o) triple for the same j in-lane.
// r stays in LDS rs[64][129] (no rbufT round-trip); FC phase identical to old k_fc.
// ps aliases the dead Wh buffer after the last MFMA (10.2 KB < 15.4 KB).
__global__ __launch_bounds__(256) void k_lstm_full(const float* __restrict__ h,
                                                   const unsigned short* __restrict__ wsg,
                                                   const float* __restrict__ wp,
                                                   void* __restrict__ out,
                                                   const int* __restrict__ flags, int n) {
    __shared__ unsigned short Ah[64 * 40];   // 5.1 KB
    __shared__ unsigned short Al[64 * 40];   // 5.1 KB
    __shared__ unsigned short Wh[192 * 40];  // 15.4 KB (ps aliases this after MFMA)
    __shared__ unsigned short Wl[192 * 40];  // 15.4 KB
    __shared__ float rs[64 * 129];           // 33.0 KB
    __shared__ float bI[2][64], bG[2][64], bO[2][64], gsc[2][64], gbe[2][64];  // 2.5 KB
    float* ps = (float*)Wh;
    int t = threadIdx.x, l = t & 63, w = t >> 6;
    int base = blockIdx.x * 64;
    // stage h hi/lo
#pragma unroll
    for (int p = 0; p < 2; ++p) {
        int c = p * 256 + t, nd = c >> 3, ko = (c & 7) * 4;
        int node = min(base + nd, n - 1);
        float4 v = *(const float4*)(h + (size_t)node * 32 + ko);
        ushort4 hi, lo;
        split4(v, hi, lo);
        *(ushort4*)(Ah + nd * 40 + ko) = hi;
        *(ushort4*)(Al + nd * 40 + ko) = lo;
    }
    // biases / BN factors, both dirs
    if (t < 128) {
        int dir = t >> 6, j = t & 63;
        const float* bi_ = wp + (dir ? OFF_BIHB : OFF_BIHF);
        const float* bh_ = wp + (dir ? OFF_BHHB : OFF_BHHF);
        bI[dir][j] = bi_[j] + bh_[j];
        bG[dir][j] = bi_[128 + j] + bh_[128 + j];
        bO[dir][j] = bi_[192 + j] + bh_[192 + j];
        gsc[dir][j] = wp[OFF_GAMMA + dir * 64 + j] * rsqrtf(1.0f + 1e-5f);
        gbe[dir][j] = wp[OFF_BETA + dir * 64 + j];
    }
    // stage W dir0
    {
        const unsigned short* sh = wsg;
        const unsigned short* sl = wsg + (size_t)192 * 32;
#pragma unroll
        for (int p = 0; p < 3; ++p) {
            int c = p * 256 + t, row = c >> 2, ko = (c & 3) * 8;
            *(uint4*)(Wh + row * 40 + ko) = *(const uint4*)(sh + (size_t)row * 32 + ko);
            *(uint4*)(Wl + row * 40 + ko) = *(const uint4*)(sl + (size_t)row * 32 + ko);
        }
    }
    __syncthreads();
    int lrow = l & 15, lk = (l >> 4) * 8;
    short8v hh = *(const short8v*)(Ah + (w * 16 + lrow) * 40 + lk);
    short8v hl = *(const short8v*)(Al + (w * 16 + lrow) * 40 + lk);
    for (int dir = 0; dir < 2; ++dir) {
        if (dir == 1) {
            __syncthreads();  // dir0 MFMA done reading Wh/Wl
            const unsigned short* sh = wsg + (size_t)2 * 192 * 32;
            const unsigned short* sl = wsg + (size_t)3 * 192 * 32;
#pragma unroll
            for (int p = 0; p < 3; ++p) {
                int c = p * 256 + t, row = c >> 2, ko = (c & 3) * 8;
                *(uint4*)(Wh + row * 40 + ko) = *(const uint4*)(sh + (size_t)row * 32 + ko);
                *(uint4*)(Wl + row * 40 + ko) = *(const uint4*)(sl + (size_t)row * 32 + ko);
            }
            __syncthreads();
        }
        f32x4 acc[12];
#pragma unroll
        for (int m = 0; m < 12; ++m) acc[m] = (f32x4){0.f, 0.f, 0.f, 0.f};
#pragma unroll
        for (int m = 0; m < 12; ++m) {
            short8v wh_ = *(const short8v*)(Wh + (m * 16 + lrow) * 40 + lk);
            short8v wl_ = *(const short8v*)(Wl + (m * 16 + lrow) * 40 + lk);
            acc[m] = __builtin_amdgcn_mfma_f32_16x16x32_bf16(wh_, hh, acc[m], 0, 0, 0);
            acc[m] = __builtin_amdgcn_mfma_f32_16x16x32_bf16(wl_, hh, acc[m], 0, 0, 0);
            acc[m] = __builtin_amdgcn_mfma_f32_16x16x32_bf16(wh_, hl, acc[m], 0, 0, 0);
        }
#pragma unroll
        for (int m = 0; m < 4; ++m) {
#pragma unroll
            for (int reg = 0; reg < 4; ++reg) {
                int j = 16 * m + (l >> 4) * 4 + reg;
                float iv = acc[m][reg] + bI[dir][j];
                float gv = acc[m + 4][reg] + bG[dir][j];
                float ov = acc[m + 8][reg] + bO[dir][j];
                float v = sigmoidf_(ov) * tanhf_(sigmoidf_(iv) * tanhf_(gv));
                rs[(w * 16 + lrow) * 129 + dir * 64 + j] = v * gsc[dir][j] + gbe[dir][j];
            }
        }
    }
    __syncthreads();  // rs complete; Wh reads done -> ps alias safe
    {
        int nd = t & 63, quarter = t >> 6;
        const float* fcw = wp + OFF_FCW;
        int jbase = quarter * 32;
        float p10[10];
#pragma unroll
        for (int c = 0; c < 10; ++c) p10[c] = 0.f;
#pragma unroll 4
        for (int k = 0; k < 32; ++k) {
            float r = rs[nd * 129 + jbase + k];
#pragma unroll
            for (int c = 0; c < 10; ++c) p10[c] += r * fcw[c * 128 + jbase + k];
        }
#pragma unroll
        for (int c = 0; c < 10; ++c) ps[quarter * 640 + nd * 10 + c] = p10[c];
    }
    __syncthreads();
    bool f32o = flags[0] != 0;
    for (int idx = t; idx < 640; idx += 256) {
        int gnode = base + idx / 10;
        if (gnode < n) {
            int c = idx % 10;
            float v = wp[OFF_FCB + c] + ps[idx] + ps[640 + idx] + ps[1280 + idx] + ps[1920 + idx];
            if (f32o) ((float*)out)[(size_t)base * 10 + idx] = v;
            else ((unsigned short*)out)[(size_t)base * 10 + idx] = f2bf(v);
        }
    }
}

// ---------------- launch ----------------
extern "C" void kernel_launch(void* const* d_in, const int* in_sizes, int n_in,
                              void* d_out, int out_size, void* d_ws, size_t ws_size,
                              hipStream_t stream) {
    const int N = NN;

    char* w = (char*)d_ws;
    auto alloc = [&](size_t bytes) {
        void* p = (void*)w;
        w += (bytes + 255) & ~(size_t)255;
        return p;
    };
    int* flags = (int*)alloc(256);
    float* wpool = (float*)alloc((size_t)WTOTAL * 4);
    unsigned short* wsplit = (unsigned short*)alloc(65536);   // W1 hi/lo
    unsigned short* ws2 = (unsigned short*)alloc(32768);      // W2 hi/lo
    unsigned short* ws3 = (unsigned short*)alloc(8192);       // W3 hi/lo
    unsigned short* wsgat = (unsigned short*)alloc(4096);     // GATW hi/lo
    unsigned short* wsg = (unsigned short*)alloc(49152);      // LSTM gate W'' hi/lo
    float* dis = (float*)alloc((size_t)N * 4);
    int* rptr = (int*)alloc((size_t)(N + 1) * 4);
    int* csr_src = (int*)alloc((size_t)EE * 4);
    unsigned* gh = (unsigned*)alloc((size_t)NBK * 256 * 4);
    unsigned* gh2 = (unsigned*)alloc((size_t)NBK * 256 * 4);
    int* bb = (int*)alloc(1024);
    int2* ebkt = (int2*)alloc((size_t)EE * 8);
    float* asrc = (float*)alloc((size_t)N * 4);
    float* adst = (float*)alloc((size_t)N * 4);
    unsigned* bufT = (unsigned*)alloc((size_t)N * 64 * 4);  // bf16 N x 128
    float* bufH = (float*)alloc((size_t)N * 128 * 4);       // fp32 N x 128

    WSrc ws_srcs;
    for (int i = 0; i < 20; ++i) ws_srcs.p[i] = d_in[2 + i];

    const int AGG = (N + 3) / 4;
    const int TMB = (N + 63) / 64;
    const int WB = (WTOTAL + 255) / 256;

    k_detect<<<1, 256, 0, stream>>>((const unsigned short*)d_in[0],
                                    (const unsigned int*)d_in[1], flags);
    k_cvt_w<<<WB, 256, 0, stream>>>(ws_srcs, wpool, flags, WTOTAL);
    k_prep_all<<<156, 256, 0, stream>>>(wpool, wsplit, ws2, ws3, wsgat, wsg);
    // bucketed CSR build
    k_hist<<<NBK, 256, 0, stream>>>(d_in[1], gh, flags);
    k_bscan<<<1, 256, 0, stream>>>(gh, gh2, bb, rptr);
    k_scatter<<<NBK, 256, 0, stream>>>(d_in[1], gh2, bb, ebkt, flags);
    k_bucket_csr<<<NBK, 256, 0, stream>>>(ebkt, bb, rptr, dis, csr_src);

    // GCN 1 (x -> t1' = (x@W1)*dis, bf16): MFMA for BOTH input dtypes (flag-gated)
    k_gcn1_mfma<0><<<TMB, 256, 0, stream>>>(d_in[0], wsplit, bufT, N, flags, dis);
    k_gcn1_mfma<1><<<TMB, 256, 0, stream>>>(d_in[0], wsplit, bufT, N, flags, dis);
    k_agg128<true><<<AGG, 256, 0, stream>>>(bufT, rptr, csr_src, dis, wpool + OFF_B1, bufH, N);
    // GCN 2 (MFMA)
    k_mm_mfma<128, 64, true><<<TMB, 256, 0, stream>>>(bufH, ws2, (unsigned short*)bufT, N, dis);
    k_agg64<true><<<AGG, 256, 0, stream>>>(bufT, rptr, csr_src, dis, wpool + OFF_B2, bufH, N);
    // GCN 3 (MFMA)
    k_mm_mfma<64, 32, true><<<TMB, 256, 0, stream>>>(bufH, ws3, (unsigned short*)bufT, N, dis);
    k_agg32<false><<<AGG, 256, 0, stream>>>(bufT, rptr, csr_src, dis, wpool + OFF_B3, bufH, N);
    // GAT projection fused with a_src/a_dst dots, then aggregation
    k_mm_gat<<<TMB, 256, 0, stream>>>(bufH, wsgat, (unsigned short*)bufT, N, wpool, asrc, adst);
    k_gat_agg<<<AGG, 256, 0, stream>>>(bufT, rptr, csr_src, asrc, adst, wpool + OFF_GAB, bufH, N);
    // fused LSTM gates (both dirs) + BN + FC + output
    k_lstm_full<<<TMB, 256, 0, stream>>>(bufH, wsg, wpool, d_out, flags, N);
}

// Round 12
// 330.891 us; speedup vs baseline: 1.1495x; 1.0073x over previous
//
#include <hip/hip_runtime.h>
#include <hip/hip_bf16.h>
#include <math.h>

typedef __hip_bfloat16 bf16;
typedef __attribute__((ext_vector_type(8))) short short8v;   // 8 bf16 = 4 VGPRs (MFMA A/B frag)
typedef __attribute__((ext_vector_type(4))) float f32x4;     // MFMA C/D frag

#define NN 50000
#define EE 800000
#define EPB 4096   // edges per block (hist/scatter)
#define NBK 196    // dst buckets = ceil(NN/256); also blocks for hist/scatter
#define BCAP 6144  // max edges per bucket (mean 4096, sd ~64)

__device__ __forceinline__ float b2f(bf16 v) { return __bfloat162float(v); }
__device__ __forceinline__ float rcp_(float x) { return __builtin_amdgcn_rcpf(x); }
__device__ __forceinline__ float sigmoidf_(float x) { return rcp_(1.0f + __expf(-x)); }
__device__ __forceinline__ float tanhf_(float x) {
    float xx = fminf(fmaxf(x, -15.0f), 15.0f);
    float e = __expf(2.0f * xx);
    return (e - 1.0f) * rcp_(e + 1.0f);
}
__device__ __forceinline__ float leakyf_(float x) { return x > 0.0f ? x : 0.2f * x; }
__device__ __forceinline__ unsigned short f2bf(float f) {
    unsigned u = __float_as_uint(f);
    unsigned r = (u + 0x7FFFu + ((u >> 16) & 1u)) >> 16;
    return (unsigned short)r;
}
__device__ __forceinline__ unsigned pack2(float a, float b) {
    return (unsigned)f2bf(a) | ((unsigned)f2bf(b) << 16);
}
__device__ __forceinline__ float lo_(unsigned u) { return __uint_as_float(u << 16); }
__device__ __forceinline__ float hi_(unsigned u) { return __uint_as_float(u & 0xFFFF0000u); }
__device__ __forceinline__ void split4(float4 v, ushort4& hi, ushort4& lo) {
    hi.x = f2bf(v.x); lo.x = f2bf(v.x - __uint_as_float((unsigned)hi.x << 16));
    hi.y = f2bf(v.y); lo.y = f2bf(v.y - __uint_as_float((unsigned)hi.y << 16));
    hi.z = f2bf(v.z); lo.z = f2bf(v.z - __uint_as_float((unsigned)hi.z << 16));
    hi.w = f2bf(v.w); lo.w = f2bf(v.w - __uint_as_float((unsigned)hi.w << 16));
}

// weight-pool element offsets (fp32 pool in ws)
#define OFF_W1 0
#define OFF_B1 16384
#define OFF_W2 16512
#define OFF_B2 24704
#define OFF_W3 24768
#define OFF_B3 26816
#define OFF_GATW 26848
#define OFF_GAS 27872
#define OFF_GAD 27904
#define OFF_GAB 27936
#define OFF_WIHF 27968
#define OFF_BIHF 36160
#define OFF_BHHF 36416
#define OFF_WIHB 36672
#define OFF_BIHB 44864
#define OFF_BHHB 45120
#define OFF_GAMMA 45376
#define OFF_BETA 45504
#define OFF_FCW 45632
#define OFF_FCB 46912
#define WTOTAL 46922

struct WSrc { const void* p[20]; };

// ---------------- dtype detection ----------------
__global__ void k_detect(const unsigned short* __restrict__ xraw,
                         const unsigned int* __restrict__ eraw, int* __restrict__ flags) {
    __shared__ int f32f, i64f;
    int t = threadIdx.x;
    if (t == 0) { f32f = 0; i64f = 1; }
    __syncthreads();
    for (int i = t; i < 4096; i += 256) {
        unsigned short u = xraw[i];
        int ex = (u >> 7) & 0xFF;
        if (ex >= 0xC0) atomicOr(&f32f, 1);
        if (eraw[2 * i + 1] != 0u) atomicAnd(&i64f, 0);
    }
    __syncthreads();
    if (t == 0) { flags[0] = f32f; flags[1] = i64f; }
}

// ---------------- weight conversion into fp32 pool ----------------
__global__ void k_cvt_w(WSrc srcs, float* __restrict__ dst, const int* __restrict__ flags,
                        int total) {
    constexpr int WOFF[21] = {OFF_W1,   OFF_B1,   OFF_W2,   OFF_B2,   OFF_W3,   OFF_B3,
                              OFF_GATW, OFF_GAS,  OFF_GAD,  OFF_GAB,  OFF_WIHF, OFF_BIHF,
                              OFF_BHHF, OFF_WIHB, OFF_BIHB, OFF_BHHB, OFF_GAMMA, OFF_BETA,
                              OFF_FCW,  OFF_FCB,  WTOTAL};
    int i = blockIdx.x * 256 + threadIdx.x;
    if (i >= total) return;
    int tn = 0;
#pragma unroll
    for (int j = 1; j < 20; ++j)
        if (i >= WOFF[j]) tn = j;
    int local = i - WOFF[tn];
    if (flags[0]) dst[i] = ((const float*)srcs.p[tn])[local];
    else dst[i] = b2f(((const bf16*)srcs.p[tn])[local]);
}

// ---------------- ALL weight hi/lo splits in one kernel ---------------------------------
// ranges: [0,16384) W1 128x128 | [16384,24576) W2 128x64 | [24576,26624) W3 64x32 |
//         [26624,27648) GAT 32x32 | [27648,39936) LSTM gates (blocked rows)
__global__ void k_prep_all(const float* __restrict__ wp, unsigned short* __restrict__ w1,
                           unsigned short* __restrict__ w2, unsigned short* __restrict__ w3,
                           unsigned short* __restrict__ wgat, unsigned short* __restrict__ wg) {
    int i = blockIdx.x * 256 + threadIdx.x;
    if (i < 16384) {
        int k = i >> 7, col = i & 127;
        float v = wp[OFF_W1 + k * 128 + col];
        unsigned short hi = f2bf(v);
        unsigned short lo = f2bf(v - __uint_as_float((unsigned)hi << 16));
        int kt = k >> 5, kk = k & 31;
        w1[((size_t)(kt * 2 + 0) * 128 + col) * 32 + kk] = hi;
        w1[((size_t)(kt * 2 + 1) * 128 + col) * 32 + kk] = lo;
    } else if (i < 24576) {
        int j = i - 16384;
        int k = j >> 6, col = j & 63;
        float v = wp[OFF_W2 + k * 64 + col];
        unsigned short hi = f2bf(v);
        unsigned short lo = f2bf(v - __uint_as_float((unsigned)hi << 16));
        int kt = k >> 5, kk = k & 31;
        w2[((size_t)(kt * 2 + 0) * 64 + col) * 32 + kk] = hi;
        w2[((size_t)(kt * 2 + 1) * 64 + col) * 32 + kk] = lo;
    } else if (i < 26624) {
        int j = i - 24576;
        int k = j >> 5, col = j & 31;
        float v = wp[OFF_W3 + k * 32 + col];
        unsigned short hi = f2bf(v);
        unsigned short lo = f2bf(v - __uint_as_float((unsigned)hi << 16));
        int kt = k >> 5, kk = k & 31;
        w3[((size_t)(kt * 2 + 0) * 32 + col) * 32 + kk] = hi;
        w3[((size_t)(kt * 2 + 1) * 32 + col) * 32 + kk] = lo;
    } else if (i < 27648) {
        int j = i - 26624;
        int k = j >> 5, col = j & 31;
        float v = wp[OFF_GATW + k * 32 + col];
        unsigned short hi = f2bf(v);
        unsigned short lo = f2bf(v - __uint_as_float((unsigned)hi << 16));
        int kk = k & 31;
        wgat[((size_t)col) * 32 + kk] = hi;
        wgat[((size_t)(32 + col)) * 32 + kk] = lo;
    } else if (i < 39936) {
        int j = i - 27648;
        int dir = j / 6144, r2 = j % 6144;
        int row = r2 >> 5, k = r2 & 31;
        int gate = row >> 6, jj = row & 63;
        int srcrow = jj + (gate == 1 ? 128 : (gate == 2 ? 192 : 0));
        const float* W = wp + (dir ? OFF_WIHB : OFF_WIHF);
        float v = W[(size_t)srcrow * 32 + k];
        unsigned short hi = f2bf(v);
        unsigned short lo = f2bf(v - __uint_as_float((unsigned)hi << 16));
        wg[((size_t)(dir * 2 + 0) * 192 + row) * 32 + k] = hi;
        wg[((size_t)(dir * 2 + 1) * 192 + row) * 32 + k] = lo;
    }
}

// ---------------- bucketed CSR build ----------------
__global__ __launch_bounds__(256) void k_hist(const void* __restrict__ eraw,
                                              unsigned* __restrict__ gh,
                                              const int* __restrict__ flags) {
    __shared__ int h[256];
    int t = threadIdx.x, b = blockIdx.x;
    h[t] = 0;
    __syncthreads();
    int e0 = b * EPB;
    bool i64 = flags[1] != 0;
    for (int i = t; i < EPB; i += 256) {
        int e = e0 + i;
        if (e < EE) {
            int d = i64 ? (int)((const long long*)eraw)[EE + e] : ((const int*)eraw)[EE + e];
            d = min(max(d, 0), NN - 1);
            atomicAdd(&h[d >> 8], 1);
        }
    }
    __syncthreads();
    gh[b * 256 + t] = (unsigned)h[t];
}

// P2a: per-bucket scan over the 196 edge-blocks (256-way block parallelism).
// Output bit-identical to the old single-block k_bscan: gh2 = within-bucket exclusive
// offsets, bsum = per-bucket totals.
__global__ __launch_bounds__(256) void k_bscan_a(const unsigned* __restrict__ gh,
                                                 unsigned* __restrict__ gh2,
                                                 unsigned* __restrict__ bsum) {
    __shared__ unsigned s[256];
    int b = blockIdx.x;   // bucket
    int t = threadIdx.x;  // edge-block index
    unsigned v = (t < NBK) ? gh[t * 256 + b] : 0u;
    s[t] = v;
    __syncthreads();
    for (int o = 1; o < 256; o <<= 1) {
        unsigned x = (t >= o) ? s[t - o] : 0u;
        __syncthreads();
        s[t] += x;
        __syncthreads();
    }
    if (t < NBK) gh2[t * 256 + b] = s[t] - v;  // exclusive within-bucket offset
    if (t == 255) bsum[b] = s[255];
}

// P2b: scan of 256 bucket totals -> bucket bases (tiny single block)
__global__ __launch_bounds__(256) void k_bscan_b(const unsigned* __restrict__ bsum,
                                                 int* __restrict__ bb, int* __restrict__ rptr) {
    __shared__ int s[256];
    int t = threadIdx.x;
    int v = (int)bsum[t];
    s[t] = v;
    __syncthreads();
    for (int o = 1; o < 256; o <<= 1) {
        int x = (t >= o) ? s[t - o] : 0;
        __syncthreads();
        s[t] += x;
        __syncthreads();
    }
    bb[t] = s[t] - v;  // exclusive bucket base (bb[196] lands on EE)
    if (t == 0) rptr[NN] = EE;
}

__global__ __launch_bounds__(256) void k_scatter(const void* __restrict__ eraw,
                                                 const unsigned* __restrict__ gh2,
                                                 const int* __restrict__ bb,
                                                 int2* __restrict__ ebkt,
                                                 const int* __restrict__ flags) {
    __shared__ unsigned cur[256];
    int t = threadIdx.x, b = blockIdx.x;
    cur[t] = gh2[b * 256 + t] + (unsigned)bb[t];
    __syncthreads();
    int e0 = b * EPB;
    bool i64 = flags[1] != 0;
    for (int i = t; i < EPB; i += 256) {
        int e = e0 + i;
        if (e < EE) {
            int sn, d;
            if (i64) {
                sn = (int)((const long long*)eraw)[e];
                d = (int)((const long long*)eraw)[EE + e];
            } else {
                sn = ((const int*)eraw)[e];
                d = ((const int*)eraw)[EE + e];
            }
            sn = min(max(sn, 0), NN - 1);
            d = min(max(d, 0), NN - 1);
            unsigned pos = atomicAdd(&cur[d >> 8], 1u);
            if (pos < (unsigned)EE) ebkt[pos] = make_int2(sn, d);
        }
    }
}

__global__ __launch_bounds__(256) void k_bucket_csr(const int2* __restrict__ ebkt,
                                                    const int* __restrict__ bb,
                                                    int* __restrict__ rptr,
                                                    float* __restrict__ dis,
                                                    int* __restrict__ csr_src) {
    __shared__ int hist[256];
    __shared__ int excl[256];
    __shared__ int cur[256];
    __shared__ int sorted[BCAP];
    int t = threadIdx.x, b = blockIdx.x;
    int s0 = bb[b], s1 = bb[b + 1];
    int len = min(s1 - s0, BCAP);
    hist[t] = 0;
    __syncthreads();
    for (int i = t; i < len; i += 256) atomicAdd(&hist[ebkt[s0 + i].y & 255], 1);
    __syncthreads();
    int v = hist[t];
    excl[t] = v;
    __syncthreads();
    for (int o = 1; o < 256; o <<= 1) {
        int x = (t >= o) ? excl[t - o] : 0;
        __syncthreads();
        excl[t] += x;
        __syncthreads();
    }
    int loc = excl[t] - v;  // local exclusive offset
    int node = b * 256 + t;
    if (node < NN) {
        rptr[node] = s0 + loc;
        dis[node] = rsqrtf((float)(v + 1));
    }
    cur[t] = loc;
    __syncthreads();
    for (int i = t; i < len; i += 256) {
        int2 p = ebkt[s0 + i];
        int pos = atomicAdd(&cur[p.y & 255], 1);
        if (pos < BCAP) sorted[pos] = p.x;
    }
    __syncthreads();
    for (int i = t; i < len; i += 256) csr_src[s0 + i] = sorted[i];
}

// ---------------- GCN1 via MFMA (both input dtypes, split-precision) --------------------
template <int MODE>
__global__ __launch_bounds__(256) void k_gcn1_mfma(const void* __restrict__ A,
                                                   const unsigned short* __restrict__ wsplit,
                                                   unsigned* __restrict__ C, int n,
                                                   const int* __restrict__ flags,
                                                   const float* __restrict__ dis) {
    if (flags[0] != MODE) return;
    __shared__ unsigned short Ah[64 * 136];                   // 17.4 KB
    __shared__ unsigned short Al[MODE ? 64 * 136 : 4];        // 17.4 KB (MODE 1 only)
    __shared__ unsigned short Wh[128 * 40];                   // 10.2 KB
    __shared__ unsigned short Wl[128 * 40];                   // 10.2 KB
    int t = threadIdx.x;
    int l = t & 63, w = t >> 6;
    int base = blockIdx.x * 64;
    if constexpr (MODE == 0) {
#pragma unroll
        for (int p = 0; p < 4; ++p) {
            int c = p * 256 + t;
            int nd = c >> 4, ko = (c & 15) * 8;
            int node = min(base + nd, n - 1);
            uint4 v = *(const uint4*)((const unsigned short*)A + (size_t)node * 128 + ko);
            *(uint4*)(Ah + nd * 136 + ko) = v;
        }
    } else {
#pragma unroll
        for (int p = 0; p < 8; ++p) {
            int c = p * 256 + t;
            int nd = c >> 5, ko = (c & 31) * 4;
            int node = min(base + nd, n - 1);
            float4 v = *(const float4*)((const float*)A + (size_t)node * 128 + ko);
            ushort4 hi, lo;
            split4(v, hi, lo);
            *(ushort4*)(Ah + nd * 136 + ko) = hi;
            *(ushort4*)(Al + nd * 136 + ko) = lo;
        }
    }
    int wr = (w >> 1) * 32, wc = (w & 1) * 64;
    int lrow = l & 15, lk = (l >> 4) * 8;
    f32x4 acc[2][4];
#pragma unroll
    for (int rb = 0; rb < 2; ++rb)
#pragma unroll
        for (int cb = 0; cb < 4; ++cb) acc[rb][cb] = (f32x4){0.f, 0.f, 0.f, 0.f};
    for (int kt = 0; kt < 4; ++kt) {
        __syncthreads();
#pragma unroll
        for (int p = 0; p < 2; ++p) {
            int c = p * 256 + t;
            int col = c >> 2, ko = (c & 3) * 8;
            *(uint4*)(Wh + col * 40 + ko) =
                *(const uint4*)(wsplit + ((size_t)(kt * 2 + 0) * 128 + col) * 32 + ko);
            *(uint4*)(Wl + col * 40 + ko) =
                *(const uint4*)(wsplit + ((size_t)(kt * 2 + 1) * 128 + col) * 32 + ko);
        }
        __syncthreads();
        short8v ah0 = *(const short8v*)(Ah + (wr + lrow) * 136 + kt * 32 + lk);
        short8v ah1 = *(const short8v*)(Ah + (wr + 16 + lrow) * 136 + kt * 32 + lk);
        short8v al0, al1;
        if constexpr (MODE == 1) {
            al0 = *(const short8v*)(Al + (wr + lrow) * 136 + kt * 32 + lk);
            al1 = *(const short8v*)(Al + (wr + 16 + lrow) * 136 + kt * 32 + lk);
        }
#pragma unroll
        for (int cb = 0; cb < 4; ++cb) {
            int col = wc + cb * 16 + lrow;
            short8v bh = *(const short8v*)(Wh + col * 40 + lk);
            short8v bl = *(const short8v*)(Wl + col * 40 + lk);
            acc[0][cb] = __builtin_amdgcn_mfma_f32_16x16x32_bf16(ah0, bh, acc[0][cb], 0, 0, 0);
            acc[0][cb] = __builtin_amdgcn_mfma_f32_16x16x32_bf16(ah0, bl, acc[0][cb], 0, 0, 0);
            acc[1][cb] = __builtin_amdgcn_mfma_f32_16x16x32_bf16(ah1, bh, acc[1][cb], 0, 0, 0);
            acc[1][cb] = __builtin_amdgcn_mfma_f32_16x16x32_bf16(ah1, bl, acc[1][cb], 0, 0, 0);
            if constexpr (MODE == 1) {
                acc[0][cb] = __builtin_amdgcn_mfma_f32_16x16x32_bf16(al0, bh, acc[0][cb], 0, 0, 0);
                acc[1][cb] = __builtin_amdgcn_mfma_f32_16x16x32_bf16(al1, bh, acc[1][cb], 0, 0, 0);
            }
        }
    }
#pragma unroll
    for (int rb = 0; rb < 2; ++rb) {
#pragma unroll
        for (int reg = 0; reg < 4; ++reg) {
            int row = wr + rb * 16 + (l >> 4) * 4 + reg;
            int node = base + row;
            if (node < n) {
                float sc = dis[node];
                unsigned short* cr = (unsigned short*)C + (size_t)node * 128;
#pragma unroll
                for (int cb = 0; cb < 4; ++cb) {
                    int col = wc + cb * 16 + lrow;
                    cr[col] = f2bf(acc[rb][cb][reg] * sc);
                }
            }
        }
    }
}

// ---------------- generic MFMA GEMM: C(bf16[KOUT]) = A(fp32[KIN]) @ W, split-precision --
template <int KIN, int KOUT, bool SCALE>
__global__ __launch_bounds__(256) void k_mm_mfma(const float* __restrict__ A,
                                                 const unsigned short* __restrict__ wsplit,
                                                 unsigned short* __restrict__ C, int n,
                                                 const float* __restrict__ dis) {
    constexpr int AST = KIN + 8;
    constexpr int KT = KIN / 32;
    constexpr int CB = KOUT / 32;  // col-blocks per wave (KOUT=64 -> 2, 32 -> 1)
    __shared__ unsigned short Ah[64 * AST];
    __shared__ unsigned short Al[64 * AST];
    __shared__ unsigned short Wh[KOUT * 40];
    __shared__ unsigned short Wl[KOUT * 40];
    int t = threadIdx.x;
    int l = t & 63, w = t >> 6;
    int base = blockIdx.x * 64;
#pragma unroll
    for (int p = 0; p < KIN / 16; ++p) {
        int c = p * 256 + t;  // 64*KIN/4 float4 chunks
        int nd = c / (KIN / 4), ko = (c % (KIN / 4)) * 4;
        int node = min(base + nd, n - 1);
        float4 v = *(const float4*)(A + (size_t)node * KIN + ko);
        ushort4 hi, lo;
        split4(v, hi, lo);
        *(ushort4*)(Ah + nd * AST + ko) = hi;
        *(ushort4*)(Al + nd * AST + ko) = lo;
    }
    int wr = (w >> 1) * 32, wc = (w & 1) * (KOUT / 2);
    int lrow = l & 15, lk = (l >> 4) * 8;
    f32x4 acc[2][CB];
#pragma unroll
    for (int rb = 0; rb < 2; ++rb)
#pragma unroll
        for (int cb = 0; cb < CB; ++cb) acc[rb][cb] = (f32x4){0.f, 0.f, 0.f, 0.f};
    for (int kt = 0; kt < KT; ++kt) {
        __syncthreads();
        for (int c = t; c < KOUT * 4; c += 256) {  // uint4 chunks of 8 bf16
            int col = c >> 2, ko = (c & 3) * 8;
            *(uint4*)(Wh + col * 40 + ko) =
                *(const uint4*)(wsplit + ((size_t)(kt * 2 + 0) * KOUT + col) * 32 + ko);
            *(uint4*)(Wl + col * 40 + ko) =
                *(const uint4*)(wsplit + ((size_t)(kt * 2 + 1) * KOUT + col) * 32 + ko);
        }
        __syncthreads();
        short8v ah0 = *(const short8v*)(Ah + (wr + lrow) * AST + kt * 32 + lk);
        short8v ah1 = *(const short8v*)(Ah + (wr + 16 + lrow) * AST + kt * 32 + lk);
        short8v al0 = *(const short8v*)(Al + (wr + lrow) * AST + kt * 32 + lk);
        short8v al1 = *(const short8v*)(Al + (wr + 16 + lrow) * AST + kt * 32 + lk);
#pragma unroll
        for (int cb = 0; cb < CB; ++cb) {
            int col = wc + cb * 16 + lrow;
            short8v bh = *(const short8v*)(Wh + col * 40 + lk);
            short8v bl = *(const short8v*)(Wl + col * 40 + lk);
            acc[0][cb] = __builtin_amdgcn_mfma_f32_16x16x32_bf16(ah0, bh, acc[0][cb], 0, 0, 0);
            acc[0][cb] = __builtin_amdgcn_mfma_f32_16x16x32_bf16(ah0, bl, acc[0][cb], 0, 0, 0);
            acc[0][cb] = __builtin_amdgcn_mfma_f32_16x16x32_bf16(al0, bh, acc[0][cb], 0, 0, 0);
            acc[1][cb] = __builtin_amdgcn_mfma_f32_16x16x32_bf16(ah1, bh, acc[1][cb], 0, 0, 0);
            acc[1][cb] = __builtin_amdgcn_mfma_f32_16x16x32_bf16(ah1, bl, acc[1][cb], 0, 0, 0);
            acc[1][cb] = __builtin_amdgcn_mfma_f32_16x16x32_bf16(al1, bh, acc[1][cb], 0, 0, 0);
        }
    }
#pragma unroll
    for (int rb = 0; rb < 2; ++rb) {
#pragma unroll
        for (int reg = 0; reg < 4; ++reg) {
            int row = wr + rb * 16 + (l >> 4) * 4 + reg;
            int node = base + row;
            if (node < n) {
                float sc = SCALE ? dis[node] : 1.0f;
                unsigned short* cr = C + (size_t)node * KOUT;
#pragma unroll
                for (int cb = 0; cb < CB; ++cb) {
                    int col = wc + cb * 16 + lrow;
                    cr[col] = f2bf(acc[rb][cb][reg] * sc);
                }
            }
        }
    }
}

// ---------------- GAT projection (32x32 MFMA) fused with a_src/a_dst dots ---------------
__global__ __launch_bounds__(256) void k_mm_gat(const float* __restrict__ A,
                                                const unsigned short* __restrict__ wsplit,
                                                unsigned short* __restrict__ C, int n,
                                                const float* __restrict__ wp,
                                                float* __restrict__ asrc,
                                                float* __restrict__ adst) {
    __shared__ unsigned short Ah[64 * 40];
    __shared__ unsigned short Al[64 * 40];
    __shared__ unsigned short Wh[32 * 40];
    __shared__ unsigned short Wl[32 * 40];
    __shared__ float gsh[64 * 33];
    int t = threadIdx.x;
    int l = t & 63, w = t >> 6;
    int base = blockIdx.x * 64;
#pragma unroll
    for (int p = 0; p < 2; ++p) {
        int c = p * 256 + t;  // 512 float4 chunks
        int nd = c >> 3, ko = (c & 7) * 4;
        int node = min(base + nd, n - 1);
        float4 v = *(const float4*)(A + (size_t)node * 32 + ko);
        ushort4 hi, lo;
        split4(v, hi, lo);
        *(ushort4*)(Ah + nd * 40 + ko) = hi;
        *(ushort4*)(Al + nd * 40 + ko) = lo;
    }
    if (t < 128) {  // 128 uint4 chunks per buffer
        int col = t >> 2, ko = (t & 3) * 8;
        *(uint4*)(Wh + col * 40 + ko) = *(const uint4*)(wsplit + ((size_t)col) * 32 + ko);
        *(uint4*)(Wl + col * 40 + ko) = *(const uint4*)(wsplit + ((size_t)(32 + col)) * 32 + ko);
    }
    __syncthreads();
    int wr = (w >> 1) * 32, wc = (w & 1) * 16;
    int lrow = l & 15, lk = (l >> 4) * 8;
    short8v ah0 = *(const short8v*)(Ah + (wr + lrow) * 40 + lk);
    short8v ah1 = *(const short8v*)(Ah + (wr + 16 + lrow) * 40 + lk);
    short8v al0 = *(const short8v*)(Al + (wr + lrow) * 40 + lk);
    short8v al1 = *(const short8v*)(Al + (wr + 16 + lrow) * 40 + lk);
    short8v bh = *(const short8v*)(Wh + (wc + lrow) * 40 + lk);
    short8v bl = *(const short8v*)(Wl + (wc + lrow) * 40 + lk);
    f32x4 acc0 = (f32x4){0.f, 0.f, 0.f, 0.f}, acc1 = (f32x4){0.f, 0.f, 0.f, 0.f};
    acc0 = __builtin_amdgcn_mfma_f32_16x16x32_bf16(ah0, bh, acc0, 0, 0, 0);
    acc0 = __builtin_amdgcn_mfma_f32_16x16x32_bf16(ah0, bl, acc0, 0, 0, 0);
    acc0 = __builtin_amdgcn_mfma_f32_16x16x32_bf16(al0, bh, acc0, 0, 0, 0);
    acc1 = __builtin_amdgcn_mfma_f32_16x16x32_bf16(ah1, bh, acc1, 0, 0, 0);
    acc1 = __builtin_amdgcn_mfma_f32_16x16x32_bf16(ah1, bl, acc1, 0, 0, 0);
    acc1 = __builtin_amdgcn_mfma_f32_16x16x32_bf16(al1, bh, acc1, 0, 0, 0);
#pragma unroll
    for (int rb = 0; rb < 2; ++rb) {
#pragma unroll
        for (int reg = 0; reg < 4; ++reg) {
            int row = wr + rb * 16 + (l >> 4) * 4 + reg;
            int node = base + row;
            float v = rb ? acc1[reg] : acc0[reg];
            unsigned short b16 = f2bf(v);
            gsh[row * 33 + wc + lrow] = __uint_as_float((unsigned)b16 << 16);
            if (node < n) C[(size_t)node * 32 + wc + lrow] = b16;
        }
    }
    __syncthreads();
    if (t < 64) {
        int node = base + t;
        float s = 0.f, d = 0.f;
#pragma unroll
        for (int c = 0; c < 32; ++c) {
            float gv = gsh[t * 33 + c];
            s += gv * wp[OFF_GAS + c];
            d += gv * wp[OFF_GAD + c];
        }
        if (node < n) { asrc[node] = s; adst[node] = d; }
    }
}

// ---------------- GCN agg over pre-scaled t' (t*dis), bf16 gather -> fp32 out -----------
template <bool RELU>
__global__ void k_agg128(const unsigned* __restrict__ t, const int* __restrict__ rptr,
                         const int* __restrict__ csr_src, const float* __restrict__ dis,
                         const float* __restrict__ bias, float* __restrict__ out, int n) {
    int wave = (blockIdx.x * blockDim.x + threadIdx.x) >> 6;
    int lane = threadIdx.x & 63;
    if (wave >= n) return;
    int dst = wave;
    float dd = dis[dst];
    float ax, ay;
    {
        unsigned u = t[(size_t)dst * 64 + lane];
        ax = lo_(u);
        ay = hi_(u);
    }
    int s = __builtin_amdgcn_readfirstlane(max(0, min(rptr[dst], EE)));
    int e = __builtin_amdgcn_readfirstlane(max(s, min(rptr[dst + 1], EE)));
    int j = s;
    for (; j + 8 <= e; j += 8) {
        int i0 = csr_src[j], i1 = csr_src[j + 1], i2 = csr_src[j + 2], i3 = csr_src[j + 3];
        int i4 = csr_src[j + 4], i5 = csr_src[j + 5], i6 = csr_src[j + 6], i7 = csr_src[j + 7];
        unsigned u0 = t[(size_t)i0 * 64 + lane], u1 = t[(size_t)i1 * 64 + lane];
        unsigned u2 = t[(size_t)i2 * 64 + lane], u3 = t[(size_t)i3 * 64 + lane];
        unsigned u4 = t[(size_t)i4 * 64 + lane], u5 = t[(size_t)i5 * 64 + lane];
        unsigned u6 = t[(size_t)i6 * 64 + lane], u7 = t[(size_t)i7 * 64 + lane];
        ax += (lo_(u0) + lo_(u1)) + (lo_(u2) + lo_(u3)) + (lo_(u4) + lo_(u5)) + (lo_(u6) + lo_(u7));
        ay += (hi_(u0) + hi_(u1)) + (hi_(u2) + hi_(u3)) + (hi_(u4) + hi_(u5)) + (hi_(u6) + hi_(u7));
    }
    for (; j + 4 <= e; j += 4) {
        int i0 = csr_src[j], i1 = csr_src[j + 1], i2 = csr_src[j + 2], i3 = csr_src[j + 3];
        unsigned u0 = t[(size_t)i0 * 64 + lane], u1 = t[(size_t)i1 * 64 + lane];
        unsigned u2 = t[(size_t)i2 * 64 + lane], u3 = t[(size_t)i3 * 64 + lane];
        ax += (lo_(u0) + lo_(u1)) + (lo_(u2) + lo_(u3));
        ay += (hi_(u0) + hi_(u1)) + (hi_(u2) + hi_(u3));
    }
    for (; j < e; ++j) {
        unsigned u0 = t[(size_t)csr_src[j] * 64 + lane];
        ax += lo_(u0);
        ay += hi_(u0);
    }
    float2 bv = *(const float2*)(bias + 2 * lane);
    float vx = ax * dd + bv.x;
    float vy = ay * dd + bv.y;
    if (RELU) { vx = fmaxf(vx, 0.f); vy = fmaxf(vy, 0.f); }
    *(float2*)(out + (size_t)dst * 128 + 2 * lane) = make_float2(vx, vy);
}

// F=64: half-wave per edge, explicit 4-batches
template <bool RELU>
__global__ void k_agg64(const unsigned* __restrict__ t, const int* __restrict__ rptr,
                        const int* __restrict__ csr_src, const float* __restrict__ dis,
                        const float* __restrict__ bias, float* __restrict__ out, int n) {
    int wave = (blockIdx.x * blockDim.x + threadIdx.x) >> 6;
    int lane = threadIdx.x & 63;
    if (wave >= n) return;
    int dst = wave;
    int half = lane >> 5, l32 = lane & 31;
    float dd = dis[dst];
    float ax = 0.f, ay = 0.f;
    if (!half) {
        unsigned u = t[(size_t)dst * 32 + l32];
        ax = lo_(u);
        ay = hi_(u);
    }
    int s = max(0, min(rptr[dst], EE));
    int e = max(s, min(rptr[dst + 1], EE));
    int cnt = e - s;
    int pairs = cnt >> 1;
    int p = 0;
    for (; p + 4 <= pairs; p += 4) {
        int jb = s + 2 * p + half;
        int i0 = csr_src[jb], i1 = csr_src[jb + 2], i2 = csr_src[jb + 4], i3 = csr_src[jb + 6];
        unsigned u0 = t[(size_t)i0 * 32 + l32], u1 = t[(size_t)i1 * 32 + l32];
        unsigned u2 = t[(size_t)i2 * 32 + l32], u3 = t[(size_t)i3 * 32 + l32];
        ax += (lo_(u0) + lo_(u1)) + (lo_(u2) + lo_(u3));
        ay += (hi_(u0) + hi_(u1)) + (hi_(u2) + hi_(u3));
    }
    for (; p < pairs; ++p) {
        int i0 = csr_src[s + 2 * p + half];
        unsigned u0 = t[(size_t)i0 * 32 + l32];
        ax += lo_(u0);
        ay += hi_(u0);
    }
    if ((cnt & 1) && !half) {
        unsigned u0 = t[(size_t)csr_src[e - 1] * 32 + l32];
        ax += lo_(u0);
        ay += hi_(u0);
    }
    ax += __shfl_down(ax, 32);
    ay += __shfl_down(ay, 32);
    if (!half) {
        float2 bv = *(const float2*)(bias + 2 * l32);
        float vx = ax * dd + bv.x;
        float vy = ay * dd + bv.y;
        if (RELU) { vx = fmaxf(vx, 0.f); vy = fmaxf(vy, 0.f); }
        *(float2*)(out + (size_t)dst * 64 + 2 * l32) = make_float2(vx, vy);
    }
}

// F=32: quarter-wave per edge, explicit 4-batches
template <bool RELU>
__global__ void k_agg32(const unsigned* __restrict__ t, const int* __restrict__ rptr,
                        const int* __restrict__ csr_src, const float* __restrict__ dis,
                        const float* __restrict__ bias, float* __restrict__ out, int n) {
    int wave = (blockIdx.x * blockDim.x + threadIdx.x) >> 6;
    int lane = threadIdx.x & 63;
    if (wave >= n) return;
    int dst = wave;
    int q = lane >> 4, l16 = lane & 15;
    float dd = dis[dst];
    float ax = 0.f, ay = 0.f;
    if (q == 0) {
        unsigned u = t[(size_t)dst * 16 + l16];
        ax = lo_(u);
        ay = hi_(u);
    }
    int s = max(0, min(rptr[dst], EE));
    int e = max(s, min(rptr[dst + 1], EE));
    int cnt = e - s;
    int quads = cnt >> 2;
    int p = 0;
    for (; p + 4 <= quads; p += 4) {
        int jb = s + 4 * p + q;
        int i0 = csr_src[jb], i1 = csr_src[jb + 4], i2 = csr_src[jb + 8], i3 = csr_src[jb + 12];
        unsigned u0 = t[(size_t)i0 * 16 + l16], u1 = t[(size_t)i1 * 16 + l16];
        unsigned u2 = t[(size_t)i2 * 16 + l16], u3 = t[(size_t)i3 * 16 + l16];
        ax += (lo_(u0) + lo_(u1)) + (lo_(u2) + lo_(u3));
        ay += (hi_(u0) + hi_(u1)) + (hi_(u2) + hi_(u3));
    }
    for (; p < quads; ++p) {
        int i0 = csr_src[s + 4 * p + q];
        unsigned u0 = t[(size_t)i0 * 16 + l16];
        ax += lo_(u0);
        ay += hi_(u0);
    }
    int rem = cnt - 4 * quads;
    if (q < rem) {
        unsigned u0 = t[(size_t)csr_src[s + 4 * quads + q] * 16 + l16];
        ax += lo_(u0);
        ay += hi_(u0);
    }
    ax += __shfl_down(ax, 32);
    ay += __shfl_down(ay, 32);
    ax += __shfl_down(ax, 16);
    ay += __shfl_down(ay, 16);
    if (q == 0) {
        float2 bv = *(const float2*)(bias + 2 * l16);
        float vx = ax * dd + bv.x;
        float vy = ay * dd + bv.y;
        if (RELU) { vx = fmaxf(vx, 0.f); vy = fmaxf(vy, 0.f); }
        *(float2*)(out + (size_t)dst * 32 + 2 * l16) = make_float2(vx, vy);
    }
}

// ---------------- GAT aggregation ----------------
__global__ void k_gat_agg(const unsigned* __restrict__ g, const int* __restrict__ rptr,
                          const int* __restrict__ csr_src, const float* __restrict__ asrc,
                          const float* __restrict__ adst, const float* __restrict__ gat_b,
                          float* __restrict__ out, int n) {
    int wave = (blockIdx.x * blockDim.x + threadIdx.x) >> 6;
    int lane = threadIdx.x & 63;
    if (wave >= n) return;
    int dst = wave;
    int q = lane >> 4, l16 = lane & 15;
    float ad = adst[dst];
    int s = max(0, min(rptr[dst], EE));
    int e = max(s, min(rptr[dst + 1], EE));
    float ax = 0.f, ay = 0.f, denom = 0.f;
    if (q == 0) {
        float w0 = __expf(fminf(leakyf_(asrc[dst] + ad), 80.f));
        unsigned u = g[(size_t)dst * 16 + l16];
        ax = lo_(u) * w0;
        ay = hi_(u) * w0;
        denom = w0;
    }
    int cnt = e - s;
    int quads = cnt >> 2;
    int p = 0;
    for (; p + 4 <= quads; p += 4) {
        int jb = s + 4 * p + q;
        int i0 = csr_src[jb], i1 = csr_src[jb + 4], i2 = csr_src[jb + 8], i3 = csr_src[jb + 12];
        float a0 = asrc[i0], a1 = asrc[i1], a2 = asrc[i2], a3 = asrc[i3];
        unsigned u0 = g[(size_t)i0 * 16 + l16], u1 = g[(size_t)i1 * 16 + l16];
        unsigned u2 = g[(size_t)i2 * 16 + l16], u3 = g[(size_t)i3 * 16 + l16];
        float w0 = __expf(fminf(leakyf_(a0 + ad), 80.f));
        float w1 = __expf(fminf(leakyf_(a1 + ad), 80.f));
        float w2 = __expf(fminf(leakyf_(a2 + ad), 80.f));
        float w3 = __expf(fminf(leakyf_(a3 + ad), 80.f));
        denom += (w0 + w1) + (w2 + w3);
        ax += lo_(u0) * w0 + lo_(u1) * w1 + lo_(u2) * w2 + lo_(u3) * w3;
        ay += hi_(u0) * w0 + hi_(u1) * w1 + hi_(u2) * w2 + hi_(u3) * w3;
    }
    for (; p < quads; ++p) {
        int i0 = csr_src[s + 4 * p + q];
        float wgt = __expf(fminf(leakyf_(asrc[i0] + ad), 80.f));
        unsigned u0 = g[(size_t)i0 * 16 + l16];
        denom += wgt;
        ax += lo_(u0) * wgt;
        ay += hi_(u0) * wgt;
    }
    int rem = cnt - 4 * quads;
    if (q < rem) {
        int i0 = csr_src[s + 4 * quads + q];
        float wgt = __expf(fminf(leakyf_(asrc[i0] + ad), 80.f));
        unsigned u0 = g[(size_t)i0 * 16 + l16];
        denom += wgt;
        ax += lo_(u0) * wgt;
        ay += hi_(u0) * wgt;
    }
    ax += __shfl_down(ax, 32);
    ay += __shfl_down(ay, 32);
    denom += __shfl_down(denom, 32);
    ax += __shfl_down(ax, 16);
    ay += __shfl_down(ay, 16);
    denom += __shfl_down(denom, 16);
    if (q == 0) {
        float r = rcp_(denom);
        float vx = fmaxf(ax * r + gat_b[2 * l16], 0.f);
        float vy = fmaxf(ay * r + gat_b[2 * l16 + 1], 0.f);
        *(float2*)(out + (size_t)dst * 32 + 2 * l16) = make_float2(vx, vy);
    }
}

// ---------------- fused LSTM gates (MFMA, both dirs) + BN + FC + output -----------------
__global__ __launch_bounds__(256) void k_lstm_full(const float* __restrict__ h,
                                                   const unsigned short* __restrict__ wsg,
                                                   const float* __restrict__ wp,
                                                   void* __restrict__ out,
                                                   const int* __restrict__ flags, int n) {
    __shared__ unsigned short Ah[64 * 40];   // 5.1 KB
    __shared__ unsigned short Al[64 * 40];   // 5.1 KB
    __shared__ unsigned short Wh[192 * 40];  // 15.4 KB (ps aliases this after MFMA)
    __shared__ unsigned short Wl[192 * 40];  // 15.4 KB
    __shared__ float rs[64 * 129];           // 33.0 KB
    __shared__ float bI[2][64], bG[2][64], bO[2][64], gsc[2][64], gbe[2][64];  // 2.5 KB
    float* ps = (float*)Wh;
    int t = threadIdx.x, l = t & 63, w = t >> 6;
    int base = blockIdx.x * 64;
    // stage h hi/lo
#pragma unroll
    for (int p = 0; p < 2; ++p) {
        int c = p * 256 + t, nd = c >> 3, ko = (c & 7) * 4;
        int node = min(base + nd, n - 1);
        float4 v = *(const float4*)(h + (size_t)node * 32 + ko);
        ushort4 hi, lo;
        split4(v, hi, lo);
        *(ushort4*)(Ah + nd * 40 + ko) = hi;
        *(ushort4*)(Al + nd * 40 + ko) = lo;
    }
    // biases / BN factors, both dirs
    if (t < 128) {
        int dir = t >> 6, j = t & 63;
        const float* bi_ = wp + (dir ? OFF_BIHB : OFF_BIHF);
        const float* bh_ = wp + (dir ? OFF_BHHB : OFF_BHHF);
        bI[dir][j] = bi_[j] + bh_[j];
        bG[dir][j] = bi_[128 + j] + bh_[128 + j];
        bO[dir][j] = bi_[192 + j] + bh_[192 + j];
        gsc[dir][j] = wp[OFF_GAMMA + dir * 64 + j] * rsqrtf(1.0f + 1e-5f);
        gbe[dir][j] = wp[OFF_BETA + dir * 64 + j];
    }
    // stage W dir0
    {
        const unsigned short* sh = wsg;
        const unsigned short* sl = wsg + (size_t)192 * 32;
#pragma unroll
        for (int p = 0; p < 3; ++p) {
            int c = p * 256 + t, row = c >> 2, ko = (c & 3) * 8;
            *(uint4*)(Wh + row * 40 + ko) = *(const uint4*)(sh + (size_t)row * 32 + ko);
            *(uint4*)(Wl + row * 40 + ko) = *(const uint4*)(sl + (size_t)row * 32 + ko);
        }
    }
    __syncthreads();
    int lrow = l & 15, lk = (l >> 4) * 8;
    short8v hh = *(const short8v*)(Ah + (w * 16 + lrow) * 40 + lk);
    short8v hl = *(const short8v*)(Al + (w * 16 + lrow) * 40 + lk);
    for (int dir = 0; dir < 2; ++dir) {
        if (dir == 1) {
            __syncthreads();  // dir0 MFMA done reading Wh/Wl
            const unsigned short* sh = wsg + (size_t)2 * 192 * 32;
            const unsigned short* sl = wsg + (size_t)3 * 192 * 32;
#pragma unroll
            for (int p = 0; p < 3; ++p) {
                int c = p * 256 + t, row = c >> 2, ko = (c & 3) * 8;
                *(uint4*)(Wh + row * 40 + ko) = *(const uint4*)(sh + (size_t)row * 32 + ko);
                *(uint4*)(Wl + row * 40 + ko) = *(const uint4*)(sl + (size_t)row * 32 + ko);
            }
            __syncthreads();
        }
        f32x4 acc[12];
#pragma unroll
        for (int m = 0; m < 12; ++m) acc[m] = (f32x4){0.f, 0.f, 0.f, 0.f};
#pragma unroll
        for (int m = 0; m < 12; ++m) {
            short8v wh_ = *(const short8v*)(Wh + (m * 16 + lrow) * 40 + lk);
            short8v wl_ = *(const short8v*)(Wl + (m * 16 + lrow) * 40 + lk);
            acc[m] = __builtin_amdgcn_mfma_f32_16x16x32_bf16(wh_, hh, acc[m], 0, 0, 0);
            acc[m] = __builtin_amdgcn_mfma_f32_16x16x32_bf16(wl_, hh, acc[m], 0, 0, 0);
            acc[m] = __builtin_amdgcn_mfma_f32_16x16x32_bf16(wh_, hl, acc[m], 0, 0, 0);
        }
#pragma unroll
        for (int m = 0; m < 4; ++m) {
#pragma unroll
            for (int reg = 0; reg < 4; ++reg) {
                int j = 16 * m + (l >> 4) * 4 + reg;
                float iv = acc[m][reg] + bI[dir][j];
                float gv = acc[m + 4][reg] + bG[dir][j];
                float ov = acc[m + 8][reg] + bO[dir][j];
                float v = sigmoidf_(ov) * tanhf_(sigmoidf_(iv) * tanhf_(gv));
                rs[(w * 16 + lrow) * 129 + dir * 64 + j] = v * gsc[dir][j] + gbe[dir][j];
            }
        }
    }
    __syncthreads();  // rs complete; Wh reads done -> ps alias safe
    {
        int nd = t & 63, quarter = t >> 6;
        const float* fcw = wp + OFF_FCW;
        int jbase = quarter * 32;
        float p10[10];
#pragma unroll
        for (int c = 0; c < 10; ++c) p10[c] = 0.f;
#pragma unroll 4
        for (int k = 0; k < 32; ++k) {
            float r = rs[nd * 129 + jbase + k];
#pragma unroll
            for (int c = 0; c < 10; ++c) p10[c] += r * fcw[c * 128 + jbase + k];
        }
#pragma unroll
        for (int c = 0; c < 10; ++c) ps[quarter * 640 + nd * 10 + c] = p10[c];
    }
    __syncthreads();
    bool f32o = flags[0] != 0;
    for (int idx = t; idx < 640; idx += 256) {
        int gnode = base + idx / 10;
        if (gnode < n) {
            int c = idx % 10;
            float v = wp[OFF_FCB + c] + ps[idx] + ps[640 + idx] + ps[1280 + idx] + ps[1920 + idx];
            if (f32o) ((float*)out)[(size_t)base * 10 + idx] = v;
            else ((unsigned short*)out)[(size_t)base * 10 + idx] = f2bf(v);
        }
    }
}

// ---------------- launch ----------------
extern "C" void kernel_launch(void* const* d_in, const int* in_sizes, int n_in,
                              void* d_out, int out_size, void* d_ws, size_t ws_size,
                              hipStream_t stream) {
    const int N = NN;

    char* w = (char*)d_ws;
    auto alloc = [&](size_t bytes) {
        void* p = (void*)w;
        w += (bytes + 255) & ~(size_t)255;
        return p;
    };
    int* flags = (int*)alloc(256);
    float* wpool = (float*)alloc((size_t)WTOTAL * 4);
    unsigned short* wsplit = (unsigned short*)alloc(65536);   // W1 hi/lo
    unsigned short* ws2 = (unsigned short*)alloc(32768);      // W2 hi/lo
    unsigned short* ws3 = (unsigned short*)alloc(8192);       // W3 hi/lo
    unsigned short* wsgat = (unsigned short*)alloc(4096);     // GATW hi/lo
    unsigned short* wsg = (unsigned short*)alloc(49152);      // LSTM gate W'' hi/lo
    float* dis = (float*)alloc((size_t)N * 4);
    int* rptr = (int*)alloc((size_t)(N + 1) * 4);
    int* csr_src = (int*)alloc((size_t)EE * 4);
    unsigned* gh = (unsigned*)alloc((size_t)NBK * 256 * 4);
    unsigned* gh2 = (unsigned*)alloc((size_t)NBK * 256 * 4);
    unsigned* bsum = (unsigned*)alloc(1024);
    int* bb = (int*)alloc(1024);
    int2* ebkt = (int2*)alloc((size_t)EE * 8);
    float* asrc = (float*)alloc((size_t)N * 4);
    float* adst = (float*)alloc((size_t)N * 4);
    unsigned* bufT = (unsigned*)alloc((size_t)N * 64 * 4);  // bf16 N x 128
    float* bufH = (float*)alloc((size_t)N * 128 * 4);       // fp32 N x 128

    WSrc ws_srcs;
    for (int i = 0; i < 20; ++i) ws_srcs.p[i] = d_in[2 + i];

    const int AGG = (N + 3) / 4;
    const int TMB = (N + 63) / 64;
    const int WB = (WTOTAL + 255) / 256;

    k_detect<<<1, 256, 0, stream>>>((const unsigned short*)d_in[0],
                                    (const unsigned int*)d_in[1], flags);
    k_cvt_w<<<WB, 256, 0, stream>>>(ws_srcs, wpool, flags, WTOTAL);
    k_prep_all<<<156, 256, 0, stream>>>(wpool, wsplit, ws2, ws3, wsgat, wsg);
    // bucketed CSR build (two-phase parallel scan replaces the old single-block k_bscan)
    k_hist<<<NBK, 256, 0, stream>>>(d_in[1], gh, flags);
    k_bscan_a<<<256, 256, 0, stream>>>(gh, gh2, bsum);
    k_bscan_b<<<1, 256, 0, stream>>>(bsum, bb, rptr);
    k_scatter<<<NBK, 256, 0, stream>>>(d_in[1], gh2, bb, ebkt, flags);
    k_bucket_csr<<<NBK, 256, 0, stream>>>(ebkt, bb, rptr, dis, csr_src);

    // GCN 1 (x -> t1' = (x@W1)*dis, bf16): MFMA for BOTH input dtypes (flag-gated)
    k_gcn1_mfma<0><<<TMB, 256, 0, stream>>>(d_in[0], wsplit, bufT, N, flags, dis);
    k_gcn1_mfma<1><<<TMB, 256, 0, stream>>>(d_in[0], wsplit, bufT, N, flags, dis);
    k_agg128<true><<<AGG, 256, 0, stream>>>(bufT, rptr, csr_src, dis, wpool + OFF_B1, bufH, N);
    // GCN 2 (MFMA)
    k_mm_mfma<128, 64, true><<<TMB, 256, 0, stream>>>(bufH, ws2, (unsigned short*)bufT, N, dis);
    k_agg64<true><<<AGG, 256, 0, stream>>>(bufT, rptr, csr_src, dis, wpool + OFF_B2, bufH, N);
    // GCN 3 (MFMA)
    k_mm_mfma<64, 32, true><<<TMB, 256, 0, stream>>>(bufH, ws3, (unsigned short*)bufT, N, dis);
    k_agg32<false><<<AGG, 256, 0, stream>>>(bufT, rptr, csr_src, dis, wpool + OFF_B3, bufH, N);
    // GAT projection fused with a_src/a_dst dots, then aggregation
    k_mm_gat<<<TMB, 256, 0, stream>>>(bufH, wsgat, (unsigned short*)bufT, N, wpool, asrc, adst);
    k_gat_agg<<<AGG, 256, 0, stream>>>(bufT, rptr, csr_src, asrc, adst, wpool + OFF_GAB, bufH, N);
    // fused LSTM gates (both dirs) + BN + FC + output
    k_lstm_full<<<TMB, 256, 0, stream>>>(bufH, wsg, wpool, d_out, flags, N);
}